// Round 3
// baseline (860.591 us; speedup 1.0000x reference)
//
#include <hip/hip_runtime.h>
#include <math.h>

#define NH    114
#define WIN   130
#define WO1   66
#define WO2   37
#define C1    5
#define C2    10
#define C3    20
#define K1    65
#define K2    30
#define K3    37
#define NN    114
#define RB    16     // rows per block

__device__ __forceinline__ float elu_f(float x) { return x > 0.f ? x : expm1f(x); }

__device__ __forceinline__ void lds_fence() {
    asm volatile("s_waitcnt lgkmcnt(0)" ::: "memory");
}

// ---------------- Kernel 1: conv pipeline, lanes = (position, row) ----------------
// Block: 256 threads = 4 waves; 16 rows per block.
// LDS: s1[66][5][16] | union( sx[130][16] , s2[370][16] ) | (st3w/st3 alias s1 in conv3 phase)
__global__ __launch_bounds__(256, 3) void conv_rows_kernel(
    const float* __restrict__ x,
    const float* __restrict__ w1, const float* __restrict__ b1,
    const float* __restrict__ g1, const float* __restrict__ be1,
    const float* __restrict__ w2, const float* __restrict__ b2,
    const float* __restrict__ g2, const float* __restrict__ be2,
    const float* __restrict__ w3, const float* __restrict__ b3,
    const float* __restrict__ g3, const float* __restrict__ be3,
    float* __restrict__ feats, int nrows)
{
    __shared__ float smem[5280 + 5920];
    float* const s1   = smem;            // [p][c][r]: (p*5+c)*16+r   (5280)
    float* const sx   = smem + 5280;     // [w][r]: w*16+r            (2080, aliases s2)
    float* const s2   = smem + 5280;     // [j][r]: j*16+r            (5920)
    float* const st3w = smem;            // [oc][wavepart][r]: oc*64+wp*16+r (1280, aliases s1)
    float* const st3  = smem + 1280;     // [oc][r]: oc*16+r          (320, aliases s1)

    const int tid  = threadIdx.x;
    const int wave = tid >> 6;
    const int lane = tid & 63;
    const int psub = lane >> 4;
    const int rsub = lane & 15;
    const int row0 = blockIdx.x * RB;
    const int row  = row0 + rsub;

    // ---- stage 16 rows of x into LDS, transposed ----
    {
        const size_t gbase = (size_t)row0 * WIN;
        const long long limit = (long long)(nrows - row0) * WIN;
        #pragma unroll
        for (int j = 0; j < 9; ++j) {
            int f = tid + j * 256;
            if (f < RB * WIN) {
                float v = ((long long)f < limit) ? x[gbase + f] : 0.f;
                int r = f / WIN, w = f - r * WIN;
                sx[w * 16 + r] = v;
            }
        }
    }
    __syncthreads();

    // ---- conv1 + LN1 + ELU : positions packed 16/iter/wave ----
    for (int it = 0; it < 5; ++it) {
        const int p  = it * 16 + wave * 4 + psub;      // 0..79
        const int p2 = min(p, WO1 - 1);
        float acc[C1];
        #pragma unroll
        for (int c = 0; c < C1; ++c) acc[c] = b1[c];
        #pragma unroll
        for (int k = 0; k < K1; ++k) {
            float xv = sx[(p2 + k) * 16 + rsub];
            #pragma unroll
            for (int c = 0; c < C1; ++c) acc[c] = fmaf(xv, w1[k * C1 + c], acc[c]);
        }
        float m = 0.f;
        #pragma unroll
        for (int c = 0; c < C1; ++c) m += acc[c];
        m *= 0.2f;
        float v = 0.f;
        #pragma unroll
        for (int c = 0; c < C1; ++c) { float d = acc[c] - m; v = fmaf(d, d, v); }
        float inv = rsqrtf(v * 0.2f + 1e-3f);
        if (p < WO1) {
            #pragma unroll
            for (int c = 0; c < C1; ++c)
                s1[(p * C1 + c) * 16 + rsub] = elu_f((acc[c] - m) * inv * g1[c] + be1[c]);
        }
    }
    __syncthreads();

    // ---- conv2 + LN2 + ELU ----
    for (int it = 0; it < 3; ++it) {
        const int p  = it * 16 + wave * 4 + psub;      // 0..47
        const int p2 = min(p, WO2 - 1);
        float acc[C2];
        #pragma unroll
        for (int o = 0; o < C2; ++o) acc[o] = b2[o];
        #pragma unroll
        for (int k = 0; k < K2; ++k) {
            const float* s1p = &s1[(p2 + k) * (C1 * 16) + rsub];
            float v0 = s1p[0];
            float v1 = s1p[16];
            float v2 = s1p[32];
            float v3 = s1p[48];
            float v4 = s1p[64];
            const float* wk = w2 + k * (C1 * C2);      // uniform -> s_load
            #pragma unroll
            for (int o = 0; o < C2; ++o) {
                float a = acc[o];
                a = fmaf(v0, wk[o], a);
                a = fmaf(v1, wk[10 + o], a);
                a = fmaf(v2, wk[20 + o], a);
                a = fmaf(v3, wk[30 + o], a);
                a = fmaf(v4, wk[40 + o], a);
                acc[o] = a;
            }
        }
        float m = 0.f;
        #pragma unroll
        for (int o = 0; o < C2; ++o) m += acc[o];
        m *= 0.1f;
        float v = 0.f;
        #pragma unroll
        for (int o = 0; o < C2; ++o) { float d = acc[o] - m; v = fmaf(d, d, v); }
        float inv = rsqrtf(v * 0.1f + 1e-3f);
        if (p < WO2) {
            #pragma unroll
            for (int o = 0; o < C2; ++o)
                s2[(p * C2 + o) * 16 + rsub] = elu_f((acc[o] - m) * inv * g2[o] + be2[o]);
        }
    }
    __syncthreads();

    // ---- conv3: 370-term dot split over 4 waves x 4 lane-groups; 20 och in regs ----
    {
        const int jw0 = (K3 * C2 * wave) / 4;
        const int jw1 = (K3 * C2 * (wave + 1)) / 4;
        const int isub = lane >> 4;
        const int jb = jw0 + ((jw1 - jw0) * isub) / 4;
        const int je = jw0 + ((jw1 - jw0) * (isub + 1)) / 4;
        float acc[C3];
        #pragma unroll
        for (int oc = 0; oc < C3; ++oc) acc[oc] = 0.f;
        for (int j = jb; j < je; ++j) {
            float sv = s2[j * 16 + rsub];
            const float4* wr = (const float4*)(w3 + j * C3);
            float4 wa = wr[0], wb = wr[1], wc = wr[2], wd = wr[3], we = wr[4];
            acc[0]  = fmaf(sv, wa.x, acc[0]);  acc[1]  = fmaf(sv, wa.y, acc[1]);
            acc[2]  = fmaf(sv, wa.z, acc[2]);  acc[3]  = fmaf(sv, wa.w, acc[3]);
            acc[4]  = fmaf(sv, wb.x, acc[4]);  acc[5]  = fmaf(sv, wb.y, acc[5]);
            acc[6]  = fmaf(sv, wb.z, acc[6]);  acc[7]  = fmaf(sv, wb.w, acc[7]);
            acc[8]  = fmaf(sv, wc.x, acc[8]);  acc[9]  = fmaf(sv, wc.y, acc[9]);
            acc[10] = fmaf(sv, wc.z, acc[10]); acc[11] = fmaf(sv, wc.w, acc[11]);
            acc[12] = fmaf(sv, wd.x, acc[12]); acc[13] = fmaf(sv, wd.y, acc[13]);
            acc[14] = fmaf(sv, wd.z, acc[14]); acc[15] = fmaf(sv, wd.w, acc[15]);
            acc[16] = fmaf(sv, we.x, acc[16]); acc[17] = fmaf(sv, we.y, acc[17]);
            acc[18] = fmaf(sv, we.z, acc[18]); acc[19] = fmaf(sv, we.w, acc[19]);
        }
        #pragma unroll
        for (int oc = 0; oc < C3; ++oc) {
            acc[oc] += __shfl_xor(acc[oc], 16, 64);
            acc[oc] += __shfl_xor(acc[oc], 32, 64);
        }
        __syncthreads();   // all conv2 reads of s1 done; safe to overwrite with st3w
        if (isub == 0) {
            #pragma unroll
            for (int oc = 0; oc < C3; ++oc)
                st3w[oc * 64 + wave * 16 + rsub] = acc[oc];
        }
    }
    __syncthreads();

    // ---- conv3 reduce + LN3 + ELU -> feats (wave 0 only) ----
    if (wave == 0) {
        const int oc4 = lane >> 4;  // 0..3
        float vals[5];
        #pragma unroll
        for (int l = 0; l < 5; ++l) {
            int oc = l * 4 + oc4;
            float v = st3w[oc * 64 + rsub] + st3w[oc * 64 + 16 + rsub]
                    + st3w[oc * 64 + 32 + rsub] + st3w[oc * 64 + 48 + rsub] + b3[oc];
            vals[l] = v;
            st3[oc * 16 + rsub] = v;
        }
        lds_fence();
        float sum = 0.f, sumsq = 0.f;
        #pragma unroll
        for (int q = 0; q < C3; ++q) {
            float v = st3[q * 16 + rsub];
            sum += v;
            sumsq = fmaf(v, v, sumsq);
        }
        float m   = sum * (1.f / C3);
        float var = sumsq * (1.f / C3) - m * m;
        float inv = rsqrtf(var + 1e-3f);
        if (row < nrows) {
            #pragma unroll
            for (int l = 0; l < 5; ++l) {
                int oc = l * 4 + oc4;
                feats[(size_t)row * C3 + oc] = elu_f((vals[l] - m) * inv * g3[oc] + be3[oc]);
            }
        }
    }
}

// ---------------- Kernel 2: per-batch graph block (unchanged) ----------------
__global__ __launch_bounds__(256) void graph_kernel(
    const float* __restrict__ feats,
    const float* __restrict__ agent_w, const float* __restrict__ agent_b,
    const float* __restrict__ g1w, const float* __restrict__ g1b,
    const float* __restrict__ g2w, const float* __restrict__ g2b,
    const float* __restrict__ dw, const float* __restrict__ db,
    const int* __restrict__ rlp,
    float* __restrict__ out)
{
    __shared__ float sfe[NN * C3];
    __shared__ float sfc[NN * C3];
    __shared__ float sA[NN * NN];
    __shared__ float snrm[NN], sidx[NN], sdv[NN];
    __shared__ float red[256];
    __shared__ float ssigma;
    __shared__ float sfeat[10];
    __shared__ float sg1[C3 * C2], sg1b[C2], sg2[C2 * C1], sg2b[C1], sdw[20], sdb[2];

    const int tid = threadIdx.x;
    const int b = blockIdx.x;
    const float* F = feats + (size_t)b * (NN * C3);
    const int rl = rlp[0];

    if (tid < C3 * C2) sg1[tid] = g1w[tid];
    if (tid < C2) sg1b[tid] = g1b[tid];
    if (tid < C2 * C1) sg2[tid] = g2w[tid];
    if (tid < C1) sg2b[tid] = g2b[tid];
    if (tid < 20) sdw[tid] = dw[tid];
    if (tid < 2) sdb[tid] = db[tid];

    for (int n = tid; n < NN; n += 256) {
        float f[C3];
        float m = 0.f;
        #pragma unroll
        for (int d = 0; d < C3; ++d) { f[d] = F[n * C3 + d]; m += f[d]; }
        m *= (1.f / C3);
        float nr = 0.f, ag = 0.f;
        #pragma unroll
        for (int d = 0; d < C3; ++d) {
            sfe[n * C3 + d] = f[d];
            float c = f[d] - m;
            sfc[n * C3 + d] = c;
            nr += c * c;
            ag += f[d] * agent_w[d];
        }
        snrm[n] = sqrtf(nr);
        sidx[n] = rl ? (1.f / (1.f + expf(-(ag + agent_b[0])))) : 1.f;
    }
    __syncthreads();

    float psum = 0.f;
    for (int e = tid; e < NN * NN; e += 256) {
        int n = e / NN, m = e - n * NN;
        float dot = 0.f;
        #pragma unroll
        for (int d = 0; d < C3; ++d) dot += sfc[n * C3 + d] * sfc[m * C3 + d];
        float corr = dot / (snrm[n] * snrm[m]);
        float dist = (n == m) ? 0.f : (1.f - corr);
        sA[e] = dist;
        psum += dist;
    }
    red[tid] = psum;
    __syncthreads();
    for (int s = 128; s > 0; s >>= 1) {
        if (tid < s) red[tid] += red[tid + s];
        __syncthreads();
    }
    if (tid == 0) ssigma = red[0] / (float)(NN * NN);
    __syncthreads();

    const float sig = ssigma;
    const float inv2s2 = 1.f / (2.f * sig * sig);
    for (int e = tid; e < NN * NN; e += 256) {
        int n = e / NN, m = e - n * NN;
        float dist = sA[e];
        sA[e] = sidx[n] * sidx[m] * expf(-dist * dist * inv2s2);
    }
    __syncthreads();

    for (int n = tid; n < NN; n += 256) {
        float s = 0.f;
        for (int m = 0; m < NN; ++m) s += sA[n * NN + m];
        float dv = rsqrtf(s);
        if (isinf(dv)) dv = 0.f;
        sdv[n] = dv;
    }
    __syncthreads();

    for (int e = tid; e < NN * NN; e += 256) {
        int n = e / NN, m = e - n * NN;
        sA[e] *= sdv[n] * sdv[m];
    }
    __syncthreads();

    for (int e = tid; e < NN * C2; e += 256) {
        int n = e / C2, o = e - n * C2;
        float acc = 0.f;
        #pragma unroll
        for (int d = 0; d < C3; ++d) acc += sfe[n * C3 + d] * sg1[d * C2 + o];
        sfc[e] = acc * sidx[n] + sg1b[o];
    }
    __syncthreads();

    for (int e = tid; e < NN * C2; e += 256) {
        int n = e / C2, o = e - n * C2;
        float acc = 0.f;
        for (int m = 0; m < NN; ++m) acc += sA[n * NN + m] * sfc[m * C2 + o];
        sfe[e] = elu_f(acc);
    }
    __syncthreads();

    for (int e = tid; e < NN * C1; e += 256) {
        int n = e / C1, c = e - n * C1;
        float acc = sg2b[c];
        #pragma unroll
        for (int o = 0; o < C2; ++o) acc += sfe[n * C2 + o] * sg2[o * C1 + c];
        sfc[NN * C2 + e] = acc;
    }
    __syncthreads();

    for (int e = tid; e < NN * C1; e += 256) {
        int n = e / C1, c = e - n * C1;
        float acc = 0.f;
        for (int m = 0; m < NN; ++m) acc += sA[n * NN + m] * sfc[NN * C2 + m * C1 + c];
        sfe[NN * C2 + e] = elu_f(acc);
    }
    __syncthreads();

    if (tid < C1) {
        const int c = tid;
        float pmax = -INFINITY, rmin = INFINITY, s = 0.f;
        for (int n = 0; n < NN; ++n) {
            float v = sfe[NN * C2 + n * C1 + c];
            pmax = fmaxf(pmax, v);
            rmin = fminf(rmin, 1.f / v);
            s += v;
        }
        float nmax = 1.f / rmin;
        sfeat[c] = (pmax == 0.f) ? nmax : pmax;
        sfeat[C1 + c] = s;
    }
    __syncthreads();

    if (tid == 0) {
        float l0 = sdb[0], l1 = sdb[1];
        #pragma unroll
        for (int j = 0; j < 10; ++j) {
            l0 += sfeat[j] * sdw[j * 2 + 0];
            l1 += sfeat[j] * sdw[j * 2 + 1];
        }
        float mx = fmaxf(l0, l1);
        float e0 = expf(l0 - mx), e1 = expf(l1 - mx);
        float s = e0 + e1;
        out[b * 2 + 0] = e0 / s;
        out[b * 2 + 1] = e1 / s;
    }
}

extern "C" void kernel_launch(void* const* d_in, const int* in_sizes, int n_in,
                              void* d_out, int out_size, void* d_ws, size_t ws_size,
                              hipStream_t stream) {
    const float* x       = (const float*)d_in[0];
    const float* conv1_w = (const float*)d_in[1];
    const float* conv1_b = (const float*)d_in[2];
    const float* ln1_g   = (const float*)d_in[3];
    const float* ln1_b   = (const float*)d_in[4];
    const float* conv2_w = (const float*)d_in[5];
    const float* conv2_b = (const float*)d_in[6];
    const float* ln2_g   = (const float*)d_in[7];
    const float* ln2_b   = (const float*)d_in[8];
    const float* conv3_w = (const float*)d_in[9];
    const float* conv3_b = (const float*)d_in[10];
    const float* ln3_g   = (const float*)d_in[11];
    const float* ln3_b   = (const float*)d_in[12];
    const float* agent_w = (const float*)d_in[13];
    const float* agent_b = (const float*)d_in[14];
    const float* gconv1_w= (const float*)d_in[15];
    const float* gconv1_b= (const float*)d_in[16];
    const float* gconv2_w= (const float*)d_in[17];
    const float* gconv2_b= (const float*)d_in[18];
    const float* dense_w = (const float*)d_in[19];
    const float* dense_b = (const float*)d_in[20];
    const int*   rl      = (const int*)d_in[21];
    float* out = (float*)d_out;

    const int B = in_sizes[0] / (NH * WIN);
    const int nrows = B * NH;
    float* feats = (float*)d_ws;

    dim3 block(256);
    dim3 grid1((nrows + RB - 1) / RB);
    hipLaunchKernelGGL(conv_rows_kernel, grid1, block, 0, stream,
                       x, conv1_w, conv1_b, ln1_g, ln1_b,
                       conv2_w, conv2_b, ln2_g, ln2_b,
                       conv3_w, conv3_b, ln3_g, ln3_b,
                       feats, nrows);

    dim3 grid2(B);
    hipLaunchKernelGGL(graph_kernel, grid2, block, 0, stream,
                       feats, agent_w, agent_b,
                       gconv1_w, gconv1_b, gconv2_w, gconv2_b,
                       dense_w, dense_b, rl, out);
}

// Round 4
// 480.756 us; speedup vs baseline: 1.7901x; 1.7901x over previous
//
#include <hip/hip_runtime.h>
#include <math.h>

#define NH    114
#define WIN   130
#define WO1   66
#define WO2   37
#define C1    5
#define C2    10
#define C3    20
#define K1    65
#define K2    30
#define K3    37
#define NN    114
#define RPB   8      // rows per block = 4 waves x 2 rows (row pair per wave)

typedef float f32x2 __attribute__((ext_vector_type(2)));

__device__ __forceinline__ f32x2 mk2(float a, float b) { f32x2 r; r.x = a; r.y = b; return r; }
__device__ __forceinline__ f32x2 splat2(float s) { f32x2 r; r.x = s; r.y = s; return r; }
#if __has_builtin(__builtin_elementwise_fma)
__device__ __forceinline__ f32x2 pkfma(f32x2 a, float w, f32x2 c) {
    return __builtin_elementwise_fma(a, splat2(w), c);   // -> v_pk_fma_f32 with op_sel splat
}
__device__ __forceinline__ f32x2 pkfma2(f32x2 a, f32x2 b, f32x2 c) {
    return __builtin_elementwise_fma(a, b, c);
}
#else
__device__ __forceinline__ f32x2 pkfma(f32x2 a, float w, f32x2 c) {
    f32x2 r; r.x = fmaf(a.x, w, c.x); r.y = fmaf(a.y, w, c.y); return r;
}
__device__ __forceinline__ f32x2 pkfma2(f32x2 a, f32x2 b, f32x2 c) {
    f32x2 r; r.x = fmaf(a.x, b.x, c.x); r.y = fmaf(a.y, b.y, c.y); return r;
}
#endif
__device__ __forceinline__ float elu_f(float v) { return v > 0.f ? v : expm1f(v); }
__device__ __forceinline__ f32x2 elu2(f32x2 v) { f32x2 r; r.x = elu_f(v.x); r.y = elu_f(v.y); return r; }
__device__ __forceinline__ f32x2 rsqrt2(f32x2 v) { f32x2 r; r.x = rsqrtf(v.x); r.y = rsqrtf(v.y); return r; }

__device__ __forceinline__ void lds_fence() {
    asm volatile("s_waitcnt lgkmcnt(0)" ::: "memory");
}

// ---------------- Kernel 1: conv pipeline, one wave per ROW PAIR, packed f32 ----------------
__global__ __launch_bounds__(256, 4) void conv_rows_kernel(
    const float* __restrict__ x,
    const float* __restrict__ w1, const float* __restrict__ b1,
    const float* __restrict__ g1, const float* __restrict__ be1,
    const float* __restrict__ w2, const float* __restrict__ b2,
    const float* __restrict__ g2, const float* __restrict__ be2,
    const float* __restrict__ w3, const float* __restrict__ b3,
    const float* __restrict__ g3, const float* __restrict__ be3,
    float* __restrict__ feats, int nrows)
{
    __shared__ f32x2 sx[4][WIN];          // input row pair        (4x130x8B)
    __shared__ f32x2 s1[4][WO1 * C1];     // conv1 out [p*5+c]     (4x330x8B)
    __shared__ f32x2 s2[4][WO2 * C2];     // conv2 out [p*10+o]    (4x370x8B)
    __shared__ f32x2 spart[4][3][C3];
    __shared__ f32x2 st[4][C3];

    const int tid  = threadIdx.x;
    const int wave = tid >> 6;
    const int lane = tid & 63;
    const int prow = blockIdx.x * RPB + wave * 2;   // even; prow+1 valid when prow < nrows
    const bool rv  = prow < nrows;

    // ---- stage row pair into LDS as f32x2 ----
    if (rv) {
        const float* xr0 = x + (size_t)prow * WIN;
        const float* xr1 = xr0 + WIN;
        sx[wave][lane]      = mk2(xr0[lane],      xr1[lane]);
        sx[wave][64 + lane] = mk2(xr0[64 + lane], xr1[64 + lane]);
        if (lane < WIN - 128)
            sx[wave][128 + lane] = mk2(xr0[128 + lane], xr1[128 + lane]);
    }
    __syncthreads();   // wave 0's leftover pass below reads other waves' sx

    // ---- conv1 + LN1 + ELU : main pass, p = lane (0..63) ----
    if (rv) {
        const int p = lane;
        f32x2 acc[C1];
        #pragma unroll
        for (int c = 0; c < C1; ++c) acc[c] = splat2(b1[c]);
        #pragma unroll
        for (int k = 0; k < K1; ++k) {
            f32x2 xv = sx[wave][p + k];
            #pragma unroll
            for (int c = 0; c < C1; ++c) acc[c] = pkfma(xv, w1[k * C1 + c], acc[c]);
        }
        f32x2 m = splat2(0.f);
        #pragma unroll
        for (int c = 0; c < C1; ++c) m += acc[c];
        m *= 0.2f;
        f32x2 v = splat2(0.f);
        #pragma unroll
        for (int c = 0; c < C1; ++c) { f32x2 d = acc[c] - m; v = pkfma2(d, d, v); }
        f32x2 inv = rsqrt2(v * 0.2f + 1e-3f);
        #pragma unroll
        for (int c = 0; c < C1; ++c)
            s1[wave][p * C1 + c] = elu2((acc[c] - m) * inv * g1[c] + be1[c]);
    }

    // ---- conv1 leftover: positions 64,65 of all 4 pairs, done by wave 0 (8 lanes) ----
    if (wave == 0) {
        const int pr = lane >> 1;            // pair 0..3
        const int pp = 64 + (lane & 1);      // 64..65
        const int rr = blockIdx.x * RPB + pr * 2;
        if (lane < 8 && rr < nrows) {
            f32x2 acc[C1];
            #pragma unroll
            for (int c = 0; c < C1; ++c) acc[c] = splat2(b1[c]);
            for (int k = 0; k < K1; ++k) {
                f32x2 xv = sx[pr][pp + k];
                #pragma unroll
                for (int c = 0; c < C1; ++c) acc[c] = pkfma(xv, w1[k * C1 + c], acc[c]);
            }
            f32x2 m = splat2(0.f);
            #pragma unroll
            for (int c = 0; c < C1; ++c) m += acc[c];
            m *= 0.2f;
            f32x2 v = splat2(0.f);
            #pragma unroll
            for (int c = 0; c < C1; ++c) { f32x2 d = acc[c] - m; v = pkfma2(d, d, v); }
            f32x2 inv = rsqrt2(v * 0.2f + 1e-3f);
            #pragma unroll
            for (int c = 0; c < C1; ++c)
                s1[pr][pp * C1 + c] = elu2((acc[c] - m) * inv * g1[c] + be1[c]);
        }
    }
    __syncthreads();   // s1 complete (incl. cross-wave leftovers)

    // ---- conv2 + LN2 + ELU : lanes 0..36, packed ----
    if (rv && lane < WO2) {
        f32x2 acc[C2];
        #pragma unroll
        for (int o = 0; o < C2; ++o) acc[o] = splat2(b2[o]);
        #pragma unroll
        for (int k = 0; k < K2; ++k) {
            const f32x2* s1p = &s1[wave][(lane + k) * C1];
            f32x2 v0 = s1p[0], v1 = s1p[1], v2 = s1p[2], v3 = s1p[3], v4 = s1p[4];
            const float* wk = w2 + k * (C1 * C2);   // uniform -> s_load
            #pragma unroll
            for (int o = 0; o < C2; ++o) {
                f32x2 a = acc[o];
                a = pkfma(v0, wk[o], a);
                a = pkfma(v1, wk[10 + o], a);
                a = pkfma(v2, wk[20 + o], a);
                a = pkfma(v3, wk[30 + o], a);
                a = pkfma(v4, wk[40 + o], a);
                acc[o] = a;
            }
        }
        f32x2 m = splat2(0.f);
        #pragma unroll
        for (int o = 0; o < C2; ++o) m += acc[o];
        m *= 0.1f;
        f32x2 v = splat2(0.f);
        #pragma unroll
        for (int o = 0; o < C2; ++o) { f32x2 d = acc[o] - m; v = pkfma2(d, d, v); }
        f32x2 inv = rsqrt2(v * 0.1f + 1e-3f);
        #pragma unroll
        for (int o = 0; o < C2; ++o)
            s2[wave][lane * C2 + o] = elu2((acc[o] - m) * inv * g2[o] + be2[o]);
    }
    lds_fence();

    // ---- conv3: 370-term dot split over 3 lane-groups of 20; packed ----
    {
        const int l2 = lane < 60 ? lane : 59;
        const int g  = l2 / 20;
        const int c  = l2 - g * 20;
        const int jb = (g == 0) ? 0 : (g == 1 ? 124 : 247);
        const int cnt = (g == 0) ? 124 : 123;
        f32x2 acc = splat2(0.f);
        for (int t = 0; t < cnt; ++t) {          // divergent tail iter is exec-masked
            int j = jb + t;
            acc = pkfma(s2[wave][j], w3[j * C3 + c], acc);
        }
        if (rv && lane < 60) spart[wave][g][c] = acc;
    }
    lds_fence();

    if (rv && lane < C3) {
        f32x2 v = spart[wave][0][lane] + spart[wave][1][lane] + spart[wave][2][lane]
                + splat2(b3[lane]);
        st[wave][lane] = v;
    }
    lds_fence();

    // ---- LN3 + ELU -> feats (both rows) ----
    if (rv && lane < C3) {
        f32x2 myv = st[wave][lane];
        f32x2 sum = splat2(0.f), sq = splat2(0.f);
        #pragma unroll
        for (int q = 0; q < C3; ++q) {
            f32x2 t = st[wave][q];
            sum += t;
            sq = pkfma2(t, t, sq);
        }
        f32x2 m   = sum * (1.f / C3);
        f32x2 var = sq * (1.f / C3) - m * m;
        f32x2 inv = rsqrt2(var + 1e-3f);
        f32x2 o   = elu2((myv - m) * inv * g3[lane] + be3[lane]);
        feats[(size_t)prow * C3 + lane]       = o.x;
        feats[(size_t)(prow + 1) * C3 + lane] = o.y;
    }
}

// ---------------- Kernel 2: per-batch graph block (unchanged, passing) ----------------
__global__ __launch_bounds__(256) void graph_kernel(
    const float* __restrict__ feats,
    const float* __restrict__ agent_w, const float* __restrict__ agent_b,
    const float* __restrict__ g1w, const float* __restrict__ g1b,
    const float* __restrict__ g2w, const float* __restrict__ g2b,
    const float* __restrict__ dw, const float* __restrict__ db,
    const int* __restrict__ rlp,
    float* __restrict__ out)
{
    __shared__ float sfe[NN * C3];
    __shared__ float sfc[NN * C3];
    __shared__ float sA[NN * NN];
    __shared__ float snrm[NN], sidx[NN], sdv[NN];
    __shared__ float red[256];
    __shared__ float ssigma;
    __shared__ float sfeat[10];
    __shared__ float sg1[C3 * C2], sg1b[C2], sg2[C2 * C1], sg2b[C1], sdw[20], sdb[2];

    const int tid = threadIdx.x;
    const int b = blockIdx.x;
    const float* F = feats + (size_t)b * (NN * C3);
    const int rl = rlp[0];

    if (tid < C3 * C2) sg1[tid] = g1w[tid];
    if (tid < C2) sg1b[tid] = g1b[tid];
    if (tid < C2 * C1) sg2[tid] = g2w[tid];
    if (tid < C1) sg2b[tid] = g2b[tid];
    if (tid < 20) sdw[tid] = dw[tid];
    if (tid < 2) sdb[tid] = db[tid];

    for (int n = tid; n < NN; n += 256) {
        float f[C3];
        float m = 0.f;
        #pragma unroll
        for (int d = 0; d < C3; ++d) { f[d] = F[n * C3 + d]; m += f[d]; }
        m *= (1.f / C3);
        float nr = 0.f, ag = 0.f;
        #pragma unroll
        for (int d = 0; d < C3; ++d) {
            sfe[n * C3 + d] = f[d];
            float c = f[d] - m;
            sfc[n * C3 + d] = c;
            nr += c * c;
            ag += f[d] * agent_w[d];
        }
        snrm[n] = sqrtf(nr);
        sidx[n] = rl ? (1.f / (1.f + expf(-(ag + agent_b[0])))) : 1.f;
    }
    __syncthreads();

    float psum = 0.f;
    for (int e = tid; e < NN * NN; e += 256) {
        int n = e / NN, m = e - n * NN;
        float dot = 0.f;
        #pragma unroll
        for (int d = 0; d < C3; ++d) dot += sfc[n * C3 + d] * sfc[m * C3 + d];
        float corr = dot / (snrm[n] * snrm[m]);
        float dist = (n == m) ? 0.f : (1.f - corr);
        sA[e] = dist;
        psum += dist;
    }
    red[tid] = psum;
    __syncthreads();
    for (int s = 128; s > 0; s >>= 1) {
        if (tid < s) red[tid] += red[tid + s];
        __syncthreads();
    }
    if (tid == 0) ssigma = red[0] / (float)(NN * NN);
    __syncthreads();

    const float sig = ssigma;
    const float inv2s2 = 1.f / (2.f * sig * sig);
    for (int e = tid; e < NN * NN; e += 256) {
        int n = e / NN, m = e - n * NN;
        float dist = sA[e];
        sA[e] = sidx[n] * sidx[m] * expf(-dist * dist * inv2s2);
    }
    __syncthreads();

    for (int n = tid; n < NN; n += 256) {
        float s = 0.f;
        for (int m = 0; m < NN; ++m) s += sA[n * NN + m];
        float dv = rsqrtf(s);
        if (isinf(dv)) dv = 0.f;
        sdv[n] = dv;
    }
    __syncthreads();

    for (int e = tid; e < NN * NN; e += 256) {
        int n = e / NN, m = e - n * NN;
        sA[e] *= sdv[n] * sdv[m];
    }
    __syncthreads();

    for (int e = tid; e < NN * C2; e += 256) {
        int n = e / C2, o = e - n * C2;
        float acc = 0.f;
        #pragma unroll
        for (int d = 0; d < C3; ++d) acc += sfe[n * C3 + d] * sg1[d * C2 + o];
        sfc[e] = acc * sidx[n] + sg1b[o];
    }
    __syncthreads();

    for (int e = tid; e < NN * C2; e += 256) {
        int n = e / C2, o = e - n * C2;
        float acc = 0.f;
        for (int m = 0; m < NN; ++m) acc += sA[n * NN + m] * sfc[m * C2 + o];
        sfe[e] = elu_f(acc);
    }
    __syncthreads();

    for (int e = tid; e < NN * C1; e += 256) {
        int n = e / C1, c = e - n * C1;
        float acc = sg2b[c];
        #pragma unroll
        for (int o = 0; o < C2; ++o) acc += sfe[n * C2 + o] * sg2[o * C1 + c];
        sfc[NN * C2 + e] = acc;
    }
    __syncthreads();

    for (int e = tid; e < NN * C1; e += 256) {
        int n = e / C1, c = e - n * C1;
        float acc = 0.f;
        for (int m = 0; m < NN; ++m) acc += sA[n * NN + m] * sfc[NN * C2 + m * C1 + c];
        sfe[NN * C2 + e] = elu_f(acc);
    }
    __syncthreads();

    if (tid < C1) {
        const int c = tid;
        float pmax = -INFINITY, rmin = INFINITY, s = 0.f;
        for (int n = 0; n < NN; ++n) {
            float v = sfe[NN * C2 + n * C1 + c];
            pmax = fmaxf(pmax, v);
            rmin = fminf(rmin, 1.f / v);
            s += v;
        }
        float nmax = 1.f / rmin;
        sfeat[c] = (pmax == 0.f) ? nmax : pmax;
        sfeat[C1 + c] = s;
    }
    __syncthreads();

    if (tid == 0) {
        float l0 = sdb[0], l1 = sdb[1];
        #pragma unroll
        for (int j = 0; j < 10; ++j) {
            l0 += sfeat[j] * sdw[j * 2 + 0];
            l1 += sfeat[j] * sdw[j * 2 + 1];
        }
        float mx = fmaxf(l0, l1);
        float e0 = expf(l0 - mx), e1 = expf(l1 - mx);
        float s = e0 + e1;
        out[b * 2 + 0] = e0 / s;
        out[b * 2 + 1] = e1 / s;
    }
}

extern "C" void kernel_launch(void* const* d_in, const int* in_sizes, int n_in,
                              void* d_out, int out_size, void* d_ws, size_t ws_size,
                              hipStream_t stream) {
    const float* x       = (const float*)d_in[0];
    const float* conv1_w = (const float*)d_in[1];
    const float* conv1_b = (const float*)d_in[2];
    const float* ln1_g   = (const float*)d_in[3];
    const float* ln1_b   = (const float*)d_in[4];
    const float* conv2_w = (const float*)d_in[5];
    const float* conv2_b = (const float*)d_in[6];
    const float* ln2_g   = (const float*)d_in[7];
    const float* ln2_b   = (const float*)d_in[8];
    const float* conv3_w = (const float*)d_in[9];
    const float* conv3_b = (const float*)d_in[10];
    const float* ln3_g   = (const float*)d_in[11];
    const float* ln3_b   = (const float*)d_in[12];
    const float* agent_w = (const float*)d_in[13];
    const float* agent_b = (const float*)d_in[14];
    const float* gconv1_w= (const float*)d_in[15];
    const float* gconv1_b= (const float*)d_in[16];
    const float* gconv2_w= (const float*)d_in[17];
    const float* gconv2_b= (const float*)d_in[18];
    const float* dense_w = (const float*)d_in[19];
    const float* dense_b = (const float*)d_in[20];
    const int*   rl      = (const int*)d_in[21];
    float* out = (float*)d_out;

    const int B = in_sizes[0] / (NH * WIN);
    const int nrows = B * NH;
    float* feats = (float*)d_ws;

    dim3 block(256);
    dim3 grid1((nrows + RPB - 1) / RPB);
    hipLaunchKernelGGL(conv_rows_kernel, grid1, block, 0, stream,
                       x, conv1_w, conv1_b, ln1_g, ln1_b,
                       conv2_w, conv2_b, ln2_g, ln2_b,
                       conv3_w, conv3_b, ln3_g, ln3_b,
                       feats, nrows);

    dim3 grid2(B);
    hipLaunchKernelGGL(graph_kernel, grid2, block, 0, stream,
                       feats, agent_w, agent_b,
                       gconv1_w, gconv1_b, gconv2_w, gconv2_b,
                       dense_w, dense_b, rl, out);
}

// Round 5
// 453.990 us; speedup vs baseline: 1.8956x; 1.0590x over previous
//
#include <hip/hip_runtime.h>
#include <math.h>

#define NH    114
#define WIN   130
#define WO1   66
#define WO2   37
#define C1    5
#define C2    10
#define C3    20
#define K1    65
#define K2    30
#define K3    37
#define NN    114
#define RPB   16     // rows per block = 4 waves x 4 rows

typedef float f32x4 __attribute__((ext_vector_type(4)));

__device__ __forceinline__ f32x4 splat4(float s) { f32x4 r; r.x = s; r.y = s; r.z = s; r.w = s; return r; }
__device__ __forceinline__ f32x4 pkfma(f32x4 a, float w, f32x4 c) {
    return __builtin_elementwise_fma(a, splat4(w), c);     // 2x v_pk_fma_f32
}
__device__ __forceinline__ f32x4 pkfma4(f32x4 a, f32x4 b, f32x4 c) {
    return __builtin_elementwise_fma(a, b, c);
}
// branchless fast ELU: exact identity for x>=0 (expf(0)==1)
__device__ __forceinline__ float elu_f(float v) { return fmaxf(v, 0.f) + __expf(fminf(v, 0.f)) - 1.f; }
__device__ __forceinline__ f32x4 elu4(f32x4 v) {
    f32x4 r;
    r.x = elu_f(v.x); r.y = elu_f(v.y); r.z = elu_f(v.z); r.w = elu_f(v.w);
    return r;
}
__device__ __forceinline__ f32x4 rsqrt4(f32x4 v) {
    f32x4 r; r.x = rsqrtf(v.x); r.y = rsqrtf(v.y); r.z = rsqrtf(v.z); r.w = rsqrtf(v.w);
    return r;
}
__device__ __forceinline__ void lds_fence() {
    asm volatile("s_waitcnt lgkmcnt(0)" ::: "memory");
}

// LDS layout (f32x4 units):
//   s1  region: quads [0 .. 1320)      : per-wave 330  (66 pos x 5 ch)   [conv3 phase: spart(60)+st(20) alias]
//   s2  region: quads [1320 .. 2808)   : per-wave 372  (370 + 2 zero-pad) [conv1 phase: sx(130) aliases]
#define S2BASE 1320
#define SMEMQ  2808

// ---------------- Kernel 1: conv pipeline, one wave per 4-ROW pack ----------------
__global__ __launch_bounds__(256, 4) void conv_rows_kernel(
    const float* __restrict__ x,
    const float* __restrict__ w1, const float* __restrict__ b1,
    const float* __restrict__ g1, const float* __restrict__ be1,
    const float* __restrict__ w2, const float* __restrict__ b2,
    const float* __restrict__ g2, const float* __restrict__ be2,
    const float* __restrict__ w3, const float* __restrict__ b3,
    const float* __restrict__ g3, const float* __restrict__ be3,
    float* __restrict__ feats, int nrows)
{
    __shared__ f32x4 smem[SMEMQ];

    const int tid  = threadIdx.x;
    const int wave = tid >> 6;
    const int lane = tid & 63;
    const int prow = blockIdx.x * RPB + wave * 4;

    f32x4* const s1  = smem + wave * 330;
    f32x4* const sxv = smem + S2BASE + wave * 372;
    f32x4* const s2  = sxv;
    f32x4* const spart = s1;        // [g*20+c], aliases s1 (safe after conv2 reads)
    f32x4* const st    = s1 + 60;   // [oc]

    // ---- stage 16 rows of x into LDS as f32x4 (row r -> quad (r>>2), comp (r&3)) ----
    {
        float* sxf = (float*)(smem + S2BASE);
        const size_t gbase = (size_t)blockIdx.x * RPB * WIN;
        const size_t gmax  = (size_t)nrows * WIN - 1;
        #pragma unroll
        for (int j = 0; j < 9; ++j) {
            int f = tid + j * 256;
            if (f < RPB * WIN) {
                size_t gi = gbase + (size_t)f;
                float v = x[gi < gmax ? gi : gmax];
                int r = f / WIN, w = f - r * WIN;
                sxf[((r >> 2) * 372 + w) * 4 + (r & 3)] = v;
            }
        }
    }
    __syncthreads();

    // ---- conv1 + LN1 + ELU : p = lane (0..63), uniform CF ----
    {
        const int p = lane;
        f32x4 acc[C1];
        #pragma unroll
        for (int c = 0; c < C1; ++c) acc[c] = splat4(b1[c]);
        #pragma unroll
        for (int k = 0; k < K1; ++k) {
            f32x4 xv = sxv[p + k];
            #pragma unroll
            for (int c = 0; c < C1; ++c) acc[c] = pkfma(xv, w1[k * C1 + c], acc[c]);
        }
        f32x4 m = splat4(0.f);
        #pragma unroll
        for (int c = 0; c < C1; ++c) m += acc[c];
        m *= 0.2f;
        f32x4 v = splat4(0.f);
        #pragma unroll
        for (int c = 0; c < C1; ++c) { f32x4 d = acc[c] - m; v = pkfma4(d, d, v); }
        f32x4 inv = rsqrt4(v * 0.2f + 1e-3f);
        #pragma unroll
        for (int c = 0; c < C1; ++c)
            s1[p * C1 + c] = elu4((acc[c] - m) * inv * g1[c] + be1[c]);
    }

    // ---- conv1 leftover: positions 64,65 for all 4 waves, computed by wave 0 ----
    // all 64 lanes compute (uniform CF), only lanes 0..7 store
    if (wave == 0) {
        const int pr = (lane >> 1) & 3;
        const int pp = 64 + (lane & 1);
        const f32x4* sxo = smem + S2BASE + pr * 372;
        f32x4 acc[C1];
        #pragma unroll
        for (int c = 0; c < C1; ++c) acc[c] = splat4(b1[c]);
        #pragma unroll
        for (int k = 0; k < K1; ++k) {
            f32x4 xv = sxo[pp + k];
            #pragma unroll
            for (int c = 0; c < C1; ++c) acc[c] = pkfma(xv, w1[k * C1 + c], acc[c]);
        }
        f32x4 m = splat4(0.f);
        #pragma unroll
        for (int c = 0; c < C1; ++c) m += acc[c];
        m *= 0.2f;
        f32x4 v = splat4(0.f);
        #pragma unroll
        for (int c = 0; c < C1; ++c) { f32x4 d = acc[c] - m; v = pkfma4(d, d, v); }
        f32x4 inv = rsqrt4(v * 0.2f + 1e-3f);
        if (lane < 8) {
            #pragma unroll
            for (int c = 0; c < C1; ++c)
                smem[pr * 330 + pp * C1 + c] = elu4((acc[c] - m) * inv * g1[c] + be1[c]);
        }
    }
    __syncthreads();

    // ---- conv2 + LN2 + ELU : uniform CF with clamped position ----
    {
        const int p2 = lane < WO2 ? lane : WO2 - 1;
        f32x4 acc[C2];
        #pragma unroll
        for (int o = 0; o < C2; ++o) acc[o] = splat4(b2[o]);
        #pragma unroll
        for (int k = 0; k < K2; ++k) {
            const f32x4* s1p = &s1[(p2 + k) * C1];
            f32x4 v0 = s1p[0], v1 = s1p[1], v2 = s1p[2], v3 = s1p[3], v4 = s1p[4];
            const float* wk = w2 + k * (C1 * C2);       // uniform -> s_load
            #pragma unroll
            for (int o = 0; o < C2; ++o) {
                f32x4 a = acc[o];
                a = pkfma(v0, wk[o], a);
                a = pkfma(v1, wk[10 + o], a);
                a = pkfma(v2, wk[20 + o], a);
                a = pkfma(v3, wk[30 + o], a);
                a = pkfma(v4, wk[40 + o], a);
                acc[o] = a;
            }
        }
        f32x4 m = splat4(0.f);
        #pragma unroll
        for (int o = 0; o < C2; ++o) m += acc[o];
        m *= 0.1f;
        f32x4 v = splat4(0.f);
        #pragma unroll
        for (int o = 0; o < C2; ++o) { f32x4 d = acc[o] - m; v = pkfma4(d, d, v); }
        f32x4 inv = rsqrt4(v * 0.1f + 1e-3f);
        if (lane < WO2) {
            #pragma unroll
            for (int o = 0; o < C2; ++o)
                s2[lane * C2 + o] = elu4((acc[o] - m) * inv * g2[o] + be2[o]);
        }
        if (lane < 2) s2[K3 * C2 + lane] = splat4(0.f);   // zero-pad 370,371
    }
    lds_fence();

    // ---- conv3: 372-term (padded) dot split over 3 lane-groups of 20, uniform CF ----
    {
        const int l2 = lane < 60 ? lane : 59;
        const int g  = l2 / 20;
        const int c  = l2 - g * 20;
        const int jb = g * 124;
        f32x4 acc = splat4(0.f);
        #pragma unroll 4
        for (int t = 0; t < 124; ++t) {
            int j  = jb + t;
            int jw = j < K3 * C2 ? j : K3 * C2 - 1;      // padded s2[j]==0 kills tail terms
            acc = pkfma(s2[j], w3[jw * C3 + c], acc);
        }
        if (lane < 60) spart[g * 20 + c] = acc;
    }
    lds_fence();

    if (lane < C3)
        st[lane] = spart[lane] + spart[20 + lane] + spart[40 + lane] + splat4(b3[lane]);
    lds_fence();

    // ---- LN3 + ELU -> feats (4 rows) ----
    if (lane < C3) {
        f32x4 myv = st[lane];
        f32x4 sum = splat4(0.f), sq = splat4(0.f);
        #pragma unroll
        for (int q = 0; q < C3; ++q) {
            f32x4 t = st[q];
            sum += t;
            sq = pkfma4(t, t, sq);
        }
        f32x4 m   = sum * (1.f / C3);
        f32x4 var = sq * (1.f / C3) - m * m;
        f32x4 inv = rsqrt4(var + 1e-3f);
        f32x4 o   = elu4((myv - m) * inv * g3[lane] + be3[lane]);
        if (prow + 0 < nrows) feats[(size_t)(prow + 0) * C3 + lane] = o.x;
        if (prow + 1 < nrows) feats[(size_t)(prow + 1) * C3 + lane] = o.y;
        if (prow + 2 < nrows) feats[(size_t)(prow + 2) * C3 + lane] = o.z;
        if (prow + 3 < nrows) feats[(size_t)(prow + 3) * C3 + lane] = o.w;
    }
}

// ---------------- Kernel 2: per-batch graph block ----------------
__global__ __launch_bounds__(256) void graph_kernel(
    const float* __restrict__ feats,
    const float* __restrict__ agent_w, const float* __restrict__ agent_b,
    const float* __restrict__ g1w, const float* __restrict__ g1b,
    const float* __restrict__ g2w, const float* __restrict__ g2b,
    const float* __restrict__ dw, const float* __restrict__ db,
    const int* __restrict__ rlp,
    float* __restrict__ out)
{
    __shared__ float sfe[NN * C3];
    __shared__ float sfc[NN * C3];
    __shared__ float sA[NN * NN];
    __shared__ float snrm[NN], sidx[NN], sdv[NN];
    __shared__ float red[256];
    __shared__ float ssigma;
    __shared__ float sfeat[10];
    __shared__ float sg1[C3 * C2], sg1b[C2], sg2[C2 * C1], sg2b[C1], sdw[20], sdb[2];

    const int tid = threadIdx.x;
    const int b = blockIdx.x;
    const float* F = feats + (size_t)b * (NN * C3);
    const int rl = rlp[0];

    if (tid < C3 * C2) sg1[tid] = g1w[tid];
    if (tid < C2) sg1b[tid] = g1b[tid];
    if (tid < C2 * C1) sg2[tid] = g2w[tid];
    if (tid < C1) sg2b[tid] = g2b[tid];
    if (tid < 20) sdw[tid] = dw[tid];
    if (tid < 2) sdb[tid] = db[tid];

    for (int n = tid; n < NN; n += 256) {
        float f[C3];
        float m = 0.f;
        #pragma unroll
        for (int d = 0; d < C3; ++d) { f[d] = F[n * C3 + d]; m += f[d]; }
        m *= (1.f / C3);
        float nr = 0.f, ag = 0.f;
        #pragma unroll
        for (int d = 0; d < C3; ++d) {
            sfe[n * C3 + d] = f[d];
            float c = f[d] - m;
            sfc[n * C3 + d] = c;
            nr += c * c;
            ag += f[d] * agent_w[d];
        }
        snrm[n] = sqrtf(nr);
        sidx[n] = rl ? (1.f / (1.f + __expf(-(ag + agent_b[0])))) : 1.f;
    }
    __syncthreads();

    float psum = 0.f;
    for (int e = tid; e < NN * NN; e += 256) {
        int n = e / NN, m = e - n * NN;
        float dot = 0.f;
        #pragma unroll
        for (int d = 0; d < C3; ++d) dot += sfc[n * C3 + d] * sfc[m * C3 + d];
        float corr = dot / (snrm[n] * snrm[m]);
        float dist = (n == m) ? 0.f : (1.f - corr);
        sA[e] = dist;
        psum += dist;
    }
    red[tid] = psum;
    __syncthreads();
    for (int s = 128; s > 0; s >>= 1) {
        if (tid < s) red[tid] += red[tid + s];
        __syncthreads();
    }
    if (tid == 0) ssigma = red[0] / (float)(NN * NN);
    __syncthreads();

    const float sig = ssigma;
    const float inv2s2 = 1.f / (2.f * sig * sig);
    for (int e = tid; e < NN * NN; e += 256) {
        int n = e / NN, m = e - n * NN;
        float dist = sA[e];
        sA[e] = sidx[n] * sidx[m] * __expf(-dist * dist * inv2s2);
    }
    __syncthreads();

    for (int n = tid; n < NN; n += 256) {
        float s = 0.f;
        for (int m = 0; m < NN; ++m) s += sA[n * NN + m];
        float dv = rsqrtf(s);
        if (isinf(dv)) dv = 0.f;
        sdv[n] = dv;
    }
    __syncthreads();

    for (int e = tid; e < NN * NN; e += 256) {
        int n = e / NN, m = e - n * NN;
        sA[e] *= sdv[n] * sdv[m];
    }
    __syncthreads();

    for (int e = tid; e < NN * C2; e += 256) {
        int n = e / C2, o = e - n * C2;
        float acc = 0.f;
        #pragma unroll
        for (int d = 0; d < C3; ++d) acc += sfe[n * C3 + d] * sg1[d * C2 + o];
        sfc[e] = acc * sidx[n] + sg1b[o];
    }
    __syncthreads();

    for (int e = tid; e < NN * C2; e += 256) {
        int n = e / C2, o = e - n * C2;
        float acc = 0.f;
        for (int m = 0; m < NN; ++m) acc += sA[n * NN + m] * sfc[m * C2 + o];
        sfe[e] = elu_f(acc);
    }
    __syncthreads();

    for (int e = tid; e < NN * C1; e += 256) {
        int n = e / C1, c = e - n * C1;
        float acc = sg2b[c];
        #pragma unroll
        for (int o = 0; o < C2; ++o) acc += sfe[n * C2 + o] * sg2[o * C1 + c];
        sfc[NN * C2 + e] = acc;
    }
    __syncthreads();

    for (int e = tid; e < NN * C1; e += 256) {
        int n = e / C1, c = e - n * C1;
        float acc = 0.f;
        for (int m = 0; m < NN; ++m) acc += sA[n * NN + m] * sfc[NN * C2 + m * C1 + c];
        sfe[NN * C2 + e] = elu_f(acc);
    }
    __syncthreads();

    if (tid < C1) {
        const int c = tid;
        float pmax = -INFINITY, rmin = INFINITY, s = 0.f;
        for (int n = 0; n < NN; ++n) {
            float v = sfe[NN * C2 + n * C1 + c];
            pmax = fmaxf(pmax, v);
            rmin = fminf(rmin, 1.f / v);
            s += v;
        }
        float nmax = 1.f / rmin;
        sfeat[c] = (pmax == 0.f) ? nmax : pmax;
        sfeat[C1 + c] = s;
    }
    __syncthreads();

    if (tid == 0) {
        float l0 = sdb[0], l1 = sdb[1];
        #pragma unroll
        for (int j = 0; j < 10; ++j) {
            l0 += sfeat[j] * sdw[j * 2 + 0];
            l1 += sfeat[j] * sdw[j * 2 + 1];
        }
        float mx = fmaxf(l0, l1);
        float e0 = expf(l0 - mx), e1 = expf(l1 - mx);
        float s = e0 + e1;
        out[b * 2 + 0] = e0 / s;
        out[b * 2 + 1] = e1 / s;
    }
}

extern "C" void kernel_launch(void* const* d_in, const int* in_sizes, int n_in,
                              void* d_out, int out_size, void* d_ws, size_t ws_size,
                              hipStream_t stream) {
    const float* x       = (const float*)d_in[0];
    const float* conv1_w = (const float*)d_in[1];
    const float* conv1_b = (const float*)d_in[2];
    const float* ln1_g   = (const float*)d_in[3];
    const float* ln1_b   = (const float*)d_in[4];
    const float* conv2_w = (const float*)d_in[5];
    const float* conv2_b = (const float*)d_in[6];
    const float* ln2_g   = (const float*)d_in[7];
    const float* ln2_b   = (const float*)d_in[8];
    const float* conv3_w = (const float*)d_in[9];
    const float* conv3_b = (const float*)d_in[10];
    const float* ln3_g   = (const float*)d_in[11];
    const float* ln3_b   = (const float*)d_in[12];
    const float* agent_w = (const float*)d_in[13];
    const float* agent_b = (const float*)d_in[14];
    const float* gconv1_w= (const float*)d_in[15];
    const float* gconv1_b= (const float*)d_in[16];
    const float* gconv2_w= (const float*)d_in[17];
    const float* gconv2_b= (const float*)d_in[18];
    const float* dense_w = (const float*)d_in[19];
    const float* dense_b = (const float*)d_in[20];
    const int*   rl      = (const int*)d_in[21];
    float* out = (float*)d_out;

    const int B = in_sizes[0] / (NH * WIN);
    const int nrows = B * NH;
    float* feats = (float*)d_ws;

    dim3 block(256);
    dim3 grid1((nrows + RPB - 1) / RPB);
    hipLaunchKernelGGL(conv_rows_kernel, grid1, block, 0, stream,
                       x, conv1_w, conv1_b, ln1_g, ln1_b,
                       conv2_w, conv2_b, ln2_g, ln2_b,
                       conv3_w, conv3_b, ln3_g, ln3_b,
                       feats, nrows);

    dim3 grid2(B);
    hipLaunchKernelGGL(graph_kernel, grid2, block, 0, stream,
                       feats, agent_w, agent_b,
                       gconv1_w, gconv1_b, gconv2_w, gconv2_b,
                       dense_w, dense_b, rl, out);
}

// Round 6
// 391.226 us; speedup vs baseline: 2.1997x; 1.1604x over previous
//
#include <hip/hip_runtime.h>
#include <math.h>

#define NH    114
#define WIN   130
#define WO1   66
#define WO2   37
#define C1    5
#define C2    10
#define C3    20
#define K1    65
#define K2    30
#define K3    37
#define NN    114
#define RPB   16     // rows per block = 4 waves x 4-row quads

typedef float f32x4 __attribute__((ext_vector_type(4)));
typedef _Float16 f16x8 __attribute__((ext_vector_type(8)));

#define S1H_STRIDE 552   // f16 per row (16B-aligned stride, 2-way-bank-safe)
#define W2H_STRIDE 264   // f16 per och row

__device__ __forceinline__ f32x4 splat4(float s) { f32x4 r; r.x = s; r.y = s; r.z = s; r.w = s; return r; }
__device__ __forceinline__ f32x4 pkfma(f32x4 a, float w, f32x4 c) {
    return __builtin_elementwise_fma(a, splat4(w), c);
}
__device__ __forceinline__ f32x4 pkfma4(f32x4 a, f32x4 b, f32x4 c) {
    return __builtin_elementwise_fma(a, b, c);
}
// branchless fast ELU: exact identity for x>=0 (expf(0)==1)
__device__ __forceinline__ float elu_f(float v) { return fmaxf(v, 0.f) + __expf(fminf(v, 0.f)) - 1.f; }
__device__ __forceinline__ f32x4 elu4(f32x4 v) {
    f32x4 r;
    r.x = elu_f(v.x); r.y = elu_f(v.y); r.z = elu_f(v.z); r.w = elu_f(v.w);
    return r;
}
__device__ __forceinline__ f32x4 rsqrt4(f32x4 v) {
    f32x4 r; r.x = rsqrtf(v.x); r.y = rsqrtf(v.y); r.z = rsqrtf(v.z); r.w = rsqrtf(v.w);
    return r;
}
__device__ __forceinline__ void lds_fence() {
    asm volatile("s_waitcnt lgkmcnt(0)" ::: "memory");
}

// LDS layout in f32x4 quads (total 3120 quads = 49,920 B):
//   [0    .. 1104): s1h  = 16 rows x 552 f16        (conv1 out, [row][p*8+c], zero-padded)
//   [1104 .. 1632): w2h  = 16 och x 264 f16         (conv2 weights; phase-3: spart/st alias)
//   [1632 .. 3120): s2q  = 4 quads x 372 f32x4      (conv2 out; phase-0/1: sx alias 4x132)
#define SMEMQ   3120
#define W2HQ    1104
#define S2Q     1632

__global__ __launch_bounds__(256, 3) void conv_rows_kernel(
    const float* __restrict__ x,
    const float* __restrict__ w1, const float* __restrict__ b1,
    const float* __restrict__ g1, const float* __restrict__ be1,
    const float* __restrict__ w2, const float* __restrict__ b2,
    const float* __restrict__ g2, const float* __restrict__ be2,
    const float* __restrict__ w3, const float* __restrict__ b3,
    const float* __restrict__ g3, const float* __restrict__ be3,
    float* __restrict__ feats, int nrows)
{
    __shared__ f32x4 smem[SMEMQ];

    const int tid  = threadIdx.x;
    const int wave = tid >> 6;
    const int lane = tid & 63;
    const int prow = blockIdx.x * RPB + wave * 4;

    _Float16* const s1h = (_Float16*)smem;               // [row*552 + p*8 + c]
    _Float16* const w2h = (_Float16*)(smem + W2HQ);      // [n*264 + k]
    f32x4* const s2q    = smem + S2Q;                    // [g*372 + j]
    f32x4* const sxv    = smem + S2Q + wave * 132;       // conv1 input (aliases s2q)
    f32x4* const spart  = smem + W2HQ + wave * 80;       // conv3 partials (aliases w2h)
    f32x4* const st     = spart + 60;

    const int och  = lane & 15;
    const int grp  = lane >> 4;
    const bool ok10 = och < 10;
    const int oc9  = ok10 ? och : 9;
    const float b2v = b2[oc9], g2v = g2[oc9], be2v = be2[oc9];

    // ---- phase 0a: zero s1h + w2h regions ----
    for (int i = tid; i < S2Q; i += 256) smem[i] = splat4(0.f);
    __syncthreads();

    // ---- phase 0b: fill w2h (f16, [och][tap*8+c]) + stage x rows ----
    for (int i = tid; i < K2 * C1 * C2; i += 256) {
        int tap = i / 50, rem = i - tap * 50;
        int c = rem / 10, n = rem - c * 10;
        w2h[n * W2H_STRIDE + tap * 8 + c] = (_Float16)w2[i];
    }
    {
        float* sxf = (float*)(smem + S2Q);
        const size_t gbase = (size_t)blockIdx.x * RPB * WIN;
        const size_t gmax  = (size_t)nrows * WIN - 1;
        #pragma unroll
        for (int j = 0; j < 9; ++j) {
            int f = tid + j * 256;
            if (f < RPB * WIN) {
                size_t gi = gbase + (size_t)f;
                float v = x[gi < gmax ? gi : gmax];
                int r = f / WIN, w = f - r * WIN;
                sxf[((r >> 2) * 132 + w) * 4 + (r & 3)] = v;
            }
        }
    }
    __syncthreads();

    // ---- phase 1: conv1 + LN1 + ELU -> s1h (f16) ----
    {
        const int p = lane;
        f32x4 acc[C1];
        #pragma unroll
        for (int c = 0; c < C1; ++c) acc[c] = splat4(b1[c]);
        #pragma unroll
        for (int k = 0; k < K1; ++k) {
            f32x4 xv = sxv[p + k];
            #pragma unroll
            for (int c = 0; c < C1; ++c) acc[c] = pkfma(xv, w1[k * C1 + c], acc[c]);
        }
        f32x4 m = splat4(0.f);
        #pragma unroll
        for (int c = 0; c < C1; ++c) m += acc[c];
        m *= 0.2f;
        f32x4 v = splat4(0.f);
        #pragma unroll
        for (int c = 0; c < C1; ++c) { f32x4 d = acc[c] - m; v = pkfma4(d, d, v); }
        f32x4 inv = rsqrt4(v * 0.2f + 1e-3f);
        #pragma unroll
        for (int c = 0; c < C1; ++c) {
            f32x4 o = elu4((acc[c] - m) * inv * g1[c] + be1[c]);
            _Float16* dst = &s1h[(4 * wave) * S1H_STRIDE + p * 8 + c];
            dst[0]              = (_Float16)o.x;
            dst[S1H_STRIDE]     = (_Float16)o.y;
            dst[2 * S1H_STRIDE] = (_Float16)o.z;
            dst[3 * S1H_STRIDE] = (_Float16)o.w;
        }
    }
    // conv1 leftover positions 64,65 (all lanes compute, lanes 0..7 store)
    if (wave == 0) {
        const int pr = (lane >> 1) & 3;
        const int pp = 64 + (lane & 1);
        const f32x4* sxo = smem + S2Q + pr * 132;
        f32x4 acc[C1];
        #pragma unroll
        for (int c = 0; c < C1; ++c) acc[c] = splat4(b1[c]);
        #pragma unroll
        for (int k = 0; k < K1; ++k) {
            f32x4 xv = sxo[pp + k];
            #pragma unroll
            for (int c = 0; c < C1; ++c) acc[c] = pkfma(xv, w1[k * C1 + c], acc[c]);
        }
        f32x4 m = splat4(0.f);
        #pragma unroll
        for (int c = 0; c < C1; ++c) m += acc[c];
        m *= 0.2f;
        f32x4 v = splat4(0.f);
        #pragma unroll
        for (int c = 0; c < C1; ++c) { f32x4 d = acc[c] - m; v = pkfma4(d, d, v); }
        f32x4 inv = rsqrt4(v * 0.2f + 1e-3f);
        if (lane < 8) {
            #pragma unroll
            for (int c = 0; c < C1; ++c) {
                f32x4 o = elu4((acc[c] - m) * inv * g1[c] + be1[c]);
                _Float16* dst = &s1h[(4 * pr) * S1H_STRIDE + pp * 8 + c];
                dst[0]              = (_Float16)o.x;
                dst[S1H_STRIDE]     = (_Float16)o.y;
                dst[2 * S1H_STRIDE] = (_Float16)o.z;
                dst[3 * S1H_STRIDE] = (_Float16)o.w;
            }
        }
    }
    __syncthreads();

    // ---- phase 2: conv2 via MFMA f16 + LN2 + ELU -> s2q ----
    {
        if (lane < 2) s2q[wave * 372 + 370 + lane] = splat4(0.f);  // conv3 tail pad

        // B-fragments: w2h[n = och][k = ks*32 + grp*8 + j], 8 K-steps preloaded
        f16x8 bfr0 = *(const f16x8*)&w2h[och * W2H_STRIDE +   0 + grp * 8];
        f16x8 bfr1 = *(const f16x8*)&w2h[och * W2H_STRIDE +  32 + grp * 8];
        f16x8 bfr2 = *(const f16x8*)&w2h[och * W2H_STRIDE +  64 + grp * 8];
        f16x8 bfr3 = *(const f16x8*)&w2h[och * W2H_STRIDE +  96 + grp * 8];
        f16x8 bfr4 = *(const f16x8*)&w2h[och * W2H_STRIDE + 128 + grp * 8];
        f16x8 bfr5 = *(const f16x8*)&w2h[och * W2H_STRIDE + 160 + grp * 8];
        f16x8 bfr6 = *(const f16x8*)&w2h[och * W2H_STRIDE + 192 + grp * 8];
        f16x8 bfr7 = *(const f16x8*)&w2h[och * W2H_STRIDE + 224 + grp * 8];

        const int abase = och * S1H_STRIDE + grp * 8;   // A row = och-field (l&15), k-slice = grp

        for (int p = wave; p < WO2; p += 4) {
            const _Float16* ap = &s1h[abase + p * 8];
            f32x4 acc = splat4(0.f);
            acc = __builtin_amdgcn_mfma_f32_16x16x32_f16(*(const f16x8*)(ap +   0), bfr0, acc, 0, 0, 0);
            acc = __builtin_amdgcn_mfma_f32_16x16x32_f16(*(const f16x8*)(ap +  32), bfr1, acc, 0, 0, 0);
            acc = __builtin_amdgcn_mfma_f32_16x16x32_f16(*(const f16x8*)(ap +  64), bfr2, acc, 0, 0, 0);
            acc = __builtin_amdgcn_mfma_f32_16x16x32_f16(*(const f16x8*)(ap +  96), bfr3, acc, 0, 0, 0);
            acc = __builtin_amdgcn_mfma_f32_16x16x32_f16(*(const f16x8*)(ap + 128), bfr4, acc, 0, 0, 0);
            acc = __builtin_amdgcn_mfma_f32_16x16x32_f16(*(const f16x8*)(ap + 160), bfr5, acc, 0, 0, 0);
            acc = __builtin_amdgcn_mfma_f32_16x16x32_f16(*(const f16x8*)(ap + 192), bfr6, acc, 0, 0, 0);
            acc = __builtin_amdgcn_mfma_f32_16x16x32_f16(*(const f16x8*)(ap + 224), bfr7, acc, 0, 0, 0);

            // C layout: col (=och) = lane&15, row = grp*4 + i  -> rows are quad 'grp' components
            float v0 = ok10 ? acc.x + b2v : 0.f;
            float v1 = ok10 ? acc.y + b2v : 0.f;
            float v2 = ok10 ? acc.z + b2v : 0.f;
            float v3 = ok10 ? acc.w + b2v : 0.f;

            float s0 = v0; s0 += __shfl_xor(s0, 1); s0 += __shfl_xor(s0, 2); s0 += __shfl_xor(s0, 4); s0 += __shfl_xor(s0, 8);
            float s1_ = v1; s1_ += __shfl_xor(s1_, 1); s1_ += __shfl_xor(s1_, 2); s1_ += __shfl_xor(s1_, 4); s1_ += __shfl_xor(s1_, 8);
            float s2_ = v2; s2_ += __shfl_xor(s2_, 1); s2_ += __shfl_xor(s2_, 2); s2_ += __shfl_xor(s2_, 4); s2_ += __shfl_xor(s2_, 8);
            float s3 = v3; s3 += __shfl_xor(s3, 1); s3 += __shfl_xor(s3, 2); s3 += __shfl_xor(s3, 4); s3 += __shfl_xor(s3, 8);
            float m0 = s0 * 0.1f, m1 = s1_ * 0.1f, m2 = s2_ * 0.1f, m3 = s3 * 0.1f;

            float d0 = ok10 ? v0 - m0 : 0.f;
            float d1 = ok10 ? v1 - m1 : 0.f;
            float d2 = ok10 ? v2 - m2 : 0.f;
            float d3 = ok10 ? v3 - m3 : 0.f;

            float q0 = d0 * d0; q0 += __shfl_xor(q0, 1); q0 += __shfl_xor(q0, 2); q0 += __shfl_xor(q0, 4); q0 += __shfl_xor(q0, 8);
            float q1 = d1 * d1; q1 += __shfl_xor(q1, 1); q1 += __shfl_xor(q1, 2); q1 += __shfl_xor(q1, 4); q1 += __shfl_xor(q1, 8);
            float q2 = d2 * d2; q2 += __shfl_xor(q2, 1); q2 += __shfl_xor(q2, 2); q2 += __shfl_xor(q2, 4); q2 += __shfl_xor(q2, 8);
            float q3 = d3 * d3; q3 += __shfl_xor(q3, 1); q3 += __shfl_xor(q3, 2); q3 += __shfl_xor(q3, 4); q3 += __shfl_xor(q3, 8);

            float i0 = rsqrtf(q0 * 0.1f + 1e-3f);
            float i1 = rsqrtf(q1 * 0.1f + 1e-3f);
            float i2 = rsqrtf(q2 * 0.1f + 1e-3f);
            float i3 = rsqrtf(q3 * 0.1f + 1e-3f);

            if (ok10) {
                f32x4 ov;
                ov.x = elu_f(d0 * i0 * g2v + be2v);
                ov.y = elu_f(d1 * i1 * g2v + be2v);
                ov.z = elu_f(d2 * i2 * g2v + be2v);
                ov.w = elu_f(d3 * i3 * g2v + be2v);
                s2q[grp * 372 + p * C2 + och] = ov;
            }
        }
    }
    __syncthreads();

    // ---- phase 3: conv3 (f32) + LN3 + ELU -> feats ----
    {
        const f32x4* s2 = s2q + wave * 372;
        const int l2 = lane < 60 ? lane : 59;
        const int g  = l2 / 20;
        const int c  = l2 - g * 20;
        const int jb = g * 124;
        f32x4 acc = splat4(0.f);
        #pragma unroll 4
        for (int t = 0; t < 124; ++t) {
            int j  = jb + t;
            int jw = j < K3 * C2 ? j : K3 * C2 - 1;   // padded s2[j]==0 kills tail terms
            acc = pkfma(s2[j], w3[jw * C3 + c], acc);
        }
        if (lane < 60) spart[g * 20 + c] = acc;
    }
    lds_fence();

    if (lane < C3)
        st[lane] = spart[lane] + spart[20 + lane] + spart[40 + lane] + splat4(b3[lane]);
    lds_fence();

    if (lane < C3) {
        f32x4 myv = st[lane];
        f32x4 sum = splat4(0.f), sq = splat4(0.f);
        #pragma unroll
        for (int q = 0; q < C3; ++q) {
            f32x4 t = st[q];
            sum += t;
            sq = pkfma4(t, t, sq);
        }
        f32x4 m   = sum * (1.f / C3);
        f32x4 var = sq * (1.f / C3) - m * m;
        f32x4 inv = rsqrt4(var + 1e-3f);
        f32x4 o   = elu4((myv - m) * inv * g3[lane] + be3[lane]);
        if (prow + 0 < nrows) feats[(size_t)(prow + 0) * C3 + lane] = o.x;
        if (prow + 1 < nrows) feats[(size_t)(prow + 1) * C3 + lane] = o.y;
        if (prow + 2 < nrows) feats[(size_t)(prow + 2) * C3 + lane] = o.z;
        if (prow + 3 < nrows) feats[(size_t)(prow + 3) * C3 + lane] = o.w;
    }
}

// ---------------- Kernel 2: per-batch graph block ----------------
__global__ __launch_bounds__(256) void graph_kernel(
    const float* __restrict__ feats,
    const float* __restrict__ agent_w, const float* __restrict__ agent_b,
    const float* __restrict__ g1w, const float* __restrict__ g1b,
    const float* __restrict__ g2w, const float* __restrict__ g2b,
    const float* __restrict__ dw, const float* __restrict__ db,
    const int* __restrict__ rlp,
    float* __restrict__ out)
{
    __shared__ float sfe[NN * C3];
    __shared__ float sfc[NN * C3];
    __shared__ float sA[NN * NN];
    __shared__ float snrm[NN], sidx[NN], sdv[NN];
    __shared__ float red[256];
    __shared__ float ssigma;
    __shared__ float sfeat[10];
    __shared__ float sg1[C3 * C2], sg1b[C2], sg2[C2 * C1], sg2b[C1], sdw[20], sdb[2];

    const int tid = threadIdx.x;
    const int b = blockIdx.x;
    const float* F = feats + (size_t)b * (NN * C3);
    const int rl = rlp[0];

    if (tid < C3 * C2) sg1[tid] = g1w[tid];
    if (tid < C2) sg1b[tid] = g1b[tid];
    if (tid < C2 * C1) sg2[tid] = g2w[tid];
    if (tid < C1) sg2b[tid] = g2b[tid];
    if (tid < 20) sdw[tid] = dw[tid];
    if (tid < 2) sdb[tid] = db[tid];

    for (int n = tid; n < NN; n += 256) {
        float f[C3];
        float m = 0.f;
        #pragma unroll
        for (int d = 0; d < C3; ++d) { f[d] = F[n * C3 + d]; m += f[d]; }
        m *= (1.f / C3);
        float nr = 0.f, ag = 0.f;
        #pragma unroll
        for (int d = 0; d < C3; ++d) {
            sfe[n * C3 + d] = f[d];
            float c = f[d] - m;
            sfc[n * C3 + d] = c;
            nr += c * c;
            ag += f[d] * agent_w[d];
        }
        snrm[n] = sqrtf(nr);
        sidx[n] = rl ? (1.f / (1.f + __expf(-(ag + agent_b[0])))) : 1.f;
    }
    __syncthreads();

    float psum = 0.f;
    for (int e = tid; e < NN * NN; e += 256) {
        int n = e / NN, m = e - n * NN;
        float dot = 0.f;
        #pragma unroll
        for (int d = 0; d < C3; ++d) dot += sfc[n * C3 + d] * sfc[m * C3 + d];
        float corr = dot / (snrm[n] * snrm[m]);
        float dist = (n == m) ? 0.f : (1.f - corr);
        sA[e] = dist;
        psum += dist;
    }
    red[tid] = psum;
    __syncthreads();
    for (int s = 128; s > 0; s >>= 1) {
        if (tid < s) red[tid] += red[tid + s];
        __syncthreads();
    }
    if (tid == 0) ssigma = red[0] / (float)(NN * NN);
    __syncthreads();

    const float sig = ssigma;
    const float inv2s2 = 1.f / (2.f * sig * sig);
    for (int e = tid; e < NN * NN; e += 256) {
        int n = e / NN, m = e - n * NN;
        float dist = sA[e];
        sA[e] = sidx[n] * sidx[m] * __expf(-dist * dist * inv2s2);
    }
    __syncthreads();

    for (int n = tid; n < NN; n += 256) {
        float s = 0.f;
        for (int m = 0; m < NN; ++m) s += sA[n * NN + m];
        float dv = rsqrtf(s);
        if (isinf(dv)) dv = 0.f;
        sdv[n] = dv;
    }
    __syncthreads();

    for (int e = tid; e < NN * NN; e += 256) {
        int n = e / NN, m = e - n * NN;
        sA[e] *= sdv[n] * sdv[m];
    }
    __syncthreads();

    for (int e = tid; e < NN * C2; e += 256) {
        int n = e / C2, o = e - n * C2;
        float acc = 0.f;
        #pragma unroll
        for (int d = 0; d < C3; ++d) acc += sfe[n * C3 + d] * sg1[d * C2 + o];
        sfc[e] = acc * sidx[n] + sg1b[o];
    }
    __syncthreads();

    for (int e = tid; e < NN * C2; e += 256) {
        int n = e / C2, o = e - n * C2;
        float acc = 0.f;
        for (int m = 0; m < NN; ++m) acc += sA[n * NN + m] * sfc[m * C2 + o];
        sfe[e] = elu_f(acc);
    }
    __syncthreads();

    for (int e = tid; e < NN * C1; e += 256) {
        int n = e / C1, c = e - n * C1;
        float acc = sg2b[c];
        #pragma unroll
        for (int o = 0; o < C2; ++o) acc += sfe[n * C2 + o] * sg2[o * C1 + c];
        sfc[NN * C2 + e] = acc;
    }
    __syncthreads();

    for (int e = tid; e < NN * C1; e += 256) {
        int n = e / C1, c = e - n * C1;
        float acc = 0.f;
        for (int m = 0; m < NN; ++m) acc += sA[n * NN + m] * sfc[NN * C2 + m * C1 + c];
        sfe[NN * C2 + e] = elu_f(acc);
    }
    __syncthreads();

    if (tid < C1) {
        const int c = tid;
        float pmax = -INFINITY, rmin = INFINITY, s = 0.f;
        for (int n = 0; n < NN; ++n) {
            float v = sfe[NN * C2 + n * C1 + c];
            pmax = fmaxf(pmax, v);
            rmin = fminf(rmin, 1.f / v);
            s += v;
        }
        float nmax = 1.f / rmin;
        sfeat[c] = (pmax == 0.f) ? nmax : pmax;
        sfeat[C1 + c] = s;
    }
    __syncthreads();

    if (tid == 0) {
        float l0 = sdb[0], l1 = sdb[1];
        #pragma unroll
        for (int j = 0; j < 10; ++j) {
            l0 += sfeat[j] * sdw[j * 2 + 0];
            l1 += sfeat[j] * sdw[j * 2 + 1];
        }
        float mx = fmaxf(l0, l1);
        float e0 = expf(l0 - mx), e1 = expf(l1 - mx);
        float s = e0 + e1;
        out[b * 2 + 0] = e0 / s;
        out[b * 2 + 1] = e1 / s;
    }
}

extern "C" void kernel_launch(void* const* d_in, const int* in_sizes, int n_in,
                              void* d_out, int out_size, void* d_ws, size_t ws_size,
                              hipStream_t stream) {
    const float* x       = (const float*)d_in[0];
    const float* conv1_w = (const float*)d_in[1];
    const float* conv1_b = (const float*)d_in[2];
    const float* ln1_g   = (const float*)d_in[3];
    const float* ln1_b   = (const float*)d_in[4];
    const float* conv2_w = (const float*)d_in[5];
    const float* conv2_b = (const float*)d_in[6];
    const float* ln2_g   = (const float*)d_in[7];
    const float* ln2_b   = (const float*)d_in[8];
    const float* conv3_w = (const float*)d_in[9];
    const float* conv3_b = (const float*)d_in[10];
    const float* ln3_g   = (const float*)d_in[11];
    const float* ln3_b   = (const float*)d_in[12];
    const float* agent_w = (const float*)d_in[13];
    const float* agent_b = (const float*)d_in[14];
    const float* gconv1_w= (const float*)d_in[15];
    const float* gconv1_b= (const float*)d_in[16];
    const float* gconv2_w= (const float*)d_in[17];
    const float* gconv2_b= (const float*)d_in[18];
    const float* dense_w = (const float*)d_in[19];
    const float* dense_b = (const float*)d_in[20];
    const int*   rl      = (const int*)d_in[21];
    float* out = (float*)d_out;

    const int B = in_sizes[0] / (NH * WIN);
    const int nrows = B * NH;
    float* feats = (float*)d_ws;

    dim3 block(256);
    dim3 grid1((nrows + RPB - 1) / RPB);
    hipLaunchKernelGGL(conv_rows_kernel, grid1, block, 0, stream,
                       x, conv1_w, conv1_b, ln1_g, ln1_b,
                       conv2_w, conv2_b, ln2_g, ln2_b,
                       conv3_w, conv3_b, ln3_g, ln3_b,
                       feats, nrows);

    dim3 grid2(B);
    hipLaunchKernelGGL(graph_kernel, grid2, block, 0, stream,
                       feats, agent_w, agent_b,
                       gconv1_w, gconv1_b, gconv2_w, gconv2_b,
                       dense_w, dense_b, rl, out);
}

// Round 7
// 364.335 us; speedup vs baseline: 2.3621x; 1.0738x over previous
//
#include <hip/hip_runtime.h>
#include <math.h>

#define NH    114
#define WIN   130
#define WO1   66
#define WO2   37
#define C1    5
#define C2    10
#define C3    20
#define K1    65
#define K2    30
#define K3    37
#define NN    114
#define RPB   16     // rows per block = 4 waves x 4-row quads

typedef float f32x4 __attribute__((ext_vector_type(4)));
typedef _Float16 f16x8 __attribute__((ext_vector_type(8)));

#define S1H_STRIDE 552   // f16 per s1h row
#define W2H_STRIDE 264   // f16 per w2h och row
#define X16_STRIDE 168   // f16 per x16 row (130 real + zero pad)
#define WP_STRIDE  104   // f16 per toeplitz (och,delta) row (96 real + pad)

// LDS quad (16B) layout, total 3120 quads = 49,920 B:
//  A: [   0..1104): s1h 16x552 f16
//  B: [1104..1632): w2h 16x264 f16            | conv3: spart/st (320 quads)
//  C: [1632..3120): phase<=1: W' 5x16x104 f16 (1040 q) + x16 16x168 f16 (336 q @2672)
//                   phase>=2: s2q 4x372 f32x4
#define SMEMQ   3120
#define BQ      1104
#define CQ      1632
#define X16Q    2672

__device__ __forceinline__ f32x4 splat4(float s) { f32x4 r; r.x = s; r.y = s; r.z = s; r.w = s; return r; }
__device__ __forceinline__ f32x4 pkfma(f32x4 a, float w, f32x4 c) {
    return __builtin_elementwise_fma(a, splat4(w), c);
}
__device__ __forceinline__ f32x4 pkfma4(f32x4 a, f32x4 b, f32x4 c) {
    return __builtin_elementwise_fma(a, b, c);
}
__device__ __forceinline__ float elu_f(float v) { return fmaxf(v, 0.f) + __expf(fminf(v, 0.f)) - 1.f; }
__device__ __forceinline__ f32x4 elu4(f32x4 v) {
    f32x4 r;
    r.x = elu_f(v.x); r.y = elu_f(v.y); r.z = elu_f(v.z); r.w = elu_f(v.w);
    return r;
}
__device__ __forceinline__ f32x4 rsqrt4(f32x4 v) {
    f32x4 r; r.x = rsqrtf(v.x); r.y = rsqrtf(v.y); r.z = rsqrtf(v.z); r.w = rsqrtf(v.w);
    return r;
}
__device__ __forceinline__ void lds_fence() {
    asm volatile("s_waitcnt lgkmcnt(0)" ::: "memory");
}
__device__ __forceinline__ unsigned int pk2h(float a, float b) {
    union { _Float16 h[2]; unsigned int u; } v;
    v.h[0] = (_Float16)a; v.h[1] = (_Float16)b; return v.u;
}

__global__ __launch_bounds__(256, 3) void conv_rows_kernel(
    const float* __restrict__ x,
    const float* __restrict__ w1, const float* __restrict__ b1,
    const float* __restrict__ g1, const float* __restrict__ be1,
    const float* __restrict__ w2, const float* __restrict__ b2,
    const float* __restrict__ g2, const float* __restrict__ be2,
    const float* __restrict__ w3, const float* __restrict__ b3,
    const float* __restrict__ g3, const float* __restrict__ be3,
    float* __restrict__ feats, int nrows)
{
    __shared__ f32x4 smem[SMEMQ];

    const int tid  = threadIdx.x;
    const int wave = tid >> 6;
    const int lane = tid & 63;
    const int prow = blockIdx.x * RPB + wave * 4;

    _Float16* const s1h  = (_Float16*)smem;
    _Float16* const w2h  = (_Float16*)(smem + BQ);
    _Float16* const wph  = (_Float16*)(smem + CQ);
    _Float16* const x16h = (_Float16*)(smem + X16Q);
    float*    const s2qf = (float*)(smem + CQ);
    f32x4*    const spart = smem + BQ + wave * 80;   // conv3 phase (aliases w2h)
    f32x4*    const st    = spart + 60;

    const int dlt = lane & 15;      // B-col / A-row selector
    const int grp = lane >> 4;      // k-slice selector

    // ================= P0: stage x16 (f16), w2h (f16), W' toeplitz (f16) ===========
    {
        const int row0g = blockIdx.x * RPB;
        unsigned int* x16u = (unsigned int*)x16h;
        for (int q = tid; q < 16 * 84; q += 256) {          // x16: zero-padded pairs
            int r = q / 84, wp = q - r * 84;
            int gr = row0g + r; if (gr >= nrows) gr = nrows - 1;
            float a = 0.f, bb = 0.f;
            if (wp < 65) {
                const float* xp = x + (size_t)gr * WIN + 2 * wp;
                a = xp[0]; bb = xp[1];
            }
            x16u[r * 84 + wp] = pk2h(a, bb);
        }
        unsigned int* w2u = (unsigned int*)w2h;
        for (int q = tid; q < 16 * 132; q += 256) {         // w2h: [och][tap*8+c], pads zero
            int och = q / 132, up = q - och * 132;
            int u0 = 2 * up;
            float a = 0.f, bb = 0.f;
            {
                int tap = u0 >> 3, c = u0 & 7;
                if (och < 10 && c < 5 && tap < 30) a = w2[(tap * 5 + c) * 10 + och];
                int u1 = u0 + 1; tap = u1 >> 3; c = u1 & 7;
                if (och < 10 && c < 5 && tap < 30) bb = w2[(tap * 5 + c) * 10 + och];
            }
            w2u[och * 132 + up] = pk2h(a, bb);
        }
        unsigned int* wpu = (unsigned int*)wph;
        for (int q = tid; q < 5 * 16 * 52; q += 256) {      // W': [och][delta][u]
            int och = q / 832; int rem = q - och * 832;
            int dl = rem / 52; int up = rem - dl * 52;
            int u0 = 2 * up;
            int t0 = u0 - dl, t1 = u0 + 1 - dl;
            float a = (t0 >= 0 && t0 < K1) ? w1[t0 * C1 + och] : 0.f;
            float bb = (t1 >= 0 && t1 < K1) ? w1[t1 * C1 + och] : 0.f;
            wpu[(och * 16 + dl) * 52 + up] = pk2h(a, bb);
        }
        // zero s1h tail columns (528..551) so conv2 patch reads see zeros
        for (int q = tid; q < 16 * 12; q += 256) {
            int r = q / 12, wp = q - r * 12;
            ((unsigned int*)s1h)[r * 276 + 264 + wp] = 0u;
        }
    }
    __syncthreads();

    // ================= P1: conv1 via toeplitz MFMA + LN1 + ELU -> s1h ==============
    for (int g = wave; g < 5; g += 4) {
        const int p0 = g * 16;
        const _Float16* xb = x16h + dlt * X16_STRIDE + p0 + grp * 8;
        f16x8 a0 = *(const f16x8*)(xb);
        f16x8 a1 = *(const f16x8*)(xb + 32);
        f16x8 a2 = *(const f16x8*)(xb + 64);
        f32x4 o[C1];
        #pragma unroll
        for (int c = 0; c < C1; ++c) {
            const _Float16* wb = wph + (c * 16 + dlt) * WP_STRIDE + grp * 8;
            f32x4 t = splat4(0.f);
            t = __builtin_amdgcn_mfma_f32_16x16x32_f16(a0, *(const f16x8*)(wb),      t, 0, 0, 0);
            t = __builtin_amdgcn_mfma_f32_16x16x32_f16(a1, *(const f16x8*)(wb + 32), t, 0, 0, 0);
            t = __builtin_amdgcn_mfma_f32_16x16x32_f16(a2, *(const f16x8*)(wb + 64), t, 0, 0, 0);
            o[c] = t + splat4(b1[c]);
        }
        f32x4 m = splat4(0.f);
        #pragma unroll
        for (int c = 0; c < C1; ++c) m += o[c];
        m *= 0.2f;
        f32x4 v = splat4(0.f);
        #pragma unroll
        for (int c = 0; c < C1; ++c) { f32x4 d = o[c] - m; v = pkfma4(d, d, v); }
        f32x4 inv = rsqrt4(v * 0.2f + 1e-3f);
        f32x4 oo[C1];
        #pragma unroll
        for (int c = 0; c < C1; ++c) oo[c] = elu4((o[c] - m) * inv * g1[c] + be1[c]);
        const int p = p0 + dlt;
        if (p < WO1) {
            #pragma unroll
            for (int i = 0; i < 4; ++i) {
                const int row = grp * 4 + i;
                union { _Float16 h[8]; f16x8 v8; } pkv;
                pkv.h[0] = (_Float16)oo[0][i];
                pkv.h[1] = (_Float16)oo[1][i];
                pkv.h[2] = (_Float16)oo[2][i];
                pkv.h[3] = (_Float16)oo[3][i];
                pkv.h[4] = (_Float16)oo[4][i];
                pkv.h[5] = (_Float16)0.f;
                pkv.h[6] = (_Float16)0.f;
                pkv.h[7] = (_Float16)0.f;
                *(f16x8*)&s1h[row * S1H_STRIDE + p * 8] = pkv.v8;
            }
        }
    }
    __syncthreads();

    // ================= P2: conv2 MFMA (A=weights, B=patches) + LN2 -> s2q ==========
    {
        if (lane < 8) s2qf[(wave * 372 + 370) * 4 + lane] = 0.f;   // conv3 tail pad

        const _Float16* wbase = w2h + dlt * W2H_STRIDE + grp * 8;  // A: och = dlt
        f16x8 wf0 = *(const f16x8*)(wbase);
        f16x8 wf1 = *(const f16x8*)(wbase + 32);
        f16x8 wf2 = *(const f16x8*)(wbase + 64);
        f16x8 wf3 = *(const f16x8*)(wbase + 96);
        f16x8 wf4 = *(const f16x8*)(wbase + 128);
        f16x8 wf5 = *(const f16x8*)(wbase + 160);
        f16x8 wf6 = *(const f16x8*)(wbase + 192);
        f16x8 wf7 = *(const f16x8*)(wbase + 224);

        float b2r[4], g2r[4], be2r[4];
        bool  mk[4];
        #pragma unroll
        for (int i = 0; i < 4; ++i) {
            int oo = grp * 4 + i;
            mk[i] = oo < 10;
            int oc = mk[i] ? oo : 9;
            b2r[i] = b2[oc]; g2r[i] = g2[oc]; be2r[i] = be2[oc];
        }
        const int r  = lane & 3;
        const int pr = (lane >> 2) & 3;
        const _Float16* pbase = s1h + (4 * wave + r) * S1H_STRIDE + grp * 8;
        float* s2w = s2qf + (wave * 372) * 4 + r;

        for (int g = 0; g < 10; ++g) {
            const int p  = g * 4 + pr;
            const int p2 = min(p, WO2 - 1);
            const _Float16* pb = pbase + p2 * 8;
            f32x4 aA = splat4(0.f), aB = splat4(0.f);
            aA = __builtin_amdgcn_mfma_f32_16x16x32_f16(wf0, *(const f16x8*)(pb),       aA, 0, 0, 0);
            aA = __builtin_amdgcn_mfma_f32_16x16x32_f16(wf1, *(const f16x8*)(pb +  32), aA, 0, 0, 0);
            aA = __builtin_amdgcn_mfma_f32_16x16x32_f16(wf2, *(const f16x8*)(pb +  64), aA, 0, 0, 0);
            aA = __builtin_amdgcn_mfma_f32_16x16x32_f16(wf3, *(const f16x8*)(pb +  96), aA, 0, 0, 0);
            aB = __builtin_amdgcn_mfma_f32_16x16x32_f16(wf4, *(const f16x8*)(pb + 128), aB, 0, 0, 0);
            aB = __builtin_amdgcn_mfma_f32_16x16x32_f16(wf5, *(const f16x8*)(pb + 160), aB, 0, 0, 0);
            aB = __builtin_amdgcn_mfma_f32_16x16x32_f16(wf6, *(const f16x8*)(pb + 192), aB, 0, 0, 0);
            aB = __builtin_amdgcn_mfma_f32_16x16x32_f16(wf7, *(const f16x8*)(pb + 224), aB, 0, 0, 0);
            f32x4 acc = aA + aB;

            float v0 = acc.x + b2r[0], v1 = acc.y + b2r[1];
            float v2 = acc.z + b2r[2], v3 = acc.w + b2r[3];
            float sp = (mk[0] ? v0 : 0.f) + (mk[1] ? v1 : 0.f)
                     + (mk[2] ? v2 : 0.f) + (mk[3] ? v3 : 0.f);
            sp += __shfl_xor(sp, 16);
            sp += __shfl_xor(sp, 32);
            const float mean = sp * 0.1f;
            float d0 = v0 - mean, d1 = v1 - mean, d2 = v2 - mean, d3 = v3 - mean;
            float sq = (mk[0] ? d0 * d0 : 0.f) + (mk[1] ? d1 * d1 : 0.f)
                     + (mk[2] ? d2 * d2 : 0.f) + (mk[3] ? d3 * d3 : 0.f);
            sq += __shfl_xor(sq, 16);
            sq += __shfl_xor(sq, 32);
            const float inv = rsqrtf(sq * 0.1f + 1e-3f);

            if (p < WO2) {
                float* dst = s2w + p * 40;   // (p*10+och)*4 words
                if (mk[0]) dst[(grp * 4 + 0) * 4] = elu_f(d0 * inv * g2r[0] + be2r[0]);
                if (mk[1]) dst[(grp * 4 + 1) * 4] = elu_f(d1 * inv * g2r[1] + be2r[1]);
                if (mk[2]) dst[(grp * 4 + 2) * 4] = elu_f(d2 * inv * g2r[2] + be2r[2]);
                if (mk[3]) dst[(grp * 4 + 3) * 4] = elu_f(d3 * inv * g2r[3] + be2r[3]);
            }
        }
    }
    __syncthreads();

    // ================= P3: conv3 (f32) + LN3 + ELU -> feats ========================
    {
        const f32x4* s2 = smem + CQ + wave * 372;
        const int l2 = lane < 60 ? lane : 59;
        const int g  = l2 / 20;
        const int c  = l2 - g * 20;
        const int jb = g * 124;
        f32x4 acc = splat4(0.f);
        #pragma unroll 4
        for (int t = 0; t < 124; ++t) {
            int j  = jb + t;
            int jw = j < K3 * C2 ? j : K3 * C2 - 1;   // padded s2[j]==0 kills tail terms
            acc = pkfma(s2[j], w3[jw * C3 + c], acc);
        }
        if (lane < 60) spart[g * 20 + c] = acc;
    }
    lds_fence();

    if (lane < C3)
        st[lane] = spart[lane] + spart[20 + lane] + spart[40 + lane] + splat4(b3[lane]);
    lds_fence();

    if (lane < C3) {
        f32x4 myv = st[lane];
        f32x4 sum = splat4(0.f), sq = splat4(0.f);
        #pragma unroll
        for (int q = 0; q < C3; ++q) {
            f32x4 t = st[q];
            sum += t;
            sq = pkfma4(t, t, sq);
        }
        f32x4 m   = sum * (1.f / C3);
        f32x4 var = sq * (1.f / C3) - m * m;
        f32x4 inv = rsqrt4(var + 1e-3f);
        f32x4 o   = elu4((myv - m) * inv * g3[lane] + be3[lane]);
        if (prow + 0 < nrows) feats[(size_t)(prow + 0) * C3 + lane] = o.x;
        if (prow + 1 < nrows) feats[(size_t)(prow + 1) * C3 + lane] = o.y;
        if (prow + 2 < nrows) feats[(size_t)(prow + 2) * C3 + lane] = o.z;
        if (prow + 3 < nrows) feats[(size_t)(prow + 3) * C3 + lane] = o.w;
    }
}

// ---------------- Kernel 2: per-batch graph block ----------------
__global__ __launch_bounds__(256) void graph_kernel(
    const float* __restrict__ feats,
    const float* __restrict__ agent_w, const float* __restrict__ agent_b,
    const float* __restrict__ g1w, const float* __restrict__ g1b,
    const float* __restrict__ g2w, const float* __restrict__ g2b,
    const float* __restrict__ dw, const float* __restrict__ db,
    const int* __restrict__ rlp,
    float* __restrict__ out)
{
    __shared__ float sfe[NN * C3];
    __shared__ float sfc[NN * C3];
    __shared__ float sA[NN * NN];
    __shared__ float snrm[NN], sidx[NN], sdv[NN];
    __shared__ float red[256];
    __shared__ float ssigma;
    __shared__ float sfeat[10];
    __shared__ float sg1[C3 * C2], sg1b[C2], sg2[C2 * C1], sg2b[C1], sdw[20], sdb[2];

    const int tid = threadIdx.x;
    const int b = blockIdx.x;
    const float* F = feats + (size_t)b * (NN * C3);
    const int rl = rlp[0];

    if (tid < C3 * C2) sg1[tid] = g1w[tid];
    if (tid < C2) sg1b[tid] = g1b[tid];
    if (tid < C2 * C1) sg2[tid] = g2w[tid];
    if (tid < C1) sg2b[tid] = g2b[tid];
    if (tid < 20) sdw[tid] = dw[tid];
    if (tid < 2) sdb[tid] = db[tid];

    for (int n = tid; n < NN; n += 256) {
        float f[C3];
        float m = 0.f;
        #pragma unroll
        for (int d = 0; d < C3; ++d) { f[d] = F[n * C3 + d]; m += f[d]; }
        m *= (1.f / C3);
        float nr = 0.f, ag = 0.f;
        #pragma unroll
        for (int d = 0; d < C3; ++d) {
            sfe[n * C3 + d] = f[d];
            float c = f[d] - m;
            sfc[n * C3 + d] = c;
            nr += c * c;
            ag += f[d] * agent_w[d];
        }
        snrm[n] = sqrtf(nr);
        sidx[n] = rl ? (1.f / (1.f + __expf(-(ag + agent_b[0])))) : 1.f;
    }
    __syncthreads();

    float psum = 0.f;
    for (int e = tid; e < NN * NN; e += 256) {
        int n = e / NN, m = e - n * NN;
        float dot = 0.f;
        #pragma unroll
        for (int d = 0; d < C3; ++d) dot += sfc[n * C3 + d] * sfc[m * C3 + d];
        float corr = dot / (snrm[n] * snrm[m]);
        float dist = (n == m) ? 0.f : (1.f - corr);
        sA[e] = dist;
        psum += dist;
    }
    red[tid] = psum;
    __syncthreads();
    for (int s = 128; s > 0; s >>= 1) {
        if (tid < s) red[tid] += red[tid + s];
        __syncthreads();
    }
    if (tid == 0) ssigma = red[0] / (float)(NN * NN);
    __syncthreads();

    const float sig = ssigma;
    const float inv2s2 = 1.f / (2.f * sig * sig);
    for (int e = tid; e < NN * NN; e += 256) {
        int n = e / NN, m = e - n * NN;
        float dist = sA[e];
        sA[e] = sidx[n] * sidx[m] * __expf(-dist * dist * inv2s2);
    }
    __syncthreads();

    for (int n = tid; n < NN; n += 256) {
        float s = 0.f;
        for (int m = 0; m < NN; ++m) s += sA[n * NN + m];
        float dv = rsqrtf(s);
        if (isinf(dv)) dv = 0.f;
        sdv[n] = dv;
    }
    __syncthreads();

    for (int e = tid; e < NN * NN; e += 256) {
        int n = e / NN, m = e - n * NN;
        sA[e] *= sdv[n] * sdv[m];
    }
    __syncthreads();

    for (int e = tid; e < NN * C2; e += 256) {
        int n = e / C2, o = e - n * C2;
        float acc = 0.f;
        #pragma unroll
        for (int d = 0; d < C3; ++d) acc += sfe[n * C3 + d] * sg1[d * C2 + o];
        sfc[e] = acc * sidx[n] + sg1b[o];
    }
    __syncthreads();

    for (int e = tid; e < NN * C2; e += 256) {
        int n = e / C2, o = e - n * C2;
        float acc = 0.f;
        for (int m = 0; m < NN; ++m) acc += sA[n * NN + m] * sfc[m * C2 + o];
        sfe[e] = elu_f(acc);
    }
    __syncthreads();

    for (int e = tid; e < NN * C1; e += 256) {
        int n = e / C1, c = e - n * C1;
        float acc = sg2b[c];
        #pragma unroll
        for (int o = 0; o < C2; ++o) acc += sfe[n * C2 + o] * sg2[o * C1 + c];
        sfc[NN * C2 + e] = acc;
    }
    __syncthreads();

    for (int e = tid; e < NN * C1; e += 256) {
        int n = e / C1, c = e - n * C1;
        float acc = 0.f;
        for (int m = 0; m < NN; ++m) acc += sA[n * NN + m] * sfc[NN * C2 + m * C1 + c];
        sfe[NN * C2 + e] = elu_f(acc);
    }
    __syncthreads();

    if (tid < C1) {
        const int c = tid;
        float pmax = -INFINITY, rmin = INFINITY, s = 0.f;
        for (int n = 0; n < NN; ++n) {
            float v = sfe[NN * C2 + n * C1 + c];
            pmax = fmaxf(pmax, v);
            rmin = fminf(rmin, 1.f / v);
            s += v;
        }
        float nmax = 1.f / rmin;
        sfeat[c] = (pmax == 0.f) ? nmax : pmax;
        sfeat[C1 + c] = s;
    }
    __syncthreads();

    if (tid == 0) {
        float l0 = sdb[0], l1 = sdb[1];
        #pragma unroll
        for (int j = 0; j < 10; ++j) {
            l0 += sfeat[j] * sdw[j * 2 + 0];
            l1 += sfeat[j] * sdw[j * 2 + 1];
        }
        float mx = fmaxf(l0, l1);
        float e0 = expf(l0 - mx), e1 = expf(l1 - mx);
        float s = e0 + e1;
        out[b * 2 + 0] = e0 / s;
        out[b * 2 + 1] = e1 / s;
    }
}

extern "C" void kernel_launch(void* const* d_in, const int* in_sizes, int n_in,
                              void* d_out, int out_size, void* d_ws, size_t ws_size,
                              hipStream_t stream) {
    const float* x       = (const float*)d_in[0];
    const float* conv1_w = (const float*)d_in[1];
    const float* conv1_b = (const float*)d_in[2];
    const float* ln1_g   = (const float*)d_in[3];
    const float* ln1_b   = (const float*)d_in[4];
    const float* conv2_w = (const float*)d_in[5];
    const float* conv2_b = (const float*)d_in[6];
    const float* ln2_g   = (const float*)d_in[7];
    const float* ln2_b   = (const float*)d_in[8];
    const float* conv3_w = (const float*)d_in[9];
    const float* conv3_b = (const float*)d_in[10];
    const float* ln3_g   = (const float*)d_in[11];
    const float* ln3_b   = (const float*)d_in[12];
    const float* agent_w = (const float*)d_in[13];
    const float* agent_b = (const float*)d_in[14];
    const float* gconv1_w= (const float*)d_in[15];
    const float* gconv1_b= (const float*)d_in[16];
    const float* gconv2_w= (const float*)d_in[17];
    const float* gconv2_b= (const float*)d_in[18];
    const float* dense_w = (const float*)d_in[19];
    const float* dense_b = (const float*)d_in[20];
    const int*   rl      = (const int*)d_in[21];
    float* out = (float*)d_out;

    const int B = in_sizes[0] / (NH * WIN);
    const int nrows = B * NH;
    float* feats = (float*)d_ws;

    dim3 block(256);
    dim3 grid1((nrows + RPB - 1) / RPB);
    hipLaunchKernelGGL(conv_rows_kernel, grid1, block, 0, stream,
                       x, conv1_w, conv1_b, ln1_g, ln1_b,
                       conv2_w, conv2_b, ln2_g, ln2_b,
                       conv3_w, conv3_b, ln3_g, ln3_b,
                       feats, nrows);

    dim3 grid2(B);
    hipLaunchKernelGGL(graph_kernel, grid2, block, 0, stream,
                       feats, agent_w, agent_b,
                       gconv1_w, gconv1_b, gconv2_w, gconv2_b,
                       dense_w, dense_b, rl, out);
}

// Round 8
// 252.669 us; speedup vs baseline: 3.4060x; 1.4419x over previous
//
#include <hip/hip_runtime.h>
#include <math.h>

#define NH    114
#define WIN   130
#define WO1   66
#define WO2   37
#define C1    5
#define C2    10
#define C3    20
#define K1    65
#define K2    30
#define K3    37
#define NN    114
#define RPB   16     // rows per block = 4 waves; row-quads per wave

typedef float f32x4 __attribute__((ext_vector_type(4)));
typedef _Float16 f16x8 __attribute__((ext_vector_type(8)));

// ---- d_ws layout ----
// [0, 48384B): prepped f16 weights (halves):
//    w2h  [0,     4224): [och16][264]   (k = tap*8+c, pads 0)
//    wph  [4224, 11904): [(c*16+dlt)*96 + u]  toeplitz W'
//    w3t  [11904,24192): [oc32][384]    (w3 transposed, pads 0)
// [65536, ...): feats f32 [nrows][20]
#define WB_HALVES 24192
#define FEATS_OFF 65536

// ---- LDS layout (bytes), total 46592 ----
//  [0,     17664): s1h  16 x 552 f16
//  [17664, 26112): w2h  16 x 264 f16   (copied from global, lives whole kernel)
//  [26112, 41472): wph  5x16x96 f16 (P0-P1)  |  P2+: s2h 16x392 f16 [26112,38656) + scr [38656,41472)
//  [41472, 46592): x16h 16 x 160 f16
#define SMEM_BYTES 46592
#define S1H_STRIDE 552
#define W2H_STRIDE 264

__device__ __forceinline__ f32x4 splat4(float s) { f32x4 r; r.x = s; r.y = s; r.z = s; r.w = s; return r; }
__device__ __forceinline__ f32x4 pkfma4(f32x4 a, f32x4 b, f32x4 c) {
    return __builtin_elementwise_fma(a, b, c);
}
__device__ __forceinline__ float elu_f(float v) { return fmaxf(v, 0.f) + __expf(fminf(v, 0.f)) - 1.f; }
__device__ __forceinline__ f32x4 elu4(f32x4 v) {
    f32x4 r;
    r.x = elu_f(v.x); r.y = elu_f(v.y); r.z = elu_f(v.z); r.w = elu_f(v.w);
    return r;
}
__device__ __forceinline__ f32x4 rsqrt4(f32x4 v) {
    f32x4 r; r.x = rsqrtf(v.x); r.y = rsqrtf(v.y); r.z = rsqrtf(v.z); r.w = rsqrtf(v.w);
    return r;
}
__device__ __forceinline__ unsigned int pk2h(float a, float b) {
    union { _Float16 h[2]; unsigned int u; } v;
    v.h[0] = (_Float16)a; v.h[1] = (_Float16)b; return v.u;
}

// ---------------- prep kernel: format weights to f16 once ----------------
__global__ __launch_bounds__(256) void prep_kernel(
    const float* __restrict__ w1, const float* __restrict__ w2,
    const float* __restrict__ w3, _Float16* __restrict__ wb)
{
    const int gtid = blockIdx.x * 256 + threadIdx.x;
    for (int i = gtid; i < WB_HALVES; i += 32 * 256) {
        float v;
        if (i < 4224) {                     // w2h [och][264]
            int och = i / 264, k = i - och * 264;
            int tap = k >> 3, c = k & 7;
            v = (och < 10 && c < 5 && tap < 30) ? w2[(tap * 5 + c) * 10 + och] : 0.f;
        } else if (i < 11904) {             // wph [(c,dlt)][96]
            int j = i - 4224;
            int c = j / 1536, r = j - c * 1536;
            int dlt = r / 96, u = r - dlt * 96;
            int t = u - dlt;
            v = (t >= 0 && t < K1) ? w1[t * C1 + c] : 0.f;
        } else {                            // w3t [oc][384]
            int j = i - 11904;
            int oc = j / 384, jj = j - oc * 384;
            v = (oc < 20 && jj < 370) ? w3[jj * C3 + oc] : 0.f;
        }
        wb[i] = (_Float16)v;
    }
}

// ---------------- Kernel 1: conv pipeline ----------------
__global__ __launch_bounds__(256, 3) void conv_rows_kernel(
    const float* __restrict__ x,
    const _Float16* __restrict__ wb,
    const float* __restrict__ b1, const float* __restrict__ g1, const float* __restrict__ be1,
    const float* __restrict__ b2, const float* __restrict__ g2, const float* __restrict__ be2,
    const float* __restrict__ b3, const float* __restrict__ g3, const float* __restrict__ be3,
    float* __restrict__ feats, int nrows)
{
    __shared__ __align__(16) char smem[SMEM_BYTES];

    const int tid  = threadIdx.x;
    const int wave = tid >> 6;
    const int lane = tid & 63;

    _Float16* const s1h  = (_Float16*)smem;
    _Float16* const w2h  = (_Float16*)(smem + 17664);
    _Float16* const wph  = (_Float16*)(smem + 26112);
    _Float16* const s2h  = (_Float16*)(smem + 26112);
    float*    const scr  = (float*)(smem + 38656);
    _Float16* const x16h = (_Float16*)(smem + 41472);

    const int dlt = lane & 15;
    const int grp = lane >> 4;

    // ================= P0: copy weights global->LDS, stage x16 ====================
    {
        const f32x4* src = (const f32x4*)wb;
        f32x4* dst = (f32x4*)(smem + 17664);
        for (int i = tid; i < 1488; i += 256) dst[i] = src[i];   // w2h + wph, 23808 B
    }
    {
        unsigned int* x16u = (unsigned int*)x16h;
        const int row0g = blockIdx.x * RPB;
        for (int q = tid; q < 16 * 80; q += 256) {
            int r = q / 80, wp = q - r * 80;
            int gr = row0g + r; if (gr >= nrows) gr = nrows - 1;
            float a = 0.f, b = 0.f;
            if (wp < 65) { const float* xp = x + (size_t)gr * WIN + 2 * wp; a = xp[0]; b = xp[1]; }
            x16u[r * 80 + wp] = pk2h(a, b);
        }
    }
    if (tid < 192) {    // s1h tail zero (positions 66..68)
        int r = tid / 12, wp = tid - r * 12;
        ((unsigned int*)s1h)[r * 276 + 264 + wp] = 0u;
    }
    __syncthreads();

    // ================= P1: conv1 via toeplitz MFMA + LN1 + ELU -> s1h ==============
    for (int g = wave; g < 5; g += (wave == 1 ? 3 : 5)) {
        const int p0 = g * 16;
        const _Float16* xb = x16h + dlt * 160 + p0 + grp * 8;
        f16x8 a0 = *(const f16x8*)(xb);
        f16x8 a1 = *(const f16x8*)(xb + 32);
        f16x8 a2 = *(const f16x8*)(xb + 64);
        f32x4 o[C1];
        #pragma unroll
        for (int c = 0; c < C1; ++c) {
            const _Float16* wbp = wph + (c * 16 + dlt) * 96 + grp * 8;
            f32x4 t = splat4(0.f);
            t = __builtin_amdgcn_mfma_f32_16x16x32_f16(a0, *(const f16x8*)(wbp),      t, 0, 0, 0);
            t = __builtin_amdgcn_mfma_f32_16x16x32_f16(a1, *(const f16x8*)(wbp + 32), t, 0, 0, 0);
            t = __builtin_amdgcn_mfma_f32_16x16x32_f16(a2, *(const f16x8*)(wbp + 64), t, 0, 0, 0);
            o[c] = t + splat4(b1[c]);
        }
        f32x4 m = splat4(0.f);
        #pragma unroll
        for (int c = 0; c < C1; ++c) m += o[c];
        m *= 0.2f;
        f32x4 v = splat4(0.f);
        #pragma unroll
        for (int c = 0; c < C1; ++c) { f32x4 d = o[c] - m; v = pkfma4(d, d, v); }
        f32x4 inv = rsqrt4(v * 0.2f + 1e-3f);
        f32x4 oo[C1];
        #pragma unroll
        for (int c = 0; c < C1; ++c) oo[c] = elu4((o[c] - m) * inv * g1[c] + be1[c]);
        const int p = p0 + dlt;
        if (p < WO1) {
            #pragma unroll
            for (int i = 0; i < 4; ++i) {
                const int row = grp * 4 + i;
                union { _Float16 h[8]; f16x8 v8; } pkv;
                pkv.h[0] = (_Float16)oo[0][i];
                pkv.h[1] = (_Float16)oo[1][i];
                pkv.h[2] = (_Float16)oo[2][i];
                pkv.h[3] = (_Float16)oo[3][i];
                pkv.h[4] = (_Float16)oo[4][i];
                pkv.h[5] = (_Float16)0.f;
                pkv.h[6] = (_Float16)0.f;
                pkv.h[7] = (_Float16)0.f;
                *(f16x8*)&s1h[row * S1H_STRIDE + p * 8] = pkv.v8;
            }
        }
    }
    __syncthreads();

    // ================= P2: conv2 MFMA + LN2 + ELU -> s2h (f16) =====================
    {
        unsigned int* s2u = (unsigned int*)s2h;
        if (lane < 44) {        // zero pad j in [370,392) for this wave's 4 rows
            int r4 = lane / 11, jj = lane - r4 * 11;
            s2u[(4 * wave + r4) * 196 + 185 + jj] = 0u;
        }

        const _Float16* wbase = w2h + dlt * W2H_STRIDE + grp * 8;  // A: och = dlt
        f16x8 wf0 = *(const f16x8*)(wbase);
        f16x8 wf1 = *(const f16x8*)(wbase + 32);
        f16x8 wf2 = *(const f16x8*)(wbase + 64);
        f16x8 wf3 = *(const f16x8*)(wbase + 96);
        f16x8 wf4 = *(const f16x8*)(wbase + 128);
        f16x8 wf5 = *(const f16x8*)(wbase + 160);
        f16x8 wf6 = *(const f16x8*)(wbase + 192);
        f16x8 wf7 = *(const f16x8*)(wbase + 224);

        float b2r[4], g2r[4], be2r[4];
        bool  mk[4];
        #pragma unroll
        for (int i = 0; i < 4; ++i) {
            int oo = grp * 4 + i;
            mk[i] = oo < 10;
            int oc = mk[i] ? oo : 9;
            b2r[i] = b2[oc]; g2r[i] = g2[oc]; be2r[i] = be2[oc];
        }
        const int r  = lane & 3;
        const int pr = (lane >> 2) & 3;
        const _Float16* pbase = s1h + (4 * wave + r) * S1H_STRIDE + grp * 8;

        for (int g = 0; g < 10; ++g) {
            const int p  = g * 4 + pr;
            const int p2 = min(p, WO2 - 1);
            const _Float16* pb = pbase + p2 * 8;
            f32x4 aA = splat4(0.f), aB = splat4(0.f);
            aA = __builtin_amdgcn_mfma_f32_16x16x32_f16(wf0, *(const f16x8*)(pb),       aA, 0, 0, 0);
            aA = __builtin_amdgcn_mfma_f32_16x16x32_f16(wf1, *(const f16x8*)(pb +  32), aA, 0, 0, 0);
            aA = __builtin_amdgcn_mfma_f32_16x16x32_f16(wf2, *(const f16x8*)(pb +  64), aA, 0, 0, 0);
            aA = __builtin_amdgcn_mfma_f32_16x16x32_f16(wf3, *(const f16x8*)(pb +  96), aA, 0, 0, 0);
            aB = __builtin_amdgcn_mfma_f32_16x16x32_f16(wf4, *(const f16x8*)(pb + 128), aB, 0, 0, 0);
            aB = __builtin_amdgcn_mfma_f32_16x16x32_f16(wf5, *(const f16x8*)(pb + 160), aB, 0, 0, 0);
            aB = __builtin_amdgcn_mfma_f32_16x16x32_f16(wf6, *(const f16x8*)(pb + 192), aB, 0, 0, 0);
            aB = __builtin_amdgcn_mfma_f32_16x16x32_f16(wf7, *(const f16x8*)(pb + 224), aB, 0, 0, 0);
            f32x4 acc = aA + aB;

            float v0 = acc.x + b2r[0], v1 = acc.y + b2r[1];
            float v2 = acc.z + b2r[2], v3 = acc.w + b2r[3];
            float sp = (mk[0] ? v0 : 0.f) + (mk[1] ? v1 : 0.f)
                     + (mk[2] ? v2 : 0.f) + (mk[3] ? v3 : 0.f);
            sp += __shfl_xor(sp, 16);
            sp += __shfl_xor(sp, 32);
            const float mean = sp * 0.1f;
            float d0 = v0 - mean, d1 = v1 - mean, d2 = v2 - mean, d3 = v3 - mean;
            float sq = (mk[0] ? d0 * d0 : 0.f) + (mk[1] ? d1 * d1 : 0.f)
                     + (mk[2] ? d2 * d2 : 0.f) + (mk[3] ? d3 * d3 : 0.f);
            sq += __shfl_xor(sq, 16);
            sq += __shfl_xor(sq, 32);
            const float inv = rsqrtf(sq * 0.1f + 1e-3f);

            if (p < WO2) {
                float e0 = elu_f(d0 * inv * g2r[0] + be2r[0]);
                float e1 = elu_f(d1 * inv * g2r[1] + be2r[1]);
                float e2 = elu_f(d2 * inv * g2r[2] + be2r[2]);
                float e3 = elu_f(d3 * inv * g2r[3] + be2r[3]);
                int base = (4 * wave + r) * 196 + p * 5 + grp * 2;
                if (mk[0]) s2u[base]     = pk2h(e0, e1);
                if (mk[2]) s2u[base + 1] = pk2h(e2, e3);
            }
        }
    }
    __syncthreads();

    // ================= P3: conv3 via MFMA + LN3 + ELU -> feats =====================
    {
        const int tile  = wave & 1;    // 0: oc 0-15, 1: oc 16-19
        const int khalf = wave >> 1;   // K-steps 0-5 / 6-11
        const int col   = lane & 15;

        const _Float16* arow = s2h + col * 392 + (lane >> 4) * 8;
        const _Float16* brow = wb + 11904 + (size_t)(tile * 16 + col) * 384 + (lane >> 4) * 8;

        f32x4 acc = splat4(0.f);
        #pragma unroll
        for (int s = 0; s < 6; ++s) {
            const int st = khalf * 6 + s;
            f16x8 af = *(const f16x8*)(arow + st * 32);
            f16x8 bf = *(const f16x8*)(brow + st * 32);
            acc = __builtin_amdgcn_mfma_f32_16x16x32_f16(af, bf, acc, 0, 0, 0);
        }
        f32x4* scrv = (f32x4*)scr;
        if (khalf == 1) scrv[tile * 64 + lane] = acc;
        __syncthreads();

        const int ocg = tile * 16 + col;
        const bool vc = ocg < 20;
        const int occ = vc ? ocg : 19;
        f32x4 vv = splat4(0.f);
        float* sums = scr + 512;
        if (khalf == 0) {
            acc += scrv[tile * 64 + lane];
            vv = acc + splat4(b3[occ]);
            if (!vc) vv = splat4(0.f);
            f32x4 s = vv, q = vv * vv;
            #pragma unroll
            for (int d = 1; d < 16; d <<= 1) {
                s.x += __shfl_xor(s.x, d); s.y += __shfl_xor(s.y, d);
                s.z += __shfl_xor(s.z, d); s.w += __shfl_xor(s.w, d);
                q.x += __shfl_xor(q.x, d); q.y += __shfl_xor(q.y, d);
                q.z += __shfl_xor(q.z, d); q.w += __shfl_xor(q.w, d);
            }
            if (col == 0) {
                const int rb = (lane >> 4) * 4;
                #pragma unroll
                for (int i = 0; i < 4; ++i) {
                    sums[tile * 64 + rb + i]      = s[i];
                    sums[tile * 64 + 16 + rb + i] = q[i];
                }
            }
        }
        __syncthreads();
        if (khalf == 0) {
            const float gg = g3[occ], bb = be3[occ];
            #pragma unroll
            for (int i = 0; i < 4; ++i) {
                const int row = (lane >> 4) * 4 + i;
                const float ts = sums[row] + sums[64 + row];
                const float tq = sums[16 + row] + sums[80 + row];
                const float mn = ts * 0.05f;
                const float vr = tq * 0.05f - mn * mn;
                const float iv = rsqrtf(vr + 1e-3f);
                if (vc) {
                    const int grow = blockIdx.x * RPB + row;
                    if (grow < nrows)
                        feats[(size_t)grow * C3 + ocg] = elu_f((vv[i] - mn) * iv * gg + bb);
                }
            }
        }
    }
}

// ---------------- Kernel 2: per-batch graph block ----------------
__global__ __launch_bounds__(256) void graph_kernel(
    const float* __restrict__ feats,
    const float* __restrict__ agent_w, const float* __restrict__ agent_b,
    const float* __restrict__ g1w, const float* __restrict__ g1b,
    const float* __restrict__ g2w, const float* __restrict__ g2b,
    const float* __restrict__ dw, const float* __restrict__ db,
    const int* __restrict__ rlp,
    float* __restrict__ out)
{
    __shared__ float sfe[NN * C3];
    __shared__ float sfc[NN * C3];
    __shared__ float sA[NN * NN];
    __shared__ float snrm[NN], sidx[NN], sdv[NN];
    __shared__ float red[256];
    __shared__ float ssigma;
    __shared__ float sfeat[10];
    __shared__ float sg1[C3 * C2], sg1b[C2], sg2[C2 * C1], sg2b[C1], sdw[20], sdb[2];

    const int tid = threadIdx.x;
    const int b = blockIdx.x;
    const float* F = feats + (size_t)b * (NN * C3);
    const int rl = rlp[0];

    if (tid < C3 * C2) sg1[tid] = g1w[tid];
    if (tid < C2) sg1b[tid] = g1b[tid];
    if (tid < C2 * C1) sg2[tid] = g2w[tid];
    if (tid < C1) sg2b[tid] = g2b[tid];
    if (tid < 20) sdw[tid] = dw[tid];
    if (tid < 2) sdb[tid] = db[tid];

    for (int n = tid; n < NN; n += 256) {
        float f[C3];
        float m = 0.f;
        #pragma unroll
        for (int d = 0; d < C3; ++d) { f[d] = F[n * C3 + d]; m += f[d]; }
        m *= (1.f / C3);
        float nr = 0.f, ag = 0.f;
        #pragma unroll
        for (int d = 0; d < C3; ++d) {
            sfe[n * C3 + d] = f[d];
            float c = f[d] - m;
            sfc[n * C3 + d] = c;
            nr += c * c;
            ag += f[d] * agent_w[d];
        }
        snrm[n] = sqrtf(nr);
        sidx[n] = rl ? (1.f / (1.f + __expf(-(ag + agent_b[0])))) : 1.f;
    }
    __syncthreads();

    float psum = 0.f;
    for (int e = tid; e < NN * NN; e += 256) {
        int n = e / NN, m = e - n * NN;
        float dot = 0.f;
        #pragma unroll
        for (int d = 0; d < C3; ++d) dot += sfc[n * C3 + d] * sfc[m * C3 + d];
        float corr = dot / (snrm[n] * snrm[m]);
        float dist = (n == m) ? 0.f : (1.f - corr);
        sA[e] = dist;
        psum += dist;
    }
    red[tid] = psum;
    __syncthreads();
    for (int s = 128; s > 0; s >>= 1) {
        if (tid < s) red[tid] += red[tid + s];
        __syncthreads();
    }
    if (tid == 0) ssigma = red[0] / (float)(NN * NN);
    __syncthreads();

    const float sig = ssigma;
    const float inv2s2 = 1.f / (2.f * sig * sig);
    for (int e = tid; e < NN * NN; e += 256) {
        int n = e / NN, m = e - n * NN;
        float dist = sA[e];
        sA[e] = sidx[n] * sidx[m] * __expf(-dist * dist * inv2s2);
    }
    __syncthreads();

    for (int n = tid; n < NN; n += 256) {
        float s = 0.f;
        for (int m = 0; m < NN; ++m) s += sA[n * NN + m];
        float dv = rsqrtf(s);
        if (isinf(dv)) dv = 0.f;
        sdv[n] = dv;
    }
    __syncthreads();

    for (int e = tid; e < NN * NN; e += 256) {
        int n = e / NN, m = e - n * NN;
        sA[e] *= sdv[n] * sdv[m];
    }
    __syncthreads();

    for (int e = tid; e < NN * C2; e += 256) {
        int n = e / C2, o = e - n * C2;
        float acc = 0.f;
        #pragma unroll
        for (int d = 0; d < C3; ++d) acc += sfe[n * C3 + d] * sg1[d * C2 + o];
        sfc[e] = acc * sidx[n] + sg1b[o];
    }
    __syncthreads();

    for (int e = tid; e < NN * C2; e += 256) {
        int n = e / C2, o = e - n * C2;
        float acc = 0.f;
        for (int m = 0; m < NN; ++m) acc += sA[n * NN + m] * sfc[m * C2 + o];
        sfe[e] = elu_f(acc);
    }
    __syncthreads();

    for (int e = tid; e < NN * C1; e += 256) {
        int n = e / C1, c = e - n * C1;
        float acc = sg2b[c];
        #pragma unroll
        for (int o = 0; o < C2; ++o) acc += sfe[n * C2 + o] * sg2[o * C1 + c];
        sfc[NN * C2 + e] = acc;
    }
    __syncthreads();

    for (int e = tid; e < NN * C1; e += 256) {
        int n = e / C1, c = e - n * C1;
        float acc = 0.f;
        for (int m = 0; m < NN; ++m) acc += sA[n * NN + m] * sfc[NN * C2 + m * C1 + c];
        sfe[NN * C2 + e] = elu_f(acc);
    }
    __syncthreads();

    if (tid < C1) {
        const int c = tid;
        float pmax = -INFINITY, rmin = INFINITY, s = 0.f;
        for (int n = 0; n < NN; ++n) {
            float v = sfe[NN * C2 + n * C1 + c];
            pmax = fmaxf(pmax, v);
            rmin = fminf(rmin, 1.f / v);
            s += v;
        }
        float nmax = 1.f / rmin;
        sfeat[c] = (pmax == 0.f) ? nmax : pmax;
        sfeat[C1 + c] = s;
    }
    __syncthreads();

    if (tid == 0) {
        float l0 = sdb[0], l1 = sdb[1];
        #pragma unroll
        for (int j = 0; j < 10; ++j) {
            l0 += sfeat[j] * sdw[j * 2 + 0];
            l1 += sfeat[j] * sdw[j * 2 + 1];
        }
        float mx = fmaxf(l0, l1);
        float e0 = expf(l0 - mx), e1 = expf(l1 - mx);
        float s = e0 + e1;
        out[b * 2 + 0] = e0 / s;
        out[b * 2 + 1] = e1 / s;
    }
}

extern "C" void kernel_launch(void* const* d_in, const int* in_sizes, int n_in,
                              void* d_out, int out_size, void* d_ws, size_t ws_size,
                              hipStream_t stream) {
    const float* x       = (const float*)d_in[0];
    const float* conv1_w = (const float*)d_in[1];
    const float* conv1_b = (const float*)d_in[2];
    const float* ln1_g   = (const float*)d_in[3];
    const float* ln1_b   = (const float*)d_in[4];
    const float* conv2_w = (const float*)d_in[5];
    const float* conv2_b = (const float*)d_in[6];
    const float* ln2_g   = (const float*)d_in[7];
    const float* ln2_b   = (const float*)d_in[8];
    const float* conv3_w = (const float*)d_in[9];
    const float* conv3_b = (const float*)d_in[10];
    const float* ln3_g   = (const float*)d_in[11];
    const float* ln3_b   = (const float*)d_in[12];
    const float* agent_w = (const float*)d_in[13];
    const float* agent_b = (const float*)d_in[14];
    const float* gconv1_w= (const float*)d_in[15];
    const float* gconv1_b= (const float*)d_in[16];
    const float* gconv2_w= (const float*)d_in[17];
    const float* gconv2_b= (const float*)d_in[18];
    const float* dense_w = (const float*)d_in[19];
    const float* dense_b = (const float*)d_in[20];
    const int*   rl      = (const int*)d_in[21];
    float* out = (float*)d_out;

    const int B = in_sizes[0] / (NH * WIN);
    const int nrows = B * NH;
    _Float16* wbuf = (_Float16*)d_ws;
    float* feats = (float*)((char*)d_ws + FEATS_OFF);

    dim3 block(256);
    hipLaunchKernelGGL(prep_kernel, dim3(32), block, 0, stream,
                       conv1_w, conv2_w, conv3_w, wbuf);

    dim3 grid1((nrows + RPB - 1) / RPB);
    hipLaunchKernelGGL(conv_rows_kernel, grid1, block, 0, stream,
                       x, (const _Float16*)wbuf,
                       conv1_b, ln1_g, ln1_b,
                       conv2_b, ln2_g, ln2_b,
                       conv3_b, ln3_g, ln3_b,
                       feats, nrows);

    dim3 grid2(B);
    hipLaunchKernelGGL(graph_kernel, grid2, block, 0, stream,
                       feats, agent_w, agent_b,
                       gconv1_w, gconv1_b, gconv2_w, gconv2_b,
                       dense_w, dense_b, rl, out);
}

// Round 9
// 188.812 us; speedup vs baseline: 4.5579x; 1.3382x over previous
//
#include <hip/hip_runtime.h>
#include <math.h>

#define NH    114
#define WIN   130
#define WO1   66
#define WO2   37
#define C1    5
#define C2    10
#define C3    20
#define K1    65
#define K2    30
#define K3    37
#define NN    114
#define RPB   16     // rows per block = 4 waves; row-quads per wave

typedef float f32x4 __attribute__((ext_vector_type(4)));
typedef _Float16 f16x8 __attribute__((ext_vector_type(8)));

// ---- d_ws layout ----
#define WB_HALVES 24192
#define FEATS_OFF 65536

// ---- conv LDS layout (bytes), total 46592 ----
#define SMEM_BYTES 46592
#define S1H_STRIDE 552
#define W2H_STRIDE 264

__device__ __forceinline__ f32x4 splat4(float s) { f32x4 r; r.x = s; r.y = s; r.z = s; r.w = s; return r; }
__device__ __forceinline__ f32x4 pkfma4(f32x4 a, f32x4 b, f32x4 c) {
    return __builtin_elementwise_fma(a, b, c);
}
__device__ __forceinline__ float elu_f(float v) { return fmaxf(v, 0.f) + __expf(fminf(v, 0.f)) - 1.f; }
__device__ __forceinline__ f32x4 elu4(f32x4 v) {
    f32x4 r;
    r.x = elu_f(v.x); r.y = elu_f(v.y); r.z = elu_f(v.z); r.w = elu_f(v.w);
    return r;
}
__device__ __forceinline__ f32x4 rsqrt4(f32x4 v) {
    f32x4 r; r.x = rsqrtf(v.x); r.y = rsqrtf(v.y); r.z = rsqrtf(v.z); r.w = rsqrtf(v.w);
    return r;
}
__device__ __forceinline__ unsigned int pk2h(float a, float b) {
    union { _Float16 h[2]; unsigned int u; } v;
    v.h[0] = (_Float16)a; v.h[1] = (_Float16)b; return v.u;
}

// ---------------- prep kernel: format weights to f16 once ----------------
__global__ __launch_bounds__(256) void prep_kernel(
    const float* __restrict__ w1, const float* __restrict__ w2,
    const float* __restrict__ w3, _Float16* __restrict__ wb)
{
    const int gtid = blockIdx.x * 256 + threadIdx.x;
    for (int i = gtid; i < WB_HALVES; i += 32 * 256) {
        float v;
        if (i < 4224) {                     // w2h [och][264]
            int och = i / 264, k = i - och * 264;
            int tap = k >> 3, c = k & 7;
            v = (och < 10 && c < 5 && tap < 30) ? w2[(tap * 5 + c) * 10 + och] : 0.f;
        } else if (i < 11904) {             // wph [(c,dlt)][96]
            int j = i - 4224;
            int c = j / 1536, r = j - c * 1536;
            int dlt = r / 96, u = r - dlt * 96;
            int t = u - dlt;
            v = (t >= 0 && t < K1) ? w1[t * C1 + c] : 0.f;
        } else {                            // w3t [oc][384]
            int j = i - 11904;
            int oc = j / 384, jj = j - oc * 384;
            v = (oc < 20 && jj < 370) ? w3[jj * C3 + oc] : 0.f;
        }
        wb[i] = (_Float16)v;
    }
}

// ---------------- Kernel 1: conv pipeline (unchanged from round 8) ----------------
__global__ __launch_bounds__(256, 3) void conv_rows_kernel(
    const float* __restrict__ x,
    const _Float16* __restrict__ wb,
    const float* __restrict__ b1, const float* __restrict__ g1, const float* __restrict__ be1,
    const float* __restrict__ b2, const float* __restrict__ g2, const float* __restrict__ be2,
    const float* __restrict__ b3, const float* __restrict__ g3, const float* __restrict__ be3,
    float* __restrict__ feats, int nrows)
{
    __shared__ __align__(16) char smem[SMEM_BYTES];

    const int tid  = threadIdx.x;
    const int wave = tid >> 6;
    const int lane = tid & 63;

    _Float16* const s1h  = (_Float16*)smem;
    _Float16* const w2h  = (_Float16*)(smem + 17664);
    _Float16* const wph  = (_Float16*)(smem + 26112);
    _Float16* const s2h  = (_Float16*)(smem + 26112);
    float*    const scr  = (float*)(smem + 38656);
    _Float16* const x16h = (_Float16*)(smem + 41472);

    const int dlt = lane & 15;
    const int grp = lane >> 4;

    // ---- P0 ----
    {
        const f32x4* src = (const f32x4*)wb;
        f32x4* dst = (f32x4*)(smem + 17664);
        for (int i = tid; i < 1488; i += 256) dst[i] = src[i];
    }
    {
        unsigned int* x16u = (unsigned int*)x16h;
        const int row0g = blockIdx.x * RPB;
        for (int q = tid; q < 16 * 80; q += 256) {
            int r = q / 80, wp = q - r * 80;
            int gr = row0g + r; if (gr >= nrows) gr = nrows - 1;
            float a = 0.f, b = 0.f;
            if (wp < 65) { const float* xp = x + (size_t)gr * WIN + 2 * wp; a = xp[0]; b = xp[1]; }
            x16u[r * 80 + wp] = pk2h(a, b);
        }
    }
    if (tid < 192) {
        int r = tid / 12, wp = tid - r * 12;
        ((unsigned int*)s1h)[r * 276 + 264 + wp] = 0u;
    }
    __syncthreads();

    // ---- P1: conv1 toeplitz MFMA ----
    for (int g = wave; g < 5; g += (wave == 1 ? 3 : 5)) {
        const int p0 = g * 16;
        const _Float16* xb = x16h + dlt * 160 + p0 + grp * 8;
        f16x8 a0 = *(const f16x8*)(xb);
        f16x8 a1 = *(const f16x8*)(xb + 32);
        f16x8 a2 = *(const f16x8*)(xb + 64);
        f32x4 o[C1];
        #pragma unroll
        for (int c = 0; c < C1; ++c) {
            const _Float16* wbp = wph + (c * 16 + dlt) * 96 + grp * 8;
            f32x4 t = splat4(0.f);
            t = __builtin_amdgcn_mfma_f32_16x16x32_f16(a0, *(const f16x8*)(wbp),      t, 0, 0, 0);
            t = __builtin_amdgcn_mfma_f32_16x16x32_f16(a1, *(const f16x8*)(wbp + 32), t, 0, 0, 0);
            t = __builtin_amdgcn_mfma_f32_16x16x32_f16(a2, *(const f16x8*)(wbp + 64), t, 0, 0, 0);
            o[c] = t + splat4(b1[c]);
        }
        f32x4 m = splat4(0.f);
        #pragma unroll
        for (int c = 0; c < C1; ++c) m += o[c];
        m *= 0.2f;
        f32x4 v = splat4(0.f);
        #pragma unroll
        for (int c = 0; c < C1; ++c) { f32x4 d = o[c] - m; v = pkfma4(d, d, v); }
        f32x4 inv = rsqrt4(v * 0.2f + 1e-3f);
        f32x4 oo[C1];
        #pragma unroll
        for (int c = 0; c < C1; ++c) oo[c] = elu4((o[c] - m) * inv * g1[c] + be1[c]);
        const int p = p0 + dlt;
        if (p < WO1) {
            #pragma unroll
            for (int i = 0; i < 4; ++i) {
                const int row = grp * 4 + i;
                union { _Float16 h[8]; f16x8 v8; } pkv;
                pkv.h[0] = (_Float16)oo[0][i];
                pkv.h[1] = (_Float16)oo[1][i];
                pkv.h[2] = (_Float16)oo[2][i];
                pkv.h[3] = (_Float16)oo[3][i];
                pkv.h[4] = (_Float16)oo[4][i];
                pkv.h[5] = (_Float16)0.f;
                pkv.h[6] = (_Float16)0.f;
                pkv.h[7] = (_Float16)0.f;
                *(f16x8*)&s1h[row * S1H_STRIDE + p * 8] = pkv.v8;
            }
        }
    }
    __syncthreads();

    // ---- P2: conv2 MFMA + LN2 -> s2h ----
    {
        unsigned int* s2u = (unsigned int*)s2h;
        if (lane < 44) {
            int r4 = lane / 11, jj = lane - r4 * 11;
            s2u[(4 * wave + r4) * 196 + 185 + jj] = 0u;
        }

        const _Float16* wbase = w2h + dlt * W2H_STRIDE + grp * 8;
        f16x8 wf0 = *(const f16x8*)(wbase);
        f16x8 wf1 = *(const f16x8*)(wbase + 32);
        f16x8 wf2 = *(const f16x8*)(wbase + 64);
        f16x8 wf3 = *(const f16x8*)(wbase + 96);
        f16x8 wf4 = *(const f16x8*)(wbase + 128);
        f16x8 wf5 = *(const f16x8*)(wbase + 160);
        f16x8 wf6 = *(const f16x8*)(wbase + 192);
        f16x8 wf7 = *(const f16x8*)(wbase + 224);

        float b2r[4], g2r[4], be2r[4];
        bool  mk[4];
        #pragma unroll
        for (int i = 0; i < 4; ++i) {
            int oo = grp * 4 + i;
            mk[i] = oo < 10;
            int oc = mk[i] ? oo : 9;
            b2r[i] = b2[oc]; g2r[i] = g2[oc]; be2r[i] = be2[oc];
        }
        const int r  = lane & 3;
        const int pr = (lane >> 2) & 3;
        const _Float16* pbase = s1h + (4 * wave + r) * S1H_STRIDE + grp * 8;

        for (int g = 0; g < 10; ++g) {
            const int p  = g * 4 + pr;
            const int p2 = min(p, WO2 - 1);
            const _Float16* pb = pbase + p2 * 8;
            f32x4 aA = splat4(0.f), aB = splat4(0.f);
            aA = __builtin_amdgcn_mfma_f32_16x16x32_f16(wf0, *(const f16x8*)(pb),       aA, 0, 0, 0);
            aA = __builtin_amdgcn_mfma_f32_16x16x32_f16(wf1, *(const f16x8*)(pb +  32), aA, 0, 0, 0);
            aA = __builtin_amdgcn_mfma_f32_16x16x32_f16(wf2, *(const f16x8*)(pb +  64), aA, 0, 0, 0);
            aA = __builtin_amdgcn_mfma_f32_16x16x32_f16(wf3, *(const f16x8*)(pb +  96), aA, 0, 0, 0);
            aB = __builtin_amdgcn_mfma_f32_16x16x32_f16(wf4, *(const f16x8*)(pb + 128), aB, 0, 0, 0);
            aB = __builtin_amdgcn_mfma_f32_16x16x32_f16(wf5, *(const f16x8*)(pb + 160), aB, 0, 0, 0);
            aB = __builtin_amdgcn_mfma_f32_16x16x32_f16(wf6, *(const f16x8*)(pb + 192), aB, 0, 0, 0);
            aB = __builtin_amdgcn_mfma_f32_16x16x32_f16(wf7, *(const f16x8*)(pb + 224), aB, 0, 0, 0);
            f32x4 acc = aA + aB;

            float v0 = acc.x + b2r[0], v1 = acc.y + b2r[1];
            float v2 = acc.z + b2r[2], v3 = acc.w + b2r[3];
            float sp = (mk[0] ? v0 : 0.f) + (mk[1] ? v1 : 0.f)
                     + (mk[2] ? v2 : 0.f) + (mk[3] ? v3 : 0.f);
            sp += __shfl_xor(sp, 16);
            sp += __shfl_xor(sp, 32);
            const float mean = sp * 0.1f;
            float d0 = v0 - mean, d1 = v1 - mean, d2 = v2 - mean, d3 = v3 - mean;
            float sq = (mk[0] ? d0 * d0 : 0.f) + (mk[1] ? d1 * d1 : 0.f)
                     + (mk[2] ? d2 * d2 : 0.f) + (mk[3] ? d3 * d3 : 0.f);
            sq += __shfl_xor(sq, 16);
            sq += __shfl_xor(sq, 32);
            const float inv = rsqrtf(sq * 0.1f + 1e-3f);

            if (p < WO2) {
                float e0 = elu_f(d0 * inv * g2r[0] + be2r[0]);
                float e1 = elu_f(d1 * inv * g2r[1] + be2r[1]);
                float e2 = elu_f(d2 * inv * g2r[2] + be2r[2]);
                float e3 = elu_f(d3 * inv * g2r[3] + be2r[3]);
                int base = (4 * wave + r) * 196 + p * 5 + grp * 2;
                if (mk[0]) s2u[base]     = pk2h(e0, e1);
                if (mk[2]) s2u[base + 1] = pk2h(e2, e3);
            }
        }
    }
    __syncthreads();

    // ---- P3: conv3 MFMA + LN3 -> feats ----
    {
        const int tile  = wave & 1;
        const int khalf = wave >> 1;
        const int col   = lane & 15;

        const _Float16* arow = s2h + col * 392 + (lane >> 4) * 8;
        const _Float16* brow = wb + 11904 + (size_t)(tile * 16 + col) * 384 + (lane >> 4) * 8;

        f32x4 acc = splat4(0.f);
        #pragma unroll
        for (int s = 0; s < 6; ++s) {
            const int st = khalf * 6 + s;
            f16x8 af = *(const f16x8*)(arow + st * 32);
            f16x8 bf = *(const f16x8*)(brow + st * 32);
            acc = __builtin_amdgcn_mfma_f32_16x16x32_f16(af, bf, acc, 0, 0, 0);
        }
        f32x4* scrv = (f32x4*)scr;
        if (khalf == 1) scrv[tile * 64 + lane] = acc;
        __syncthreads();

        const int ocg = tile * 16 + col;
        const bool vc = ocg < 20;
        const int occ = vc ? ocg : 19;
        f32x4 vv = splat4(0.f);
        float* sums = scr + 512;
        if (khalf == 0) {
            acc += scrv[tile * 64 + lane];
            vv = acc + splat4(b3[occ]);
            if (!vc) vv = splat4(0.f);
            f32x4 s = vv, q = vv * vv;
            #pragma unroll
            for (int d = 1; d < 16; d <<= 1) {
                s.x += __shfl_xor(s.x, d); s.y += __shfl_xor(s.y, d);
                s.z += __shfl_xor(s.z, d); s.w += __shfl_xor(s.w, d);
                q.x += __shfl_xor(q.x, d); q.y += __shfl_xor(q.y, d);
                q.z += __shfl_xor(q.z, d); q.w += __shfl_xor(q.w, d);
            }
            if (col == 0) {
                const int rb = (lane >> 4) * 4;
                #pragma unroll
                for (int i = 0; i < 4; ++i) {
                    sums[tile * 64 + rb + i]      = s[i];
                    sums[tile * 64 + 16 + rb + i] = q[i];
                }
            }
        }
        __syncthreads();
        if (khalf == 0) {
            const float gg = g3[occ], bb = be3[occ];
            #pragma unroll
            for (int i = 0; i < 4; ++i) {
                const int row = (lane >> 4) * 4 + i;
                const float ts = sums[row] + sums[64 + row];
                const float tq = sums[16 + row] + sums[80 + row];
                const float mn = ts * 0.05f;
                const float vr = tq * 0.05f - mn * mn;
                const float iv = rsqrtf(vr + 1e-3f);
                if (vc) {
                    const int grow = blockIdx.x * RPB + row;
                    if (grow < nrows)
                        feats[(size_t)grow * C3 + ocg] = elu_f((vv[i] - mn) * iv * gg + bb);
                }
            }
        }
    }
}

// ---------------- Kernel 2: per-batch graph block, MFMA version ----------------
// LDS layout (bytes):
//  [0,     34816): sLh  f16 [128][136]  dist -> A -> L (in place)
//  [34816, 45056): sfcH f16 [128][40]   | P7+: h2T f32 [16][132]
//  [45056, 54176): sfe  f32 [114][20]   | P5+: h1f f32 [128][16]
//  [54176, 58528): t1h  f16 [16][136]   (reused as t2h)
//  [58528+ ): snrm,sidx,sdv,red,sfeat,weights
__global__ __launch_bounds__(256) void graph_kernel(
    const float* __restrict__ feats,
    const float* __restrict__ agent_w, const float* __restrict__ agent_b,
    const float* __restrict__ g1w, const float* __restrict__ g1b,
    const float* __restrict__ g2w, const float* __restrict__ g2b,
    const float* __restrict__ dw, const float* __restrict__ db,
    const int* __restrict__ rlp,
    float* __restrict__ out)
{
    __shared__ __align__(16) char gsm[61104];
    _Float16* const sLh  = (_Float16*)(gsm);
    _Float16* const sfcH = (_Float16*)(gsm + 34816);
    float*    const h2T  = (float*)(gsm + 34816);
    float*    const sfe  = (float*)(gsm + 45056);
    float*    const h1f  = (float*)(gsm + 45056);
    _Float16* const t1h  = (_Float16*)(gsm + 54176);
    float* const snrm  = (float*)(gsm + 58528);
    float* const sidx  = (float*)(gsm + 58984);
    float* const sdv   = (float*)(gsm + 59440);
    float* const red   = (float*)(gsm + 59896);
    float* const sfeat = (float*)(gsm + 59912);
    float* const sg1   = (float*)(gsm + 59952);
    float* const sg1b  = sg1 + 200;
    float* const sg2   = sg1b + 10;
    float* const sg2b  = sg2 + 50;
    float* const sdw   = sg2b + 5;
    float* const sdb   = sdw + 20;

    const int tid  = threadIdx.x;
    const int wave = tid >> 6;
    const int lane = tid & 63;
    const int b = blockIdx.x;
    const float* F = feats + (size_t)b * (NN * C3);
    const int rl = rlp[0];
    const float aw_b = agent_b[0];

    // ---- P0: zero sLh+sfcH ([0,45056)) and t1h; load small weights ----
    {
        f32x4* z = (f32x4*)gsm;
        for (int i = tid; i < 2816; i += 256) z[i] = splat4(0.f);
        f32x4* z2 = (f32x4*)(gsm + 54176);
        if (tid < 272) z2[tid] = splat4(0.f);
        if (tid < 200) sg1[tid] = g1w[tid];
        if (tid < 10)  sg1b[tid] = g1b[tid];
        if (tid < 50)  sg2[tid] = g2w[tid];
        if (tid < 5)   sg2b[tid] = g2b[tid];
        if (tid < 20)  sdw[tid] = dw[tid];
        if (tid < 2)   sdb[tid] = db[tid];
    }
    __syncthreads();

    // ---- P1: feats -> sfe (f32), fc -> sfcH (f16), nrm, idx ----
    for (int n = tid; n < NN; n += 256) {
        float f[C3];
        float m = 0.f;
        #pragma unroll
        for (int d = 0; d < C3; ++d) { f[d] = F[n * C3 + d]; m += f[d]; }
        m *= (1.f / C3);
        float nr = 0.f, ag = 0.f;
        unsigned int* dst = (unsigned int*)(sfcH + n * 40);
        #pragma unroll
        for (int d = 0; d < C3; d += 2) {
            sfe[n * C3 + d]     = f[d];
            sfe[n * C3 + d + 1] = f[d + 1];
            float c0 = f[d] - m, c1 = f[d + 1] - m;
            dst[d >> 1] = pk2h(c0, c1);
            nr = fmaf(c0, c0, fmaf(c1, c1, nr));
            ag = fmaf(f[d], agent_w[d], fmaf(f[d + 1], agent_w[d + 1], ag));
        }
        snrm[n] = sqrtf(nr);
        sidx[n] = rl ? (1.f / (1.f + __expf(-(ag + aw_b)))) : 1.f;
    }
    __syncthreads();

    // ---- P2: corr via MFMA (64 tiles), dist f16 -> sLh, sigma partial ----
    {
        float psum = 0.f;
        const int row = lane & 15;
        const int kg  = lane >> 4;
        for (int tt = 0; tt < 16; ++tt) {
            const int t  = wave * 16 + tt;
            const int tr = t >> 3, tc = t & 7;
            f16x8 a = *(const f16x8*)(sfcH + (tr * 16 + row) * 40 + kg * 8);
            f16x8 bf = *(const f16x8*)(sfcH + (tc * 16 + row) * 40 + kg * 8);
            f32x4 acc = __builtin_amdgcn_mfma_f32_16x16x32_f16(a, bf, splat4(0.f), 0, 0, 0);
            const int c = tc * 16 + row;
            const float nc = (c < NN) ? snrm[c] : 1.f;
            #pragma unroll
            for (int i = 0; i < 4; ++i) {
                const int r = tr * 16 + kg * 4 + i;
                float dist = 0.f;
                if (r < NN && c < NN && r != c)
                    dist = 1.f - acc[i] * __frcp_rn(snrm[r] * nc);
                psum += dist;
                sLh[r * 136 + c] = (_Float16)dist;
            }
        }
        #pragma unroll
        for (int d = 1; d < 64; d <<= 1) psum += __shfl_xor(psum, d);
        if (lane == 0) red[wave] = psum;
    }
    __syncthreads();

    // ---- P3: A = idx_r idx_c exp(-d^2/(2s^2)) (f16 in place) + f32 rowsum -> sdv ----
    {
        const float sg = (red[0] + red[1] + red[2] + red[3]) * (1.f / (float)(NN * NN));
        const float inv2s2 = 1.f / (2.f * sg * sg);
        if (tid < 228) {
            const int r = tid >> 1, half = tid & 1;
            const float idxr = sidx[r];
            float rsum = 0.f;
            _Float16* rp = sLh + r * 136 + half * 57;
            const int c0 = half * 57;
            for (int j = 0; j < 57; ++j) {
                float d = (float)rp[j];
                float A = idxr * sidx[c0 + j] * __expf(-d * d * inv2s2);
                rsum += A;
                rp[j] = (_Float16)A;
            }
            rsum += __shfl_xor(rsum, 1);
            if (half == 0) {
                float dv = rsqrtf(rsum);
                if (isinf(dv)) dv = 0.f;
                sdv[r] = dv;
            }
        }
    }
    __syncthreads();

    // ---- P4: L = d A d (f16 in place, u32 pairs) ; t1 -> t1h (f16, transposed) ----
    {
        unsigned int* L32 = (unsigned int*)sLh;
        for (int e2 = tid; e2 < NN * 57; e2 += 256) {
            const int r = e2 / 57, cp = e2 - r * 57;
            const unsigned int u = L32[r * 68 + cp];
            union { unsigned int uu; _Float16 h[2]; } in;
            in.uu = u;
            const float dr = sdv[r];
            float v0 = (float)in.h[0] * dr * sdv[2 * cp];
            float v1 = (float)in.h[1] * dr * sdv[2 * cp + 1];
            L32[r * 68 + cp] = pk2h(v0, v1);
        }
        for (int e = tid; e < NN * C2; e += 256) {
            const int n = e / C2, o = e - n * C2;
            float acc = 0.f;
            #pragma unroll
            for (int d = 0; d < C3; ++d) acc = fmaf(sfe[n * C3 + d], sg1[d * C2 + o], acc);
            t1h[o * 136 + n] = (_Float16)(acc * sidx[n] + sg1b[o]);
        }
    }
    __syncthreads();

    // ---- P5: h1 = elu(L @ t1) via MFMA -> h1f (f32 [128][16], overwrites sfe) ----
    {
        const int row = lane & 15;
        const int kg  = lane >> 4;
        #pragma unroll
        for (int tt = 0; tt < 2; ++tt) {
            const int tr = wave * 2 + tt;
            f32x4 acc = splat4(0.f);
            #pragma unroll
            for (int ks = 0; ks < 4; ++ks) {
                f16x8 a = *(const f16x8*)(sLh + (tr * 16 + row) * 136 + ks * 32 + kg * 8);
                f16x8 bf = *(const f16x8*)(t1h + row * 136 + ks * 32 + kg * 8);
                acc = __builtin_amdgcn_mfma_f32_16x16x32_f16(a, bf, acc, 0, 0, 0);
            }
            #pragma unroll
            for (int i = 0; i < 4; ++i) {
                const int n = tr * 16 + kg * 4 + i;
                h1f[n * 16 + row] = elu_f(acc[i]);
            }
        }
    }
    __syncthreads();

    // ---- P6: t2 = h1 @ g2w + b -> t1h (f16 transposed, aliased) ----
    for (int e = tid; e < NN * C1; e += 256) {
        const int n = e / C1, c = e - n * C1;
        float acc = sg2b[c];
        #pragma unroll
        for (int o = 0; o < C2; ++o) acc = fmaf(h1f[n * 16 + o], sg2[o * C1 + c], acc);
        t1h[c * 136 + n] = (_Float16)acc;
    }
    __syncthreads();

    // ---- P7: h2 = elu(L @ t2) via MFMA -> h2T (f32 [16][132], overwrites sfcH) ----
    {
        const int row = lane & 15;
        const int kg  = lane >> 4;
        #pragma unroll
        for (int tt = 0; tt < 2; ++tt) {
            const int tr = wave * 2 + tt;
            f32x4 acc = splat4(0.f);
            #pragma unroll
            for (int ks = 0; ks < 4; ++ks) {
                f16x8 a = *(const f16x8*)(sLh + (tr * 16 + row) * 136 + ks * 32 + kg * 8);
                f16x8 bf = *(const f16x8*)(t1h + row * 136 + ks * 32 + kg * 8);
                acc = __builtin_amdgcn_mfma_f32_16x16x32_f16(a, bf, acc, 0, 0, 0);
            }
            if (row < C1) {
                #pragma unroll
                for (int i = 0; i < 4; ++i) {
                    const int n = tr * 16 + kg * 4 + i;
                    h2T[row * 132 + n] = elu_f(acc[i]);
                }
            }
        }
    }
    __syncthreads();

    // ---- P8: pooling (32 lanes per channel) ----
    if (tid < 160) {
        const int c = tid >> 5, s = tid & 31;
        float pmax = -INFINITY, rmin = INFINITY, sum = 0.f;
        #pragma unroll
        for (int k = 0; k < 4; ++k) {
            const int n = s + 32 * k;
            if (n < NN) {
                float v = h2T[c * 132 + n];
                pmax = fmaxf(pmax, v);
                rmin = fminf(rmin, 1.f / v);
                sum += v;
            }
        }
        #pragma unroll
        for (int d = 16; d > 0; d >>= 1) {
            pmax = fmaxf(pmax, __shfl_xor(pmax, d));
            rmin = fminf(rmin, __shfl_xor(rmin, d));
            sum += __shfl_xor(sum, d);
        }
        if (s == 0) {
            float nmax = 1.f / rmin;
            sfeat[c] = (pmax == 0.f) ? nmax : pmax;
            sfeat[C1 + c] = sum;
        }
    }
    __syncthreads();

    if (tid == 0) {
        float l0 = sdb[0], l1 = sdb[1];
        #pragma unroll
        for (int j = 0; j < 10; ++j) {
            l0 += sfeat[j] * sdw[j * 2 + 0];
            l1 += sfeat[j] * sdw[j * 2 + 1];
        }
        float mx = fmaxf(l0, l1);
        float e0 = expf(l0 - mx), e1 = expf(l1 - mx);
        float s = e0 + e1;
        out[b * 2 + 0] = e0 / s;
        out[b * 2 + 1] = e1 / s;
    }
}

extern "C" void kernel_launch(void* const* d_in, const int* in_sizes, int n_in,
                              void* d_out, int out_size, void* d_ws, size_t ws_size,
                              hipStream_t stream) {
    const float* x       = (const float*)d_in[0];
    const float* conv1_w = (const float*)d_in[1];
    const float* conv1_b = (const float*)d_in[2];
    const float* ln1_g   = (const float*)d_in[3];
    const float* ln1_b   = (const float*)d_in[4];
    const float* conv2_w = (const float*)d_in[5];
    const float* conv2_b = (const float*)d_in[6];
    const float* ln2_g   = (const float*)d_in[7];
    const float* ln2_b   = (const float*)d_in[8];
    const float* conv3_w = (const float*)d_in[9];
    const float* conv3_b = (const float*)d_in[10];
    const float* ln3_g   = (const float*)d_in[11];
    const float* ln3_b   = (const float*)d_in[12];
    const float* agent_w = (const float*)d_in[13];
    const float* agent_b = (const float*)d_in[14];
    const float* gconv1_w= (const float*)d_in[15];
    const float* gconv1_b= (const float*)d_in[16];
    const float* gconv2_w= (const float*)d_in[17];
    const float* gconv2_b= (const float*)d_in[18];
    const float* dense_w = (const float*)d_in[19];
    const float* dense_b = (const float*)d_in[20];
    const int*   rl      = (const int*)d_in[21];
    float* out = (float*)d_out;

    const int B = in_sizes[0] / (NH * WIN);
    const int nrows = B * NH;
    _Float16* wbuf = (_Float16*)d_ws;
    float* feats = (float*)((char*)d_ws + FEATS_OFF);

    dim3 block(256);
    hipLaunchKernelGGL(prep_kernel, dim3(32), block, 0, stream,
                       conv1_w, conv2_w, conv3_w, wbuf);

    dim3 grid1((nrows + RPB - 1) / RPB);
    hipLaunchKernelGGL(conv_rows_kernel, grid1, block, 0, stream,
                       x, (const _Float16*)wbuf,
                       conv1_b, ln1_g, ln1_b,
                       conv2_b, ln2_g, ln2_b,
                       conv3_b, ln3_g, ln3_b,
                       feats, nrows);

    dim3 grid2(B);
    hipLaunchKernelGGL(graph_kernel, grid2, block, 0, stream,
                       feats, agent_w, agent_b,
                       gconv1_w, gconv1_b, gconv2_w, gconv2_b,
                       dense_w, dense_b, rl, out);
}

// Round 10
// 167.296 us; speedup vs baseline: 5.1441x; 1.1286x over previous
//
#include <hip/hip_runtime.h>
#include <math.h>

#define NH    114
#define WIN   130
#define WO1   66
#define WO2   37
#define C1    5
#define C2    10
#define C3    20
#define K1    65
#define K2    30
#define K3    37
#define NN    114
#define RPB   16     // rows per block = 4 waves; row-quads per wave

typedef float f32x4 __attribute__((ext_vector_type(4)));
typedef _Float16 f16x8 __attribute__((ext_vector_type(8)));

// ---- d_ws layout ----
#define WB_HALVES 24192
#define FEATS_OFF 65536

// ---- conv LDS layout (bytes), total 38048 -> 4 blocks/CU ----
//  [0,     17664): s1h  16 x 552 f16
//  [17664, 22944): w2h  10 x 264 f16  (B-frag reads for dlt>=10 hit stale LDS; D-rows masked)
//  [22944, 35488): s2h  16 x 392 f16  | P0-P1: x16h 16 x 160 f16 aliases at 22944
//  [35488, 38048): scr  f32 (scrv 2048B + sums 512B)
#define SMEM_BYTES 38048
#define S1H_STRIDE 552
#define W2H_STRIDE 264

__device__ __forceinline__ f32x4 splat4(float s) { f32x4 r; r.x = s; r.y = s; r.z = s; r.w = s; return r; }
__device__ __forceinline__ f32x4 pkfma4(f32x4 a, f32x4 b, f32x4 c) {
    return __builtin_elementwise_fma(a, b, c);
}
__device__ __forceinline__ float elu_f(float v) { return fmaxf(v, 0.f) + __expf(fminf(v, 0.f)) - 1.f; }
__device__ __forceinline__ f32x4 elu4(f32x4 v) {
    f32x4 r;
    r.x = elu_f(v.x); r.y = elu_f(v.y); r.z = elu_f(v.z); r.w = elu_f(v.w);
    return r;
}
__device__ __forceinline__ f32x4 rsqrt4(f32x4 v) {
    f32x4 r; r.x = rsqrtf(v.x); r.y = rsqrtf(v.y); r.z = rsqrtf(v.z); r.w = rsqrtf(v.w);
    return r;
}
__device__ __forceinline__ unsigned int pk2h(float a, float b) {
    union { _Float16 h[2]; unsigned int u; } v;
    v.h[0] = (_Float16)a; v.h[1] = (_Float16)b; return v.u;
}

// ---------------- prep kernel: format weights to f16 once ----------------
__global__ __launch_bounds__(256) void prep_kernel(
    const float* __restrict__ w1, const float* __restrict__ w2,
    const float* __restrict__ w3, _Float16* __restrict__ wb)
{
    const int gtid = blockIdx.x * 256 + threadIdx.x;
    for (int i = gtid; i < WB_HALVES; i += 32 * 256) {
        float v;
        if (i < 4224) {                     // w2h [och][264]
            int och = i / 264, k = i - och * 264;
            int tap = k >> 3, c = k & 7;
            v = (och < 10 && c < 5 && tap < 30) ? w2[(tap * 5 + c) * 10 + och] : 0.f;
        } else if (i < 11904) {             // wph [(c,dlt)][96]
            int j = i - 4224;
            int c = j / 1536, r = j - c * 1536;
            int dlt = r / 96, u = r - dlt * 96;
            int t = u - dlt;
            v = (t >= 0 && t < K1) ? w1[t * C1 + c] : 0.f;
        } else {                            // w3t [oc][384]
            int j = i - 11904;
            int oc = j / 384, jj = j - oc * 384;
            v = (oc < 20 && jj < 370) ? w3[jj * C3 + oc] : 0.f;
        }
        wb[i] = (_Float16)v;
    }
}

// ---------------- Kernel 1: conv pipeline ----------------
__global__ __launch_bounds__(256, 4) void conv_rows_kernel(
    const float* __restrict__ x,
    const _Float16* __restrict__ wb,
    const float* __restrict__ b1, const float* __restrict__ g1, const float* __restrict__ be1,
    const float* __restrict__ b2, const float* __restrict__ g2, const float* __restrict__ be2,
    const float* __restrict__ b3, const float* __restrict__ g3, const float* __restrict__ be3,
    float* __restrict__ feats, int nrows)
{
    __shared__ __align__(16) char smem[SMEM_BYTES];

    const int tid  = threadIdx.x;
    const int wave = tid >> 6;
    const int lane = tid & 63;

    _Float16* const s1h  = (_Float16*)smem;
    _Float16* const w2h  = (_Float16*)(smem + 17664);
    _Float16* const s2h  = (_Float16*)(smem + 22944);
    _Float16* const x16h = (_Float16*)(smem + 22944);   // aliases s2h (P0-P1 only)
    float*    const scr  = (float*)(smem + 35488);

    const int dlt = lane & 15;
    const int grp = lane >> 4;

    // ---- P0: copy w2h (10 rows) global->LDS, stage x16 ----
    {
        const f32x4* src = (const f32x4*)wb;
        f32x4* dst = (f32x4*)(smem + 17664);
        for (int i = tid; i < 330; i += 256) dst[i] = src[i];   // 5280 B
    }
    {
        unsigned int* x16u = (unsigned int*)x16h;
        const int row0g = blockIdx.x * RPB;
        for (int q = tid; q < 16 * 80; q += 256) {
            int r = q / 80, wp = q - r * 80;
            int gr = row0g + r; if (gr >= nrows) gr = nrows - 1;
            float a = 0.f, b = 0.f;
            if (wp < 65) { const float* xp = x + (size_t)gr * WIN + 2 * wp; a = xp[0]; b = xp[1]; }
            x16u[r * 80 + wp] = pk2h(a, b);
        }
    }
    if (tid < 192) {
        int r = tid / 12, wp = tid - r * 12;
        ((unsigned int*)s1h)[r * 276 + 264 + wp] = 0u;
    }
    __syncthreads();

    // ---- P1: conv1 toeplitz MFMA (B-frags direct from global/L1) ----
    for (int g = wave; g < 5; g += (wave == 1 ? 3 : 5)) {
        const int p0 = g * 16;
        const _Float16* xb = x16h + dlt * 160 + p0 + grp * 8;
        f16x8 a0 = *(const f16x8*)(xb);
        f16x8 a1 = *(const f16x8*)(xb + 32);
        f16x8 a2 = *(const f16x8*)(xb + 64);
        f32x4 o[C1];
        #pragma unroll
        for (int c = 0; c < C1; ++c) {
            const _Float16* wbp = wb + 4224 + (c * 16 + dlt) * 96 + grp * 8;
            f32x4 t = splat4(0.f);
            t = __builtin_amdgcn_mfma_f32_16x16x32_f16(a0, *(const f16x8*)(wbp),      t, 0, 0, 0);
            t = __builtin_amdgcn_mfma_f32_16x16x32_f16(a1, *(const f16x8*)(wbp + 32), t, 0, 0, 0);
            t = __builtin_amdgcn_mfma_f32_16x16x32_f16(a2, *(const f16x8*)(wbp + 64), t, 0, 0, 0);
            o[c] = t + splat4(b1[c]);
        }
        f32x4 m = splat4(0.f);
        #pragma unroll
        for (int c = 0; c < C1; ++c) m += o[c];
        m *= 0.2f;
        f32x4 v = splat4(0.f);
        #pragma unroll
        for (int c = 0; c < C1; ++c) { f32x4 d = o[c] - m; v = pkfma4(d, d, v); }
        f32x4 inv = rsqrt4(v * 0.2f + 1e-3f);
        f32x4 oo[C1];
        #pragma unroll
        for (int c = 0; c < C1; ++c) oo[c] = elu4((o[c] - m) * inv * g1[c] + be1[c]);
        const int p = p0 + dlt;
        if (p < WO1) {
            #pragma unroll
            for (int i = 0; i < 4; ++i) {
                const int row = grp * 4 + i;
                union { _Float16 h[8]; f16x8 v8; } pkv;
                pkv.h[0] = (_Float16)oo[0][i];
                pkv.h[1] = (_Float16)oo[1][i];
                pkv.h[2] = (_Float16)oo[2][i];
                pkv.h[3] = (_Float16)oo[3][i];
                pkv.h[4] = (_Float16)oo[4][i];
                pkv.h[5] = (_Float16)0.f;
                pkv.h[6] = (_Float16)0.f;
                pkv.h[7] = (_Float16)0.f;
                *(f16x8*)&s1h[row * S1H_STRIDE + p * 8] = pkv.v8;
            }
        }
    }
    __syncthreads();

    // ---- P2: conv2 MFMA + LN2 -> s2h (f16) ----
    {
        unsigned int* s2u = (unsigned int*)s2h;
        if (lane < 44) {
            int r4 = lane / 11, jj = lane - r4 * 11;
            s2u[(4 * wave + r4) * 196 + 185 + jj] = 0u;
        }

        // B-frag source rows dlt>=10 read stale LDS; their MFMA D-rows are mk-masked.
        const _Float16* wbase = w2h + dlt * W2H_STRIDE + grp * 8;
        f16x8 wf0 = *(const f16x8*)(wbase);
        f16x8 wf1 = *(const f16x8*)(wbase + 32);
        f16x8 wf2 = *(const f16x8*)(wbase + 64);
        f16x8 wf3 = *(const f16x8*)(wbase + 96);
        f16x8 wf4 = *(const f16x8*)(wbase + 128);
        f16x8 wf5 = *(const f16x8*)(wbase + 160);
        f16x8 wf6 = *(const f16x8*)(wbase + 192);
        f16x8 wf7 = *(const f16x8*)(wbase + 224);

        float b2r[4], g2r[4], be2r[4];
        bool  mk[4];
        #pragma unroll
        for (int i = 0; i < 4; ++i) {
            int oo = grp * 4 + i;
            mk[i] = oo < 10;
            int oc = mk[i] ? oo : 9;
            b2r[i] = b2[oc]; g2r[i] = g2[oc]; be2r[i] = be2[oc];
        }
        const int r  = lane & 3;
        const int pr = (lane >> 2) & 3;
        const _Float16* pbase = s1h + (4 * wave + r) * S1H_STRIDE + grp * 8;

        for (int g = 0; g < 10; ++g) {
            const int p  = g * 4 + pr;
            const int p2 = min(p, WO2 - 1);
            const _Float16* pb = pbase + p2 * 8;
            f32x4 aA = splat4(0.f), aB = splat4(0.f);
            aA = __builtin_amdgcn_mfma_f32_16x16x32_f16(wf0, *(const f16x8*)(pb),       aA, 0, 0, 0);
            aA = __builtin_amdgcn_mfma_f32_16x16x32_f16(wf1, *(const f16x8*)(pb +  32), aA, 0, 0, 0);
            aA = __builtin_amdgcn_mfma_f32_16x16x32_f16(wf2, *(const f16x8*)(pb +  64), aA, 0, 0, 0);
            aA = __builtin_amdgcn_mfma_f32_16x16x32_f16(wf3, *(const f16x8*)(pb +  96), aA, 0, 0, 0);
            aB = __builtin_amdgcn_mfma_f32_16x16x32_f16(wf4, *(const f16x8*)(pb + 128), aB, 0, 0, 0);
            aB = __builtin_amdgcn_mfma_f32_16x16x32_f16(wf5, *(const f16x8*)(pb + 160), aB, 0, 0, 0);
            aB = __builtin_amdgcn_mfma_f32_16x16x32_f16(wf6, *(const f16x8*)(pb + 192), aB, 0, 0, 0);
            aB = __builtin_amdgcn_mfma_f32_16x16x32_f16(wf7, *(const f16x8*)(pb + 224), aB, 0, 0, 0);
            f32x4 acc = aA + aB;

            float v0 = acc.x + b2r[0], v1 = acc.y + b2r[1];
            float v2 = acc.z + b2r[2], v3 = acc.w + b2r[3];
            float sp = (mk[0] ? v0 : 0.f) + (mk[1] ? v1 : 0.f)
                     + (mk[2] ? v2 : 0.f) + (mk[3] ? v3 : 0.f);
            sp += __shfl_xor(sp, 16);
            sp += __shfl_xor(sp, 32);
            const float mean = sp * 0.1f;
            float d0 = v0 - mean, d1 = v1 - mean, d2 = v2 - mean, d3 = v3 - mean;
            float sq = (mk[0] ? d0 * d0 : 0.f) + (mk[1] ? d1 * d1 : 0.f)
                     + (mk[2] ? d2 * d2 : 0.f) + (mk[3] ? d3 * d3 : 0.f);
            sq += __shfl_xor(sq, 16);
            sq += __shfl_xor(sq, 32);
            const float inv = rsqrtf(sq * 0.1f + 1e-3f);

            if (p < WO2) {
                float e0 = elu_f(d0 * inv * g2r[0] + be2r[0]);
                float e1 = elu_f(d1 * inv * g2r[1] + be2r[1]);
                float e2 = elu_f(d2 * inv * g2r[2] + be2r[2]);
                float e3 = elu_f(d3 * inv * g2r[3] + be2r[3]);
                int base = (4 * wave + r) * 196 + p * 5 + grp * 2;
                if (mk[0]) s2u[base]     = pk2h(e0, e1);
                if (mk[2]) s2u[base + 1] = pk2h(e2, e3);
            }
        }
    }
    __syncthreads();

    // ---- P3: conv3 MFMA + LN3 -> feats ----
    {
        const int tile  = wave & 1;
        const int khalf = wave >> 1;
        const int col   = lane & 15;

        const _Float16* arow = s2h + col * 392 + (lane >> 4) * 8;
        const _Float16* brow = wb + 11904 + (size_t)(tile * 16 + col) * 384 + (lane >> 4) * 8;

        f32x4 acc = splat4(0.f);
        #pragma unroll
        for (int s = 0; s < 6; ++s) {
            const int st = khalf * 6 + s;
            f16x8 af = *(const f16x8*)(arow + st * 32);
            f16x8 bf = *(const f16x8*)(brow + st * 32);
            acc = __builtin_amdgcn_mfma_f32_16x16x32_f16(af, bf, acc, 0, 0, 0);
        }
        f32x4* scrv = (f32x4*)scr;
        if (khalf == 1) scrv[tile * 64 + lane] = acc;
        __syncthreads();

        const int ocg = tile * 16 + col;
        const bool vc = ocg < 20;
        const int occ = vc ? ocg : 19;
        f32x4 vv = splat4(0.f);
        float* sums = scr + 512;
        if (khalf == 0) {
            acc += scrv[tile * 64 + lane];
            vv = acc + splat4(b3[occ]);
            if (!vc) vv = splat4(0.f);
            f32x4 s = vv, q = vv * vv;
            #pragma unroll
            for (int d = 1; d < 16; d <<= 1) {
                s.x += __shfl_xor(s.x, d); s.y += __shfl_xor(s.y, d);
                s.z += __shfl_xor(s.z, d); s.w += __shfl_xor(s.w, d);
                q.x += __shfl_xor(q.x, d); q.y += __shfl_xor(q.y, d);
                q.z += __shfl_xor(q.z, d); q.w += __shfl_xor(q.w, d);
            }
            if (col == 0) {
                const int rb = (lane >> 4) * 4;
                #pragma unroll
                for (int i = 0; i < 4; ++i) {
                    sums[tile * 64 + rb + i]      = s[i];
                    sums[tile * 64 + 16 + rb + i] = q[i];
                }
            }
        }
        __syncthreads();
        if (khalf == 0) {
            const float gg = g3[occ], bb = be3[occ];
            #pragma unroll
            for (int i = 0; i < 4; ++i) {
                const int row = (lane >> 4) * 4 + i;
                const float ts = sums[row] + sums[64 + row];
                const float tq = sums[16 + row] + sums[80 + row];
                const float mn = ts * 0.05f;
                const float vr = tq * 0.05f - mn * mn;
                const float iv = rsqrtf(vr + 1e-3f);
                if (vc) {
                    const int grow = blockIdx.x * RPB + row;
                    if (grow < nrows)
                        feats[(size_t)grow * C3 + ocg] = elu_f((vv[i] - mn) * iv * gg + bb);
                }
            }
        }
    }
}

// ---------------- Kernel 2: per-batch graph block, MFMA version (unchanged) ----------------
__global__ __launch_bounds__(256) void graph_kernel(
    const float* __restrict__ feats,
    const float* __restrict__ agent_w, const float* __restrict__ agent_b,
    const float* __restrict__ g1w, const float* __restrict__ g1b,
    const float* __restrict__ g2w, const float* __restrict__ g2b,
    const float* __restrict__ dw, const float* __restrict__ db,
    const int* __restrict__ rlp,
    float* __restrict__ out)
{
    __shared__ __align__(16) char gsm[61104];
    _Float16* const sLh  = (_Float16*)(gsm);
    _Float16* const sfcH = (_Float16*)(gsm + 34816);
    float*    const h2T  = (float*)(gsm + 34816);
    float*    const sfe  = (float*)(gsm + 45056);
    float*    const h1f  = (float*)(gsm + 45056);
    _Float16* const t1h  = (_Float16*)(gsm + 54176);
    float* const snrm  = (float*)(gsm + 58528);
    float* const sidx  = (float*)(gsm + 58984);
    float* const sdv   = (float*)(gsm + 59440);
    float* const red   = (float*)(gsm + 59896);
    float* const sfeat = (float*)(gsm + 59912);
    float* const sg1   = (float*)(gsm + 59952);
    float* const sg1b  = sg1 + 200;
    float* const sg2   = sg1b + 10;
    float* const sg2b  = sg2 + 50;
    float* const sdw   = sg2b + 5;
    float* const sdb   = sdw + 20;

    const int tid  = threadIdx.x;
    const int wave = tid >> 6;
    const int lane = tid & 63;
    const int b = blockIdx.x;
    const float* F = feats + (size_t)b * (NN * C3);
    const int rl = rlp[0];
    const float aw_b = agent_b[0];

    // ---- P0 ----
    {
        f32x4* z = (f32x4*)gsm;
        for (int i = tid; i < 2816; i += 256) z[i] = splat4(0.f);
        f32x4* z2 = (f32x4*)(gsm + 54176);
        if (tid < 272) z2[tid] = splat4(0.f);
        if (tid < 200) sg1[tid] = g1w[tid];
        if (tid < 10)  sg1b[tid] = g1b[tid];
        if (tid < 50)  sg2[tid] = g2w[tid];
        if (tid < 5)   sg2b[tid] = g2b[tid];
        if (tid < 20)  sdw[tid] = dw[tid];
        if (tid < 2)   sdb[tid] = db[tid];
    }
    __syncthreads();

    // ---- P1 ----
    for (int n = tid; n < NN; n += 256) {
        float f[C3];
        float m = 0.f;
        #pragma unroll
        for (int d = 0; d < C3; ++d) { f[d] = F[n * C3 + d]; m += f[d]; }
        m *= (1.f / C3);
        float nr = 0.f, ag = 0.f;
        unsigned int* dst = (unsigned int*)(sfcH + n * 40);
        #pragma unroll
        for (int d = 0; d < C3; d += 2) {
            sfe[n * C3 + d]     = f[d];
            sfe[n * C3 + d + 1] = f[d + 1];
            float c0 = f[d] - m, c1 = f[d + 1] - m;
            dst[d >> 1] = pk2h(c0, c1);
            nr = fmaf(c0, c0, fmaf(c1, c1, nr));
            ag = fmaf(f[d], agent_w[d], fmaf(f[d + 1], agent_w[d + 1], ag));
        }
        snrm[n] = sqrtf(nr);
        sidx[n] = rl ? (1.f / (1.f + __expf(-(ag + aw_b)))) : 1.f;
    }
    __syncthreads();

    // ---- P2 ----
    {
        float psum = 0.f;
        const int row = lane & 15;
        const int kg  = lane >> 4;
        for (int tt = 0; tt < 16; ++tt) {
            const int t  = wave * 16 + tt;
            const int tr = t >> 3, tc = t & 7;
            f16x8 a = *(const f16x8*)(sfcH + (tr * 16 + row) * 40 + kg * 8);
            f16x8 bf = *(const f16x8*)(sfcH + (tc * 16 + row) * 40 + kg * 8);
            f32x4 acc = __builtin_amdgcn_mfma_f32_16x16x32_f16(a, bf, splat4(0.f), 0, 0, 0);
            const int c = tc * 16 + row;
            const float nc = (c < NN) ? snrm[c] : 1.f;
            #pragma unroll
            for (int i = 0; i < 4; ++i) {
                const int r = tr * 16 + kg * 4 + i;
                float dist = 0.f;
                if (r < NN && c < NN && r != c)
                    dist = 1.f - acc[i] * __frcp_rn(snrm[r] * nc);
                psum += dist;
                sLh[r * 136 + c] = (_Float16)dist;
            }
        }
        #pragma unroll
        for (int d = 1; d < 64; d <<= 1) psum += __shfl_xor(psum, d);
        if (lane == 0) red[wave] = psum;
    }
    __syncthreads();

    // ---- P3 ----
    {
        const float sg = (red[0] + red[1] + red[2] + red[3]) * (1.f / (float)(NN * NN));
        const float inv2s2 = 1.f / (2.f * sg * sg);
        if (tid < 228) {
            const int r = tid >> 1, half = tid & 1;
            const float idxr = sidx[r];
            float rsum = 0.f;
            _Float16* rp = sLh + r * 136 + half * 57;
            const int c0 = half * 57;
            for (int j = 0; j < 57; ++j) {
                float d = (float)rp[j];
                float A = idxr * sidx[c0 + j] * __expf(-d * d * inv2s2);
                rsum += A;
                rp[j] = (_Float16)A;
            }
            rsum += __shfl_xor(rsum, 1);
            if (half == 0) {
                float dv = rsqrtf(rsum);
                if (isinf(dv)) dv = 0.f;
                sdv[r] = dv;
            }
        }
    }
    __syncthreads();

    // ---- P4 ----
    {
        unsigned int* L32 = (unsigned int*)sLh;
        for (int e2 = tid; e2 < NN * 57; e2 += 256) {
            const int r = e2 / 57, cp = e2 - r * 57;
            const unsigned int u = L32[r * 68 + cp];
            union { unsigned int uu; _Float16 h[2]; } in;
            in.uu = u;
            const float dr = sdv[r];
            float v0 = (float)in.h[0] * dr * sdv[2 * cp];
            float v1 = (float)in.h[1] * dr * sdv[2 * cp + 1];
            L32[r * 68 + cp] = pk2h(v0, v1);
        }
        for (int e = tid; e < NN * C2; e += 256) {
            const int n = e / C2, o = e - n * C2;
            float acc = 0.f;
            #pragma unroll
            for (int d = 0; d < C3; ++d) acc = fmaf(sfe[n * C3 + d], sg1[d * C2 + o], acc);
            t1h[o * 136 + n] = (_Float16)(acc * sidx[n] + sg1b[o]);
        }
    }
    __syncthreads();

    // ---- P5 ----
    {
        const int row = lane & 15;
        const int kg  = lane >> 4;
        #pragma unroll
        for (int tt = 0; tt < 2; ++tt) {
            const int tr = wave * 2 + tt;
            f32x4 acc = splat4(0.f);
            #pragma unroll
            for (int ks = 0; ks < 4; ++ks) {
                f16x8 a = *(const f16x8*)(sLh + (tr * 16 + row) * 136 + ks * 32 + kg * 8);
                f16x8 bf = *(const f16x8*)(t1h + row * 136 + ks * 32 + kg * 8);
                acc = __builtin_amdgcn_mfma_f32_16x16x32_f16(a, bf, acc, 0, 0, 0);
            }
            #pragma unroll
            for (int i = 0; i < 4; ++i) {
                const int n = tr * 16 + kg * 4 + i;
                h1f[n * 16 + row] = elu_f(acc[i]);
            }
        }
    }
    __syncthreads();

    // ---- P6 ----
    for (int e = tid; e < NN * C1; e += 256) {
        const int n = e / C1, c = e - n * C1;
        float acc = sg2b[c];
        #pragma unroll
        for (int o = 0; o < C2; ++o) acc = fmaf(h1f[n * 16 + o], sg2[o * C1 + c], acc);
        t1h[c * 136 + n] = (_Float16)acc;
    }
    __syncthreads();

    // ---- P7 ----
    {
        const int row = lane & 15;
        const int kg  = lane >> 4;
        #pragma unroll
        for (int tt = 0; tt < 2; ++tt) {
            const int tr = wave * 2 + tt;
            f32x4 acc = splat4(0.f);
            #pragma unroll
            for (int ks = 0; ks < 4; ++ks) {
                f16x8 a = *(const f16x8*)(sLh + (tr * 16 + row) * 136 + ks * 32 + kg * 8);
                f16x8 bf = *(const f16x8*)(t1h + row * 136 + ks * 32 + kg * 8);
                acc = __builtin_amdgcn_mfma_f32_16x16x32_f16(a, bf, acc, 0, 0, 0);
            }
            if (row < C1) {
                #pragma unroll
                for (int i = 0; i < 4; ++i) {
                    const int n = tr * 16 + kg * 4 + i;
                    h2T[row * 132 + n] = elu_f(acc[i]);
                }
            }
        }
    }
    __syncthreads();

    // ---- P8 ----
    if (tid < 160) {
        const int c = tid >> 5, s = tid & 31;
        float pmax = -INFINITY, rmin = INFINITY, sum = 0.f;
        #pragma unroll
        for (int k = 0; k < 4; ++k) {
            const int n = s + 32 * k;
            if (n < NN) {
                float v = h2T[c * 132 + n];
                pmax = fmaxf(pmax, v);
                rmin = fminf(rmin, 1.f / v);
                sum += v;
            }
        }
        #pragma unroll
        for (int d = 16; d > 0; d >>= 1) {
            pmax = fmaxf(pmax, __shfl_xor(pmax, d));
            rmin = fminf(rmin, __shfl_xor(rmin, d));
            sum += __shfl_xor(sum, d);
        }
        if (s == 0) {
            float nmax = 1.f / rmin;
            sfeat[c] = (pmax == 0.f) ? nmax : pmax;
            sfeat[C1 + c] = sum;
        }
    }
    __syncthreads();

    if (tid == 0) {
        float l0 = sdb[0], l1 = sdb[1];
        #pragma unroll
        for (int j = 0; j < 10; ++j) {
            l0 += sfeat[j] * sdw[j * 2 + 0];
            l1 += sfeat[j] * sdw[j * 2 + 1];
        }
        float mx = fmaxf(l0, l1);
        float e0 = expf(l0 - mx), e1 = expf(l1 - mx);
        float s = e0 + e1;
        out[b * 2 + 0] = e0 / s;
        out[b * 2 + 1] = e1 / s;
    }
}

extern "C" void kernel_launch(void* const* d_in, const int* in_sizes, int n_in,
                              void* d_out, int out_size, void* d_ws, size_t ws_size,
                              hipStream_t stream) {
    const float* x       = (const float*)d_in[0];
    const float* conv1_w = (const float*)d_in[1];
    const float* conv1_b = (const float*)d_in[2];
    const float* ln1_g   = (const float*)d_in[3];
    const float* ln1_b   = (const float*)d_in[4];
    const float* conv2_w = (const float*)d_in[5];
    const float* conv2_b = (const float*)d_in[6];
    const float* ln2_g   = (const float*)d_in[7];
    const float* ln2_b   = (const float*)d_in[8];
    const float* conv3_w = (const float*)d_in[9];
    const float* conv3_b = (const float*)d_in[10];
    const float* ln3_g   = (const float*)d_in[11];
    const float* ln3_b   = (const float*)d_in[12];
    const float* agent_w = (const float*)d_in[13];
    const float* agent_b = (const float*)d_in[14];
    const float* gconv1_w= (const float*)d_in[15];
    const float* gconv1_b= (const float*)d_in[16];
    const float* gconv2_w= (const float*)d_in[17];
    const float* gconv2_b= (const float*)d_in[18];
    const float* dense_w = (const float*)d_in[19];
    const float* dense_b = (const float*)d_in[20];
    const int*   rl      = (const int*)d_in[21];
    float* out = (float*)d_out;

    const int B = in_sizes[0] / (NH * WIN);
    const int nrows = B * NH;
    _Float16* wbuf = (_Float16*)d_ws;
    float* feats = (float*)((char*)d_ws + FEATS_OFF);

    dim3 block(256);
    hipLaunchKernelGGL(prep_kernel, dim3(32), block, 0, stream,
                       conv1_w, conv2_w, conv3_w, wbuf);

    dim3 grid1((nrows + RPB - 1) / RPB);
    hipLaunchKernelGGL(conv_rows_kernel, grid1, block, 0, stream,
                       x, (const _Float16*)wbuf,
                       conv1_b, ln1_g, ln1_b,
                       conv2_b, ln2_g, ln2_b,
                       conv3_b, ln3_g, ln3_b,
                       feats, nrows);

    dim3 grid2(B);
    hipLaunchKernelGGL(graph_kernel, grid2, block, 0, stream,
                       feats, agent_w, agent_b,
                       gconv1_w, gconv1_b, gconv2_w, gconv2_b,
                       dense_w, dense_b, rl, out);
}

// Round 11
// 163.502 us; speedup vs baseline: 5.2635x; 1.0232x over previous
//
#include <hip/hip_runtime.h>
#include <math.h>

#define NH    114
#define WIN   130
#define WO1   66
#define WO2   37
#define C1    5
#define C2    10
#define C3    20
#define K1    65
#define K2    30
#define K3    37
#define NN    114
#define RPB   16     // rows per block = 4 waves; row-quads per wave

typedef float f32x4 __attribute__((ext_vector_type(4)));
typedef _Float16 f16x8 __attribute__((ext_vector_type(8)));

// ---- d_ws layout ----
#define WB_HALVES 24192
#define FEATS_OFF 65536

// ---- conv LDS layout (bytes), total 38816 -> 4 blocks/CU ----
//  [0,     18432): s1h  16 x 576 f16  (pos 0..65 real, 66..71 zero)
//  [18432, 23712): w2h  10 x 264 f16
//  [23712, 36256): s2h  16 x 392 f16  | P0-P1: x16h 16 x 160 f16 aliases
//  [36256, 38816): scr  f32 (scrv 2048B + sums 512B)
#define SMEM_BYTES 38816
#define S1H_STRIDE 576
#define W2H_STRIDE 264

__device__ __forceinline__ f32x4 splat4(float s) { f32x4 r; r.x = s; r.y = s; r.z = s; r.w = s; return r; }
__device__ __forceinline__ f32x4 pkfma4(f32x4 a, f32x4 b, f32x4 c) {
    return __builtin_elementwise_fma(a, b, c);
}
__device__ __forceinline__ float elu_f(float v) { return fmaxf(v, 0.f) + __expf(fminf(v, 0.f)) - 1.f; }
__device__ __forceinline__ f32x4 elu4(f32x4 v) {
    f32x4 r;
    r.x = elu_f(v.x); r.y = elu_f(v.y); r.z = elu_f(v.z); r.w = elu_f(v.w);
    return r;
}
__device__ __forceinline__ f32x4 rsqrt4(f32x4 v) {
    f32x4 r; r.x = rsqrtf(v.x); r.y = rsqrtf(v.y); r.z = rsqrtf(v.z); r.w = rsqrtf(v.w);
    return r;
}
__device__ __forceinline__ unsigned int pk2h(float a, float b) {
    union { _Float16 h[2]; unsigned int u; } v;
    v.h[0] = (_Float16)a; v.h[1] = (_Float16)b; return v.u;
}

// ---------------- prep kernel: format weights to f16 once ----------------
__global__ __launch_bounds__(256) void prep_kernel(
    const float* __restrict__ w1, const float* __restrict__ w2,
    const float* __restrict__ w3, _Float16* __restrict__ wb)
{
    const int gtid = blockIdx.x * 256 + threadIdx.x;
    for (int i = gtid; i < WB_HALVES; i += 32 * 256) {
        float v;
        if (i < 4224) {                     // w2h [och][264]
            int och = i / 264, k = i - och * 264;
            int tap = k >> 3, c = k & 7;
            v = (och < 10 && c < 5 && tap < 30) ? w2[(tap * 5 + c) * 10 + och] : 0.f;
        } else if (i < 11904) {             // wph [(c,dlt)][96]
            int j = i - 4224;
            int c = j / 1536, r = j - c * 1536;
            int dlt = r / 96, u = r - dlt * 96;
            int t = u - dlt;
            v = (t >= 0 && t < K1) ? w1[t * C1 + c] : 0.f;
        } else {                            // w3t [oc][384]
            int j = i - 11904;
            int oc = j / 384, jj = j - oc * 384;
            v = (oc < 20 && jj < 370) ? w3[jj * C3 + oc] : 0.f;
        }
        wb[i] = (_Float16)v;
    }
}

// ---------------- Kernel 1: conv pipeline ----------------
__global__ __launch_bounds__(256, 4) void conv_rows_kernel(
    const float* __restrict__ x,
    const _Float16* __restrict__ wb,
    const float* __restrict__ b1, const float* __restrict__ g1, const float* __restrict__ be1,
    const float* __restrict__ b2, const float* __restrict__ g2, const float* __restrict__ be2,
    const float* __restrict__ b3, const float* __restrict__ g3, const float* __restrict__ be3,
    float* __restrict__ feats, int nrows)
{
    __shared__ __align__(16) char smem[SMEM_BYTES];

    const int tid  = threadIdx.x;
    const int wave = tid >> 6;
    const int lane = tid & 63;

    _Float16* const s1h  = (_Float16*)smem;
    _Float16* const w2h  = (_Float16*)(smem + 18432);
    _Float16* const s2h  = (_Float16*)(smem + 23712);
    _Float16* const x16h = (_Float16*)(smem + 23712);   // aliases s2h (P0-P1 only)
    float*    const scr  = (float*)(smem + 36256);

    const int dlt = lane & 15;
    const int grp = lane >> 4;

    // ---- P0: copy w2h (10 rows) global->LDS, stage x16, zero s1h tail ----
    {
        const f32x4* src = (const f32x4*)wb;
        f32x4* dst = (f32x4*)(smem + 18432);
        for (int i = tid; i < 330; i += 256) dst[i] = src[i];   // 5280 B
    }
    {
        unsigned int* x16u = (unsigned int*)x16h;
        const int row0g = blockIdx.x * RPB;
        for (int q = tid; q < 16 * 80; q += 256) {
            int r = q / 80, wp = q - r * 80;
            int gr = row0g + r; if (gr >= nrows) gr = nrows - 1;
            float a = 0.f, b = 0.f;
            if (wp < 65) { const float* xp = x + (size_t)gr * WIN + 2 * wp; a = xp[0]; b = xp[1]; }
            x16u[r * 80 + wp] = pk2h(a, b);
        }
    }
    for (int i = tid; i < 16 * 24; i += 256) {   // s1h halves [528,576) per row = u32 [264,288)
        int r = i / 24, c = i - r * 24;
        ((unsigned int*)s1h)[r * 288 + 264 + c] = 0u;
    }
    __syncthreads();

    // ---- P1: conv1 toeplitz MFMA (B-frags direct from global/L1) ----
    for (int g = wave; g < 5; g += (wave == 1 ? 3 : 5)) {
        const int p0 = g * 16;
        const _Float16* xb = x16h + dlt * 160 + p0 + grp * 8;
        f16x8 a0 = *(const f16x8*)(xb);
        f16x8 a1 = *(const f16x8*)(xb + 32);
        f16x8 a2 = *(const f16x8*)(xb + 64);
        f32x4 o[C1];
        #pragma unroll
        for (int c = 0; c < C1; ++c) {
            const _Float16* wbp = wb + 4224 + (c * 16 + dlt) * 96 + grp * 8;
            f32x4 t = splat4(0.f);
            t = __builtin_amdgcn_mfma_f32_16x16x32_f16(a0, *(const f16x8*)(wbp),      t, 0, 0, 0);
            t = __builtin_amdgcn_mfma_f32_16x16x32_f16(a1, *(const f16x8*)(wbp + 32), t, 0, 0, 0);
            t = __builtin_amdgcn_mfma_f32_16x16x32_f16(a2, *(const f16x8*)(wbp + 64), t, 0, 0, 0);
            o[c] = t + splat4(b1[c]);
        }
        f32x4 m = splat4(0.f);
        #pragma unroll
        for (int c = 0; c < C1; ++c) m += o[c];
        m *= 0.2f;
        f32x4 v = splat4(0.f);
        #pragma unroll
        for (int c = 0; c < C1; ++c) { f32x4 d = o[c] - m; v = pkfma4(d, d, v); }
        f32x4 inv = rsqrt4(v * 0.2f + 1e-3f);
        f32x4 oo[C1];
        #pragma unroll
        for (int c = 0; c < C1; ++c) oo[c] = elu4((o[c] - m) * inv * g1[c] + be1[c]);
        const int p = p0 + dlt;
        if (p < WO1) {
            #pragma unroll
            for (int i = 0; i < 4; ++i) {
                const int row = grp * 4 + i;
                union { _Float16 h[8]; f16x8 v8; } pkv;
                pkv.h[0] = (_Float16)oo[0][i];
                pkv.h[1] = (_Float16)oo[1][i];
                pkv.h[2] = (_Float16)oo[2][i];
                pkv.h[3] = (_Float16)oo[3][i];
                pkv.h[4] = (_Float16)oo[4][i];
                pkv.h[5] = (_Float16)0.f;
                pkv.h[6] = (_Float16)0.f;
                pkv.h[7] = (_Float16)0.f;
                *(f16x8*)&s1h[row * S1H_STRIDE + p * 8] = pkv.v8;
            }
        }
    }
    __syncthreads();

    // ---- P2: conv2 MFMA + LN2 -> s2h (f16), sliding-window A-chunk reuse ----
    {
        unsigned int* s2u = (unsigned int*)s2h;
        if (lane < 44) {
            int r4 = lane / 11, jj = lane - r4 * 11;
            s2u[(4 * wave + r4) * 196 + 185 + jj] = 0u;
        }

        // B-frag rows dlt>=10 read stale LDS; their MFMA D-rows are mk-masked.
        const _Float16* wbase = w2h + dlt * W2H_STRIDE + grp * 8;
        f16x8 wf0 = *(const f16x8*)(wbase);
        f16x8 wf1 = *(const f16x8*)(wbase + 32);
        f16x8 wf2 = *(const f16x8*)(wbase + 64);
        f16x8 wf3 = *(const f16x8*)(wbase + 96);
        f16x8 wf4 = *(const f16x8*)(wbase + 128);
        f16x8 wf5 = *(const f16x8*)(wbase + 160);
        f16x8 wf6 = *(const f16x8*)(wbase + 192);
        f16x8 wf7 = *(const f16x8*)(wbase + 224);

        float b2r[4], g2r[4], be2r[4];
        bool  mk[4];
        #pragma unroll
        for (int i = 0; i < 4; ++i) {
            int oo = grp * 4 + i;
            mk[i] = oo < 10;
            int oc = mk[i] ? oo : 9;
            b2r[i] = b2[oc]; g2r[i] = g2[oc]; be2r[i] = be2[oc];
        }
        const int r  = lane & 3;
        const int pr = (lane >> 2) & 3;
        // A-chunk c (= g+j): 8 halves at row r, offset 32c + 8*(pr+grp)
        const _Float16* arow = s1h + (4 * wave + r) * S1H_STRIDE + (pr + grp) * 8;

        f16x8 ch[17];
        #pragma unroll
        for (int c = 0; c < 8; ++c) ch[c] = *(const f16x8*)(arow + c * 32);

        #pragma unroll
        for (int g = 0; g < 10; ++g) {
            if (g + 8 <= 16) ch[g + 8] = *(const f16x8*)(arow + (g + 8) * 32);

            f32x4 aA = splat4(0.f), aB = splat4(0.f);
            aA = __builtin_amdgcn_mfma_f32_16x16x32_f16(wf0, ch[g + 0], aA, 0, 0, 0);
            aB = __builtin_amdgcn_mfma_f32_16x16x32_f16(wf1, ch[g + 1], aB, 0, 0, 0);
            aA = __builtin_amdgcn_mfma_f32_16x16x32_f16(wf2, ch[g + 2], aA, 0, 0, 0);
            aB = __builtin_amdgcn_mfma_f32_16x16x32_f16(wf3, ch[g + 3], aB, 0, 0, 0);
            aA = __builtin_amdgcn_mfma_f32_16x16x32_f16(wf4, ch[g + 4], aA, 0, 0, 0);
            aB = __builtin_amdgcn_mfma_f32_16x16x32_f16(wf5, ch[g + 5], aB, 0, 0, 0);
            aA = __builtin_amdgcn_mfma_f32_16x16x32_f16(wf6, ch[g + 6], aA, 0, 0, 0);
            aB = __builtin_amdgcn_mfma_f32_16x16x32_f16(wf7, ch[g + 7], aB, 0, 0, 0);
            f32x4 acc = aA + aB;

            float v0 = acc.x + b2r[0], v1 = acc.y + b2r[1];
            float v2 = acc.z + b2r[2], v3 = acc.w + b2r[3];
            float sp = (mk[0] ? v0 : 0.f) + (mk[1] ? v1 : 0.f)
                     + (mk[2] ? v2 : 0.f) + (mk[3] ? v3 : 0.f);
            sp += __shfl_xor(sp, 16);
            sp += __shfl_xor(sp, 32);
            const float mean = sp * 0.1f;
            float d0 = v0 - mean, d1 = v1 - mean, d2 = v2 - mean, d3 = v3 - mean;
            float sq = (mk[0] ? d0 * d0 : 0.f) + (mk[1] ? d1 * d1 : 0.f)
                     + (mk[2] ? d2 * d2 : 0.f) + (mk[3] ? d3 * d3 : 0.f);
            sq += __shfl_xor(sq, 16);
            sq += __shfl_xor(sq, 32);
            const float inv = rsqrtf(sq * 0.1f + 1e-3f);

            const int p = g * 4 + pr;
            if (p < WO2) {
                float e0 = elu_f(d0 * inv * g2r[0] + be2r[0]);
                float e1 = elu_f(d1 * inv * g2r[1] + be2r[1]);
                float e2 = elu_f(d2 * inv * g2r[2] + be2r[2]);
                float e3 = elu_f(d3 * inv * g2r[3] + be2r[3]);
                int base = (4 * wave + r) * 196 + p * 5 + grp * 2;
                if (mk[0]) s2u[base]     = pk2h(e0, e1);
                if (mk[2]) s2u[base + 1] = pk2h(e2, e3);
            }
        }
    }
    __syncthreads();

    // ---- P3: conv3 MFMA + LN3 -> feats ----
    {
        const int tile  = wave & 1;
        const int khalf = wave >> 1;
        const int col   = lane & 15;

        const _Float16* arow = s2h + col * 392 + (lane >> 4) * 8;
        const _Float16* brow = wb + 11904 + (size_t)(tile * 16 + col) * 384 + (lane >> 4) * 8;

        f32x4 acc = splat4(0.f);
        #pragma unroll
        for (int s = 0; s < 6; ++s) {
            const int st = khalf * 6 + s;
            f16x8 af = *(const f16x8*)(arow + st * 32);
            f16x8 bf = *(const f16x8*)(brow + st * 32);
            acc = __builtin_amdgcn_mfma_f32_16x16x32_f16(af, bf, acc, 0, 0, 0);
        }
        f32x4* scrv = (f32x4*)scr;
        if (khalf == 1) scrv[tile * 64 + lane] = acc;
        __syncthreads();

        const int ocg = tile * 16 + col;
        const bool vc = ocg < 20;
        const int occ = vc ? ocg : 19;
        f32x4 vv = splat4(0.f);
        float* sums = scr + 512;
        if (khalf == 0) {
            acc += scrv[tile * 64 + lane];
            vv = acc + splat4(b3[occ]);
            if (!vc) vv = splat4(0.f);
            f32x4 s = vv, q = vv * vv;
            #pragma unroll
            for (int d = 1; d < 16; d <<= 1) {
                s.x += __shfl_xor(s.x, d); s.y += __shfl_xor(s.y, d);
                s.z += __shfl_xor(s.z, d); s.w += __shfl_xor(s.w, d);
                q.x += __shfl_xor(q.x, d); q.y += __shfl_xor(q.y, d);
                q.z += __shfl_xor(q.z, d); q.w += __shfl_xor(q.w, d);
            }
            if (col == 0) {
                const int rb = (lane >> 4) * 4;
                #pragma unroll
                for (int i = 0; i < 4; ++i) {
                    sums[tile * 64 + rb + i]      = s[i];
                    sums[tile * 64 + 16 + rb + i] = q[i];
                }
            }
        }
        __syncthreads();
        if (khalf == 0) {
            const float gg = g3[occ], bb = be3[occ];
            #pragma unroll
            for (int i = 0; i < 4; ++i) {
                const int row = (lane >> 4) * 4 + i;
                const float ts = sums[row] + sums[64 + row];
                const float tq = sums[16 + row] + sums[80 + row];
                const float mn = ts * 0.05f;
                const float vr = tq * 0.05f - mn * mn;
                const float iv = rsqrtf(vr + 1e-3f);
                if (vc) {
                    const int grow = blockIdx.x * RPB + row;
                    if (grow < nrows)
                        feats[(size_t)grow * C3 + ocg] = elu_f((vv[i] - mn) * iv * gg + bb);
                }
            }
        }
    }
}

// ---------------- Kernel 2: per-batch graph block, MFMA version (unchanged) ----------------
__global__ __launch_bounds__(256) void graph_kernel(
    const float* __restrict__ feats,
    const float* __restrict__ agent_w, const float* __restrict__ agent_b,
    const float* __restrict__ g1w, const float* __restrict__ g1b,
    const float* __restrict__ g2w, const float* __restrict__ g2b,
    const float* __restrict__ dw, const float* __restrict__ db,
    const int* __restrict__ rlp,
    float* __restrict__ out)
{
    __shared__ __align__(16) char gsm[61104];
    _Float16* const sLh  = (_Float16*)(gsm);
    _Float16* const sfcH = (_Float16*)(gsm + 34816);
    float*    const h2T  = (float*)(gsm + 34816);
    float*    const sfe  = (float*)(gsm + 45056);
    float*    const h1f  = (float*)(gsm + 45056);
    _Float16* const t1h  = (_Float16*)(gsm + 54176);
    float* const snrm  = (float*)(gsm + 58528);
    float* const sidx  = (float*)(gsm + 58984);
    float* const sdv   = (float*)(gsm + 59440);
    float* const red   = (float*)(gsm + 59896);
    float* const sfeat = (float*)(gsm + 59912);
    float* const sg1   = (float*)(gsm + 59952);
    float* const sg1b  = sg1 + 200;
    float* const sg2   = sg1b + 10;
    float* const sg2b  = sg2 + 50;
    float* const sdw   = sg2b + 5;
    float* const sdb   = sdw + 20;

    const int tid  = threadIdx.x;
    const int wave = tid >> 6;
    const int lane = tid & 63;
    const int b = blockIdx.x;
    const float* F = feats + (size_t)b * (NN * C3);
    const int rl = rlp[0];
    const float aw_b = agent_b[0];

    // ---- P0 ----
    {
        f32x4* z = (f32x4*)gsm;
        for (int i = tid; i < 2816; i += 256) z[i] = splat4(0.f);
        f32x4* z2 = (f32x4*)(gsm + 54176);
        if (tid < 272) z2[tid] = splat4(0.f);
        if (tid < 200) sg1[tid] = g1w[tid];
        if (tid < 10)  sg1b[tid] = g1b[tid];
        if (tid < 50)  sg2[tid] = g2w[tid];
        if (tid < 5)   sg2b[tid] = g2b[tid];
        if (tid < 20)  sdw[tid] = dw[tid];
        if (tid < 2)   sdb[tid] = db[tid];
    }
    __syncthreads();

    // ---- P1 ----
    for (int n = tid; n < NN; n += 256) {
        float f[C3];
        float m = 0.f;
        #pragma unroll
        for (int d = 0; d < C3; ++d) { f[d] = F[n * C3 + d]; m += f[d]; }
        m *= (1.f / C3);
        float nr = 0.f, ag = 0.f;
        unsigned int* dst = (unsigned int*)(sfcH + n * 40);
        #pragma unroll
        for (int d = 0; d < C3; d += 2) {
            sfe[n * C3 + d]     = f[d];
            sfe[n * C3 + d + 1] = f[d + 1];
            float c0 = f[d] - m, c1 = f[d + 1] - m;
            dst[d >> 1] = pk2h(c0, c1);
            nr = fmaf(c0, c0, fmaf(c1, c1, nr));
            ag = fmaf(f[d], agent_w[d], fmaf(f[d + 1], agent_w[d + 1], ag));
        }
        snrm[n] = sqrtf(nr);
        sidx[n] = rl ? (1.f / (1.f + __expf(-(ag + aw_b)))) : 1.f;
    }
    __syncthreads();

    // ---- P2 ----
    {
        float psum = 0.f;
        const int row = lane & 15;
        const int kg  = lane >> 4;
        for (int tt = 0; tt < 16; ++tt) {
            const int t  = wave * 16 + tt;
            const int tr = t >> 3, tc = t & 7;
            f16x8 a = *(const f16x8*)(sfcH + (tr * 16 + row) * 40 + kg * 8);
            f16x8 bf = *(const f16x8*)(sfcH + (tc * 16 + row) * 40 + kg * 8);
            f32x4 acc = __builtin_amdgcn_mfma_f32_16x16x32_f16(a, bf, splat4(0.f), 0, 0, 0);
            const int c = tc * 16 + row;
            const float nc = (c < NN) ? snrm[c] : 1.f;
            #pragma unroll
            for (int i = 0; i < 4; ++i) {
                const int r = tr * 16 + kg * 4 + i;
                float dist = 0.f;
                if (r < NN && c < NN && r != c)
                    dist = 1.f - acc[i] * __frcp_rn(snrm[r] * nc);
                psum += dist;
                sLh[r * 136 + c] = (_Float16)dist;
            }
        }
        #pragma unroll
        for (int d = 1; d < 64; d <<= 1) psum += __shfl_xor(psum, d);
        if (lane == 0) red[wave] = psum;
    }
    __syncthreads();

    // ---- P3 ----
    {
        const float sg = (red[0] + red[1] + red[2] + red[3]) * (1.f / (float)(NN * NN));
        const float inv2s2 = 1.f / (2.f * sg * sg);
        if (tid < 228) {
            const int r = tid >> 1, half = tid & 1;
            const float idxr = sidx[r];
            float rsum = 0.f;
            _Float16* rp = sLh + r * 136 + half * 57;
            const int c0 = half * 57;
            for (int j = 0; j < 57; ++j) {
                float d = (float)rp[j];
                float A = idxr * sidx[c0 + j] * __expf(-d * d * inv2s2);
                rsum += A;
                rp[j] = (_Float16)A;
            }
            rsum += __shfl_xor(rsum, 1);
            if (half == 0) {
                float dv = rsqrtf(rsum);
                if (isinf(dv)) dv = 0.f;
                sdv[r] = dv;
            }
        }
    }
    __syncthreads();

    // ---- P4 ----
    {
        unsigned int* L32 = (unsigned int*)sLh;
        for (int e2 = tid; e2 < NN * 57; e2 += 256) {
            const int r = e2 / 57, cp = e2 - r * 57;
            const unsigned int u = L32[r * 68 + cp];
            union { unsigned int uu; _Float16 h[2]; } in;
            in.uu = u;
            const float dr = sdv[r];
            float v0 = (float)in.h[0] * dr * sdv[2 * cp];
            float v1 = (float)in.h[1] * dr * sdv[2 * cp + 1];
            L32[r * 68 + cp] = pk2h(v0, v1);
        }
        for (int e = tid; e < NN * C2; e += 256) {
            const int n = e / C2, o = e - n * C2;
            float acc = 0.f;
            #pragma unroll
            for (int d = 0; d < C3; ++d) acc = fmaf(sfe[n * C3 + d], sg1[d * C2 + o], acc);
            t1h[o * 136 + n] = (_Float16)(acc * sidx[n] + sg1b[o]);
        }
    }
    __syncthreads();

    // ---- P5 ----
    {
        const int row = lane & 15;
        const int kg  = lane >> 4;
        #pragma unroll
        for (int tt = 0; tt < 2; ++tt) {
            const int tr = wave * 2 + tt;
            f32x4 acc = splat4(0.f);
            #pragma unroll
            for (int ks = 0; ks < 4; ++ks) {
                f16x8 a = *(const f16x8*)(sLh + (tr * 16 + row) * 136 + ks * 32 + kg * 8);
                f16x8 bf = *(const f16x8*)(t1h + row * 136 + ks * 32 + kg * 8);
                acc = __builtin_amdgcn_mfma_f32_16x16x32_f16(a, bf, acc, 0, 0, 0);
            }
            #pragma unroll
            for (int i = 0; i < 4; ++i) {
                const int n = tr * 16 + kg * 4 + i;
                h1f[n * 16 + row] = elu_f(acc[i]);
            }
        }
    }
    __syncthreads();

    // ---- P6 ----
    for (int e = tid; e < NN * C1; e += 256) {
        const int n = e / C1, c = e - n * C1;
        float acc = sg2b[c];
        #pragma unroll
        for (int o = 0; o < C2; ++o) acc = fmaf(h1f[n * 16 + o], sg2[o * C1 + c], acc);
        t1h[c * 136 + n] = (_Float16)acc;
    }
    __syncthreads();

    // ---- P7 ----
    {
        const int row = lane & 15;
        const int kg  = lane >> 4;
        #pragma unroll
        for (int tt = 0; tt < 2; ++tt) {
            const int tr = wave * 2 + tt;
            f32x4 acc = splat4(0.f);
            #pragma unroll
            for (int ks = 0; ks < 4; ++ks) {
                f16x8 a = *(const f16x8*)(sLh + (tr * 16 + row) * 136 + ks * 32 + kg * 8);
                f16x8 bf = *(const f16x8*)(t1h + row * 136 + ks * 32 + kg * 8);
                acc = __builtin_amdgcn_mfma_f32_16x16x32_f16(a, bf, acc, 0, 0, 0);
            }
            if (row < C1) {
                #pragma unroll
                for (int i = 0; i < 4; ++i) {
                    const int n = tr * 16 + kg * 4 + i;
                    h2T[row * 132 + n] = elu_f(acc[i]);
                }
            }
        }
    }
    __syncthreads();

    // ---- P8 ----
    if (tid < 160) {
        const int c = tid >> 5, s = tid & 31;
        float pmax = -INFINITY, rmin = INFINITY, sum = 0.f;
        #pragma unroll
        for (int k = 0; k < 4; ++k) {
            const int n = s + 32 * k;
            if (n < NN) {
                float v = h2T[c * 132 + n];
                pmax = fmaxf(pmax, v);
                rmin = fminf(rmin, 1.f / v);
                sum += v;
            }
        }
        #pragma unroll
        for (int d = 16; d > 0; d >>= 1) {
            pmax = fmaxf(pmax, __shfl_xor(pmax, d));
            rmin = fminf(rmin, __shfl_xor(rmin, d));
            sum += __shfl_xor(sum, d);
        }
        if (s == 0) {
            float nmax = 1.f / rmin;
            sfeat[c] = (pmax == 0.f) ? nmax : pmax;
            sfeat[C1 + c] = sum;
        }
    }
    __syncthreads();

    if (tid == 0) {
        float l0 = sdb[0], l1 = sdb[1];
        #pragma unroll
        for (int j = 0; j < 10; ++j) {
            l0 += sfeat[j] * sdw[j * 2 + 0];
            l1 += sfeat[j] * sdw[j * 2 + 1];
        }
        float mx = fmaxf(l0, l1);
        float e0 = expf(l0 - mx), e1 = expf(l1 - mx);
        float s = e0 + e1;
        out[b * 2 + 0] = e0 / s;
        out[b * 2 + 1] = e1 / s;
    }
}

extern "C" void kernel_launch(void* const* d_in, const int* in_sizes, int n_in,
                              void* d_out, int out_size, void* d_ws, size_t ws_size,
                              hipStream_t stream) {
    const float* x       = (const float*)d_in[0];
    const float* conv1_w = (const float*)d_in[1];
    const float* conv1_b = (const float*)d_in[2];
    const float* ln1_g   = (const float*)d_in[3];
    const float* ln1_b   = (const float*)d_in[4];
    const float* conv2_w = (const float*)d_in[5];
    const float* conv2_b = (const float*)d_in[6];
    const float* ln2_g   = (const float*)d_in[7];
    const float* ln2_b   = (const float*)d_in[8];
    const float* conv3_w = (const float*)d_in[9];
    const float* conv3_b = (const float*)d_in[10];
    const float* ln3_g   = (const float*)d_in[11];
    const float* ln3_b   = (const float*)d_in[12];
    const float* agent_w = (const float*)d_in[13];
    const float* agent_b = (const float*)d_in[14];
    const float* gconv1_w= (const float*)d_in[15];
    const float* gconv1_b= (const float*)d_in[16];
    const float* gconv2_w= (const float*)d_in[17];
    const float* gconv2_b= (const float*)d_in[18];
    const float* dense_w = (const float*)d_in[19];
    const float* dense_b = (const float*)d_in[20];
    const int*   rl      = (const int*)d_in[21];
    float* out = (float*)d_out;

    const int B = in_sizes[0] / (NH * WIN);
    const int nrows = B * NH;
    _Float16* wbuf = (_Float16*)d_ws;
    float* feats = (float*)((char*)d_ws + FEATS_OFF);

    dim3 block(256);
    hipLaunchKernelGGL(prep_kernel, dim3(32), block, 0, stream,
                       conv1_w, conv2_w, conv3_w, wbuf);

    dim3 grid1((nrows + RPB - 1) / RPB);
    hipLaunchKernelGGL(conv_rows_kernel, grid1, block, 0, stream,
                       x, (const _Float16*)wbuf,
                       conv1_b, ln1_g, ln1_b,
                       conv2_b, ln2_g, ln2_b,
                       conv3_b, ln3_g, ln3_b,
                       feats, nrows);

    dim3 grid2(B);
    hipLaunchKernelGGL(graph_kernel, grid2, block, 0, stream,
                       feats, agent_w, agent_b,
                       gconv1_w, gconv1_b, gconv2_w, gconv2_b,
                       dense_w, dense_b, rl, out);
}